// Round 8
// baseline (1175.189 us; speedup 1.0000x reference)
//
#include <hip/hip_runtime.h>

// ============================================================================
// GLM4-MoE attention layer on MI355X (gfx950), fp16 MFMA pipeline.
// Round 8: GEMM "B-direct" experiment. r4-r7 (4 different schedules) all pin
// at 35-37% MfmaUtil / ~820 TF — invariant across them: both operands flow
// through LDS and every MFMA trails a fresh ds_read burst. This round B is
// loaded global->VGPR directly (per-wave-owned 64 B^T rows, 64B-contiguous
// per 4 lanes, L1/L2-resident); A stays in LDS (4-way wave sharing).
// Per block-tile: LDS staged 48->16 KB, ds_read 131->65 KB, drain loads 6->2.
// Attention v4 (round-5) and aux kernels unchanged.
// ============================================================================

typedef _Float16 f16;
typedef _Float16 f16x8 __attribute__((ext_vector_type(8)));
typedef float f32x4 __attribute__((ext_vector_type(4)));

static constexpr int Bn = 2, Sn = 2048, Hn = 4096, NH = 32, NKV = 8, HD = 128;
static constexpr float QSC = 0.08838834764831845f * 1.44269504088896340736f; // 1/sqrt(128)*log2e

#define AS1 __attribute__((address_space(1)))
#define AS3 __attribute__((address_space(3)))

__device__ __forceinline__ void async_ld16(const void* g, void* l) {
    __builtin_amdgcn_global_load_lds((const AS1 void*)g, (AS3 void*)l, 16, 0, 0);
}

__device__ __forceinline__ unsigned pk2(float a, float b) {
    unsigned r;
    asm("v_cvt_pkrtz_f16_f32 %0, %1, %2" : "=v"(r) : "v"(a), "v"(b));
    return r;
}

// native exp2: v_exp_f32 computes 2^x
__device__ __forceinline__ float fexp2(float x) {
    float r;
    asm("v_exp_f32 %0, %1" : "=v"(r) : "v"(x));
    return r;
}

// ---------------------------------------------------------------------------
__global__ void k_cvt(const float* __restrict__ src, f16* __restrict__ dst, long n) {
    long i = ((long)blockIdx.x * blockDim.x + threadIdx.x) * 8;
    if (i >= n) return;
    float4 a = *(const float4*)(src + i);
    float4 b = *(const float4*)(src + i + 4);
    f16x8 o = {(f16)a.x, (f16)a.y, (f16)a.z, (f16)a.w,
               (f16)b.x, (f16)b.y, (f16)b.z, (f16)b.w};
    *(f16x8*)(dst + i) = o;
}

// ---------------------------------------------------------------------------
__global__ void k_tcvt(const float* __restrict__ src, f16* __restrict__ dst,
                       int K, int N, long rs) {
    __shared__ float tile[32][33];
    int k0 = blockIdx.y * 32, n0 = blockIdx.x * 32;
    int tx = threadIdx.x, ty = threadIdx.y;
#pragma unroll
    for (int r = ty; r < 32; r += 8)
        tile[r][tx] = src[(long)(k0 + r) * N + (n0 + tx)];
    __syncthreads();
#pragma unroll
    for (int r = ty; r < 32; r += 8)
        dst[(long)(n0 + r) * rs + (k0 + tx)] = (f16)tile[tx][r];
}

// ---------------------------------------------------------------------------
__global__ void k_rope(f16* __restrict__ x, const float* __restrict__ cosb,
                       const float* __restrict__ sinb, int nheads) {
    long idx = (long)blockIdx.x * blockDim.x + threadIdx.x;
    int i = (int)(idx & 31);
    long t = idx >> 5;
    int s = (int)(t & (Sn - 1));
    int bh = (int)(t >> 11);
    int b = bh / nheads;
    long base = t * HD + 2 * i;
    float c = cosb[((long)b * Sn + s) * 64 + i];
    float sv = sinb[((long)b * Sn + s) * 64 + i];
    float x0 = (float)x[base], x1 = (float)x[base + 1];
    x[base]     = (f16)(x0 * c - x1 * sv);
    x[base + 1] = (f16)(x1 * c + x0 * sv);
}

// ---------------------------------------------------------------------------
__global__ void k_tv(const f16* __restrict__ v, f16* __restrict__ vt) {
    __shared__ f16 tile[32][33];
    int bk = blockIdx.z;
    int s0 = blockIdx.x * 32, d0 = blockIdx.y * 32;
    const f16* src = v + (long)bk * Sn * HD;
    f16* dst = vt + (long)bk * Sn * HD;
    int tx = threadIdx.x, ty = threadIdx.y;
#pragma unroll
    for (int r = ty; r < 32; r += 8)
        tile[r][tx] = src[(long)(s0 + r) * HD + (d0 + tx)];
    __syncthreads();
#pragma unroll
    for (int r = ty; r < 32; r += 8)
        dst[(long)(d0 + r) * Sn + (s0 + tx)] = tile[tx][r];
}

// ---------------------------------------------------------------------------
// 128x256 GEMM core, BK=64, 8 waves (2M x 4N, each 64x64), K=4096 fixed.
// A: staged to LDS [128][64] f16 (16 KB, swizzled rows) via 2 gload_lds/wave.
// B: DIRECT global->register. Each wave owns rows n0+wn*64..+64 of B^T; per
// (nf,ks) fragment = global dwordx4, 16 rows x 64B contiguous, L1/L2-hot.
// Per K-tile: issue 8 B-frag loads + stage A -> syncthreads (drains vmcnt)
// -> 2 ksteps of {4 ds_read af + 16 MFMA} -> syncthreads.
__device__ __forceinline__ void gemm_core(
    const f16* __restrict__ A, const f16* __restrict__ Bt,
    char* L, int m0, int n0, f32x4 acc[4][4]) {
    const int t = threadIdx.x, lane = t & 63, wave = t >> 6;
    const int wm = wave >> 2, wn = wave & 3;
    const int fr = lane & 15, fg = lane >> 4;

    // A staging sources (linear LDS dest; source col pre-swizzled)
    const f16* gsa[2];
#pragma unroll
    for (int i = 0; i < 2; ++i) {
        int d = i * 8192 + t * 16;
        int row = d >> 7, cb = (d & 127) ^ ((row & 7) << 4);
        gsa[i] = A + (long)(m0 + row) * 4096 + (cb >> 1);
    }
    const int dst0 = wave * 1024;   // wave-uniform; HW adds lane*16

    // B fragment base addresses (4 nf rows-groups; fg picks the 16B chunk)
    const f16* gbp[4];
#pragma unroll
    for (int nf = 0; nf < 4; ++nf)
        gbp[nf] = Bt + (long)(n0 + wn * 64 + nf * 16 + fr) * 4096 + fg * 8;

    for (int kt = 0; kt < 64; ++kt) {
        // B fragments for this tile: 8 x global dwordx4 into regs
        f16x8 bq[2][4];
#pragma unroll
        for (int ks = 0; ks < 2; ++ks)
#pragma unroll
            for (int nf = 0; nf < 4; ++nf)
                bq[ks][nf] = *(const f16x8*)(gbp[nf] + ks * 32);
#pragma unroll
        for (int nf = 0; nf < 4; ++nf) gbp[nf] += 64;
        // stage A tile (2 x global_load_lds)
#pragma unroll
        for (int i = 0; i < 2; ++i)
            async_ld16(gsa[i] + kt * 64, L + i * 8192 + dst0);
        __syncthreads();   // drains vmcnt: A in LDS, bq in regs

#pragma unroll
        for (int ks = 0; ks < 2; ++ks) {
            const int cb = ks * 64 + 16 * fg;
            f16x8 af[4];
#pragma unroll
            for (int mf = 0; mf < 4; ++mf) {
                int r = wm * 64 + mf * 16 + fr;
                af[mf] = *(const f16x8*)(L + r * 128 + (cb ^ ((r & 7) << 4)));
            }
            __builtin_amdgcn_s_setprio(1);
#pragma unroll
            for (int mf = 0; mf < 4; ++mf)
#pragma unroll
                for (int nf = 0; nf < 4; ++nf)
                    acc[mf][nf] = __builtin_amdgcn_mfma_f32_16x16x32_f16(
                        af[mf], bq[ks][nf], acc[mf][nf], 0, 0, 0);
            __builtin_amdgcn_s_setprio(0);
        }
        __syncthreads();   // af reads done before next tile's A stage
    }
}

// GEMM1: hidden[4096][4096] @ Wqkv^T[6144][4096] -> scatter q/k/v (Q pre-scaled)
// grid 768; n-major per-XCD chunks (B panel stays XCD-local for L1/L2 reuse).
__global__ __launch_bounds__(512) void k_gemm_qkv(
    const f16* __restrict__ A, const f16* __restrict__ Bt,
    f16* __restrict__ q, f16* __restrict__ kk_, f16* __restrict__ vv) {
    __shared__ __align__(16) char L[16384];
    const int xcd = blockIdx.x & 7, i = blockIdx.x >> 3;   // i in [0,96)
    const int n0 = (xcd * 3 + (i >> 5)) * 256;
    const int m0 = (i & 31) * 128;
    f32x4 acc[4][4] = {};
    gemm_core(A, Bt, L, m0, n0, acc);

    const int lane = threadIdx.x & 63, wave = threadIdx.x >> 6;
    const int wm = wave >> 2, wn = wave & 3;
    const int fr = lane & 15, fg = lane >> 4;
#pragma unroll
    for (int mf = 0; mf < 4; ++mf) {
        int r0 = m0 + wm * 64 + mf * 16 + 4 * fg;
#pragma unroll
        for (int nf = 0; nf < 4; ++nf) {
            int cc = n0 + wn * 64 + nf * 16 + fr;
            int d = cc & 127;
#pragma unroll
            for (int e = 0; e < 4; ++e) {
                int r = r0 + e;
                int b = r >> 11, s = r & (Sn - 1);
                if (cc < 4096) {
                    int h = cc >> 7;
                    q[(((long)b * NH + h) * Sn + s) * HD + d] = (f16)(acc[mf][nf][e] * QSC);
                } else if (cc < 5120) {
                    int h = (cc - 4096) >> 7;
                    kk_[(((long)b * NKV + h) * Sn + s) * HD + d] = (f16)acc[mf][nf][e];
                } else {
                    int h = (cc - 5120) >> 7;
                    vv[(((long)b * NKV + h) * Sn + s) * HD + d] = (f16)acc[mf][nf][e];
                }
            }
        }
    }
}

// GEMM2: attn_out[4096][4096] @ wo^T[4096][4096] -> d_out f32, grid 512
__global__ __launch_bounds__(512) void k_gemm_out(
    const f16* __restrict__ A, const f16* __restrict__ Bt,
    float* __restrict__ out) {
    __shared__ __align__(16) char L[16384];
    const int xcd = blockIdx.x & 7, i = blockIdx.x >> 3;   // i in [0,64)
    const int n0 = (xcd * 2 + (i >> 5)) * 256;
    const int m0 = (i & 31) * 128;
    f32x4 acc[4][4] = {};
    gemm_core(A, Bt, L, m0, n0, acc);

    const int lane = threadIdx.x & 63, wave = threadIdx.x >> 6;
    const int wm = wave >> 2, wn = wave & 3;
    const int fr = lane & 15, fg = lane >> 4;
#pragma unroll
    for (int mf = 0; mf < 4; ++mf) {
        int r0 = m0 + wm * 64 + mf * 16 + 4 * fg;
#pragma unroll
        for (int nf = 0; nf < 4; ++nf) {
            int cc = n0 + wn * 64 + nf * 16 + fr;
#pragma unroll
            for (int e = 0; e < 4; ++e)
                out[(long)(r0 + e) * 4096 + cc] = acc[mf][nf][e];
        }
    }
}

// ---------------------------------------------------------------------------
// Flash attention v4 (round-5 proven): swapped QK^T + in-lane softmax +
// defer-rescale, native v_exp, Psm[32][32] 2-phase PV, kvh-grouped grid,
// K/V dbuf + vmcnt(8) + XOR swizzle.

__device__ __forceinline__ f16x8 ld_sw256(const f16* base, int r, int c) {
    int byte = r * 256 + ((c * 2) ^ ((r & 7) << 4));
    return *(const f16x8*)((const char*)base + byte);
}
__device__ __forceinline__ f16x8 ld_sw128(const f16* base, int r, int c) {
    int byte = r * 128 + ((c * 2) ^ ((r & 7) << 4));
    return *(const f16x8*)((const char*)base + byte);
}

__device__ __forceinline__ void stage_k(const f16* __restrict__ Kb, f16* ksm,
                                        int k0, int wave, int lane) {
#pragma unroll
    for (int i = 0; i < 4; ++i) {
        int dbase = (i * 4 + wave) * 1024;
        int d = dbase + lane * 16;
        int row = d >> 8;
        int cb = (d & 255) ^ ((row & 7) << 4);
        async_ld16(Kb + (long)(k0 + row) * HD + (cb >> 1), (char*)ksm + dbase);
    }
}
__device__ __forceinline__ void stage_v(const f16* __restrict__ Vb, f16* vsm,
                                        int k0, int wave, int lane) {
#pragma unroll
    for (int i = 0; i < 4; ++i) {
        int dbase = (i * 4 + wave) * 1024;
        int d = dbase + lane * 16;
        int row = d >> 7;
        int cb = (d & 127) ^ ((row & 7) << 4);
        async_ld16(Vb + (long)row * Sn + k0 + (cb >> 1), (char*)vsm + dbase);
    }
}

__global__ __launch_bounds__(256) void k_attn(
    const f16* __restrict__ Q, const f16* __restrict__ K,
    const f16* __restrict__ Vt, f16* __restrict__ O) {
    __shared__ __align__(16) f16 Ksm[2][64 * 128];
    __shared__ __align__(16) f16 Vsm[2][128 * 64];
    __shared__ __align__(16) f16 Psm[4][32 * 32];

    const int id = blockIdx.x;
    const int kvh = id & 7;
    const int r_ = id >> 3;
    const int qt = 15 - (r_ & 15);
    const int hg = (r_ >> 4) & 3;
    const int b  = r_ >> 6;
    const int h  = kvh * 4 + hg;
    const int q0 = qt * 128;
    const int t = threadIdx.x, lane = t & 63, wave = t >> 6;
    const int q0w = q0 + wave * 32;
    const int fr = lane & 15, fg = lane >> 4;

    const f16* Qb = Q + ((long)(b * NH + h) * Sn) * HD;
    const f16* Kb = K + ((long)(b * NKV + kvh) * Sn) * HD;
    const f16* Vb = Vt + ((long)(b * NKV + kvh) * HD) * Sn;

    f16x8 qf[2][4];
#pragma unroll
    for (int mq = 0; mq < 2; ++mq)
#pragma unroll
        for (int kk = 0; kk < 4; ++kk)
            qf[mq][kk] = *(const f16x8*)&Qb[(long)(q0w + mq * 16 + fr) * HD + kk * 32 + 8 * fg];

    f32x4 oacc[2][8] = {};
    float mrun[2] = {-1e30f, -1e30f};
    float lrun[2] = {0.f, 0.f};

    const int nt = q0 / 64 + 2;
    stage_k(Kb, Ksm[0], 0, wave, lane);
    stage_v(Vb, Vsm[0], 0, wave, lane);

    for (int kt = 0; kt < nt; ++kt) {
        const int k0 = kt * 64;
        const int cur = kt & 1;
        if (kt + 1 < nt) {
            stage_k(Kb, Ksm[cur ^ 1], (kt + 1) * 64, wave, lane);
            stage_v(Vb, Vsm[cur ^ 1], (kt + 1) * 64, wave, lane);
            asm volatile("s_waitcnt vmcnt(8)" ::: "memory");
        } else {
            asm volatile("s_waitcnt vmcnt(0)" ::: "memory");
        }
        __builtin_amdgcn_s_barrier();

        if (k0 <= q0w + 31) {
            f32x4 st[4][2] = {};
#pragma unroll
            for (int kk = 0; kk < 4; ++kk)
#pragma unroll
                for (int nn = 0; nn < 4; ++nn) {
                    f16x8 kf = ld_sw256(Ksm[cur], nn * 16 + fr, kk * 32 + 8 * fg);
#pragma unroll
                    for (int mq = 0; mq < 2; ++mq)
                        st[nn][mq] = __builtin_amdgcn_mfma_f32_16x16x32_f16(
                            kf, qf[mq][kk], st[nn][mq], 0, 0, 0);
                }
            const bool full = (k0 + 63 <= q0w);
            if (!full) {
#pragma unroll
                for (int nn = 0; nn < 4; ++nn)
#pragma unroll
                    for (int mq = 0; mq < 2; ++mq)
#pragma unroll
                        for (int e = 0; e < 4; ++e) {
                            int kv = k0 + 16 * nn + 4 * fg + e;
                            int qq = q0w + 16 * mq + fr;
                            if (kv > qq) st[nn][mq][e] = -1e30f;
                        }
            }
            float pmax[2];
#pragma unroll
            for (int mq = 0; mq < 2; ++mq) {
                float m0v = fmaxf(fmaxf(st[0][mq][0], st[0][mq][1]),
                                  fmaxf(st[0][mq][2], st[0][mq][3]));
#pragma unroll
                for (int nn = 1; nn < 4; ++nn) {
                    float mv = fmaxf(fmaxf(st[nn][mq][0], st[nn][mq][1]),
                                     fmaxf(st[nn][mq][2], st[nn][mq][3]));
                    m0v = fmaxf(m0v, mv);
                }
                m0v = fmaxf(m0v, __shfl_xor(m0v, 16, 64));
                m0v = fmaxf(m0v, __shfl_xor(m0v, 32, 64));
                pmax[mq] = m0v;
            }
            bool need = (pmax[0] > mrun[0] + 8.f) || (pmax[1] > mrun[1] + 8.f);
            if (__any(need)) {
#pragma unroll
                for (int mq = 0; mq < 2; ++mq) {
                    float mn = fmaxf(mrun[mq], pmax[mq]);
                    float sc = fexp2(mrun[mq] - mn);
                    mrun[mq] = mn;
                    lrun[mq] *= sc;
                    float scr[4];
#pragma unroll
                    for (int e = 0; e < 4; ++e)
                        scr[e] = __shfl(sc, (lane & 48) | (4 * fg + e), 64);
#pragma unroll
                    for (int nd = 0; nd < 8; ++nd)
#pragma unroll
                        for (int e = 0; e < 4; ++e)
                            oacc[mq][nd][e] *= scr[e];
                }
            }
#pragma unroll
            for (int ph = 0; ph < 2; ++ph) {
#pragma unroll
                for (int mq = 0; mq < 2; ++mq) {
                    int row = 16 * mq + fr;
                    int rot = ((row >> 1) & 3) << 4;
                    char* pbase = (char*)&Psm[wave][0] + row * 64;
#pragma unroll
                    for (int nh = 0; nh < 2; ++nh) {
                        int nn = 2 * ph + nh;
                        float p0 = fexp2(st[nn][mq][0] - mrun[mq]);
                        float p1 = fexp2(st[nn][mq][1] - mrun[mq]);
                        float p2 = fexp2(st[nn][mq][2] - mrun[mq]);
                        float p3 = fexp2(st[nn][mq][3] - mrun[mq]);
                        lrun[mq] += (p0 + p1) + (p2 + p3);
                        uint2 w = {pk2(p0, p1), pk2(p2, p3)};
                        *(uint2*)(pbase + ((32 * nh + 8 * fg + rot) & 63)) = w;
                    }
                }
                asm volatile("s_waitcnt lgkmcnt(0)" ::: "memory");
                f16x8 pf[2];
#pragma unroll
                for (int mq = 0; mq < 2; ++mq) {
                    int row = 16 * mq + fr;
                    int rot = ((row >> 1) & 3) << 4;
                    pf[mq] = *(const f16x8*)((char*)&Psm[wave][0] + row * 64 +
                                             ((16 * fg + rot) & 63));
                }
#pragma unroll
                for (int nd = 0; nd < 8; ++nd) {
                    f16x8 vf = ld_sw128(Vsm[cur], nd * 16 + fr, ph * 32 + 8 * fg);
#pragma unroll
                    for (int mq = 0; mq < 2; ++mq)
                        oacc[mq][nd] = __builtin_amdgcn_mfma_f32_16x16x32_f16(
                            pf[mq], vf, oacc[mq][nd], 0, 0, 0);
                }
            }
        }
        __builtin_amdgcn_s_barrier();
    }

#pragma unroll
    for (int mq = 0; mq < 2; ++mq) {
        lrun[mq] += __shfl_xor(lrun[mq], 16, 64);
        lrun[mq] += __shfl_xor(lrun[mq], 32, 64);
    }
#pragma unroll
    for (int mq = 0; mq < 2; ++mq) {
        float li = 1.f / lrun[mq];
        float ir[4];
#pragma unroll
        for (int e = 0; e < 4; ++e)
            ir[e] = __shfl(li, (lane & 48) | (4 * fg + e), 64);
#pragma unroll
        for (int nd = 0; nd < 8; ++nd)
#pragma unroll
            for (int e = 0; e < 4; ++e) {
                int srow = q0w + mq * 16 + 4 * fg + e;
                long tok = (long)b * Sn + srow;
                O[tok * (NH * HD) + h * HD + nd * 16 + fr] = (f16)(oacc[mq][nd][e] * ir[e]);
            }
    }
}

// sentinel if workspace too small
__global__ void k_ws_fail(float* out) { out[0] = 1.0e9f; }

// ---------------------------------------------------------------------------
extern "C" void kernel_launch(void* const* d_in, const int* in_sizes, int n_in,
                              void* d_out, int out_size, void* d_ws, size_t ws_size,
                              hipStream_t stream) {
    const float* hs   = (const float*)d_in[0];
    const float* wq   = (const float*)d_in[1];
    const float* wk   = (const float*)d_in[2];
    const float* wv   = (const float*)d_in[3];
    const float* wo   = (const float*)d_in[4];
    const float* cosb = (const float*)d_in[5];
    const float* sinb = (const float*)d_in[6];
    float* out = (float*)d_out;

    const size_t OFF_WQKV = 0;
    const size_t OFF_WO   = 50331648;
    const size_t OFF_HID  = 83886080;
    const size_t OFF_Q    = 117440512;
    const size_t OFF_K    = 150994944;
    const size_t OFF_V    = 159383552;
    const size_t OFF_VT   = 167772160;
    const size_t WS_NEED  = 176160768;
    if (ws_size < WS_NEED) { k_ws_fail<<<1, 1, 0, stream>>>(out); return; }

    char* ws = (char*)d_ws;
    f16* wqkv_t = (f16*)(ws + OFF_WQKV);
    f16* wo_t   = (f16*)(ws + OFF_WO);
    f16* hid    = (f16*)(ws + OFF_HID);
    f16* qb     = (f16*)(ws + OFF_Q);
    f16* kb     = (f16*)(ws + OFF_K);
    f16* vb     = (f16*)(ws + OFF_V);
    f16* vtb    = (f16*)(ws + OFF_VT);

    dim3 tb(32, 8);
    k_cvt<<<dim3(16777216 / (256 * 8)), 256, 0, stream>>>(hs, hid, 16777216L);
    k_tcvt<<<dim3(128, 128), tb, 0, stream>>>(wq, wqkv_t, 4096, 4096, 4096);
    k_tcvt<<<dim3(32, 128),  tb, 0, stream>>>(wk, wqkv_t + (long)4096 * 4096, 4096, 1024, 4096);
    k_tcvt<<<dim3(32, 128),  tb, 0, stream>>>(wv, wqkv_t + (long)5120 * 4096, 4096, 1024, 4096);
    k_tcvt<<<dim3(128, 128), tb, 0, stream>>>(wo, wo_t, 4096, 4096, 4096);
    k_gemm_qkv<<<dim3(768), 512, 0, stream>>>(hid, wqkv_t, qb, kb, vb);
    k_rope<<<dim3(2 * 32 * 2048 * 32 / 256), 256, 0, stream>>>(qb, cosb, sinb, NH);
    k_rope<<<dim3(2 * 8 * 2048 * 32 / 256), 256, 0, stream>>>(kb, cosb, sinb, NKV);
    k_tv<<<dim3(64, 4, 16), tb, 0, stream>>>(vb, vtb);
    k_attn<<<dim3(1024), 256, 0, stream>>>(qb, kb, vtb, hid);
    k_gemm_out<<<dim3(512), 512, 0, stream>>>(hid, wo_t, out);
}

// Round 9
// 1066.824 us; speedup vs baseline: 1.1016x; 1.1016x over previous
//
#include <hip/hip_runtime.h>

// ============================================================================
// GLM4-MoE attention layer on MI355X (gfx950), fp16 MFMA pipeline.
// Round 9: B-direct v2. r8 regressed because (1) B loads had zero prefetch
// distance and (2) 6MB B-chunks thrashed L2 (FETCH 287->418MB). Fix:
//   - B global->reg prefetched ONE FULL K-TILE ahead (static ping-pong bqA/bqB)
//   - A double-buffered in LDS (2x16KB) with counted vmcnt(2) at tile boundary
//     (issue order B(t+1)x8 ... A(t+2)x2 -> vmcnt(2) retires exactly t+1's data)
//   - L2-sized B panels (r7 mapping kept: 256-row chunk = 2MB/XCD, m-sweep)
//   - k_tv ELIMINATED: GEMM1 epilogue writes V^T directly (packed 8B stores)
// Attention v4 (round-5) and other aux kernels unchanged.
// ============================================================================

typedef _Float16 f16;
typedef _Float16 f16x8 __attribute__((ext_vector_type(8)));
typedef float f32x4 __attribute__((ext_vector_type(4)));

static constexpr int Bn = 2, Sn = 2048, Hn = 4096, NH = 32, NKV = 8, HD = 128;
static constexpr float QSC = 0.08838834764831845f * 1.44269504088896340736f; // 1/sqrt(128)*log2e

#define AS1 __attribute__((address_space(1)))
#define AS3 __attribute__((address_space(3)))

__device__ __forceinline__ void async_ld16(const void* g, void* l) {
    __builtin_amdgcn_global_load_lds((const AS1 void*)g, (AS3 void*)l, 16, 0, 0);
}

__device__ __forceinline__ unsigned pk2(float a, float b) {
    unsigned r;
    asm("v_cvt_pkrtz_f16_f32 %0, %1, %2" : "=v"(r) : "v"(a), "v"(b));
    return r;
}

// native exp2: v_exp_f32 computes 2^x
__device__ __forceinline__ float fexp2(float x) {
    float r;
    asm("v_exp_f32 %0, %1" : "=v"(r) : "v"(x));
    return r;
}

// ---------------------------------------------------------------------------
__global__ void k_cvt(const float* __restrict__ src, f16* __restrict__ dst, long n) {
    long i = ((long)blockIdx.x * blockDim.x + threadIdx.x) * 8;
    if (i >= n) return;
    float4 a = *(const float4*)(src + i);
    float4 b = *(const float4*)(src + i + 4);
    f16x8 o = {(f16)a.x, (f16)a.y, (f16)a.z, (f16)a.w,
               (f16)b.x, (f16)b.y, (f16)b.z, (f16)b.w};
    *(f16x8*)(dst + i) = o;
}

// ---------------------------------------------------------------------------
__global__ void k_tcvt(const float* __restrict__ src, f16* __restrict__ dst,
                       int K, int N, long rs) {
    __shared__ float tile[32][33];
    int k0 = blockIdx.y * 32, n0 = blockIdx.x * 32;
    int tx = threadIdx.x, ty = threadIdx.y;
#pragma unroll
    for (int r = ty; r < 32; r += 8)
        tile[r][tx] = src[(long)(k0 + r) * N + (n0 + tx)];
    __syncthreads();
#pragma unroll
    for (int r = ty; r < 32; r += 8)
        dst[(long)(n0 + r) * rs + (k0 + tx)] = (f16)tile[tx][r];
}

// ---------------------------------------------------------------------------
__global__ void k_rope(f16* __restrict__ x, const float* __restrict__ cosb,
                       const float* __restrict__ sinb, int nheads) {
    long idx = (long)blockIdx.x * blockDim.x + threadIdx.x;
    int i = (int)(idx & 31);
    long t = idx >> 5;
    int s = (int)(t & (Sn - 1));
    int bh = (int)(t >> 11);
    int b = bh / nheads;
    long base = t * HD + 2 * i;
    float c = cosb[((long)b * Sn + s) * 64 + i];
    float sv = sinb[((long)b * Sn + s) * 64 + i];
    float x0 = (float)x[base], x1 = (float)x[base + 1];
    x[base]     = (f16)(x0 * c - x1 * sv);
    x[base + 1] = (f16)(x1 * c + x0 * sv);
}

// ---------------------------------------------------------------------------
// 128x256 GEMM core v3, BK=64, 8 waves (2M x 4N, each 64x64), K=4096 fixed.
// A: LDS double-buffer 2x16KB (swizzled rows, linear gload_lds dest).
// B: global->VGPR, prefetched one K-tile ahead into static ping-pong regs.
// Per tile t: PREF_B(t+1) -> compute(L[t&1], bq[t&1]) -> barrier ->
// STAGE_A(t+2 -> L[t&1]) -> vmcnt(2) -> barrier. Never drains mid-loop.
__device__ __forceinline__ void gemm_core(
    const f16* __restrict__ A, const f16* __restrict__ Bt,
    char* L, int m0, int n0, f32x4 acc[4][4]) {
    const int t = threadIdx.x, lane = t & 63, wave = t >> 6;
    const int wm = wave >> 2, wn = wave & 3;
    const int fr = lane & 15, fg = lane >> 4;

    // A staging sources (linear LDS dest; source col pre-swizzled)
    const f16* gsa[2];
#pragma unroll
    for (int i = 0; i < 2; ++i) {
        int d = i * 8192 + t * 16;
        int row = d >> 7, cb = (d & 127) ^ ((row & 7) << 4);
        gsa[i] = A + (long)(m0 + row) * 4096 + (cb >> 1);
    }
    const int dst0 = wave * 1024;   // wave-uniform; HW adds lane*16

    // B fragment bases: wave-owned 64 rows of B^T, fg picks the 16B chunk
    const f16* gbp[4];
#pragma unroll
    for (int nf = 0; nf < 4; ++nf)
        gbp[nf] = Bt + (long)(n0 + wn * 64 + nf * 16 + fr) * 4096 + fg * 8;

#define STAGE_A(kt, c)                                                  \
    { async_ld16(gsa[0] + (kt) * 64, L + (c) * 16384 + dst0);           \
      async_ld16(gsa[1] + (kt) * 64, L + (c) * 16384 + 8192 + dst0); }

#define PREF_B(dst, kt)                                                 \
    { _Pragma("unroll")                                                 \
      for (int ks = 0; ks < 2; ++ks)                                    \
          _Pragma("unroll")                                             \
          for (int nf = 0; nf < 4; ++nf)                                \
              dst[ks][nf] = *(const f16x8*)(gbp[nf] + (kt) * 64 + ks * 32); }

#define COMPUTE(c, bq)                                                  \
    { _Pragma("unroll")                                                 \
      for (int ks = 0; ks < 2; ++ks) {                                  \
          const int cb = ks * 64 + 16 * fg;                             \
          f16x8 af[4];                                                  \
          _Pragma("unroll")                                             \
          for (int mf = 0; mf < 4; ++mf) {                              \
              int r = wm * 64 + mf * 16 + fr;                           \
              af[mf] = *(const f16x8*)(L + (c) * 16384 + r * 128 +      \
                                       (cb ^ ((r & 7) << 4)));          \
          }                                                             \
          __builtin_amdgcn_s_setprio(1);                                \
          _Pragma("unroll")                                             \
          for (int mf = 0; mf < 4; ++mf)                                \
              _Pragma("unroll")                                         \
              for (int nf = 0; nf < 4; ++nf)                            \
                  acc[mf][nf] = __builtin_amdgcn_mfma_f32_16x16x32_f16( \
                      af[mf], bq[ks][nf], acc[mf][nf], 0, 0, 0);        \
          __builtin_amdgcn_s_setprio(0);                                \
      } }

    f16x8 bqA[2][4], bqB[2][4];

    // prologue: A(0), B(0), A(1) in flight; wait A(0)+B(0) (keep A(1))
    STAGE_A(0, 0);
    PREF_B(bqA, 0);
    STAGE_A(1, 1);
    asm volatile("s_waitcnt vmcnt(2)" ::: "memory");
    __builtin_amdgcn_s_barrier();

    for (int it = 0; it < 32; ++it) {
        const int kt = it * 2;
        // ---- tile kt: buf 0, bqA ----
        PREF_B(bqB, kt + 1);
        COMPUTE(0, bqA);
        __builtin_amdgcn_s_barrier();           // all waves done reading buf 0
        if (kt + 2 < 64) {
            STAGE_A(kt + 2, 0);
            asm volatile("s_waitcnt vmcnt(2)" ::: "memory"); // t+1 data landed
        } else {
            asm volatile("s_waitcnt vmcnt(0)" ::: "memory");
        }
        __builtin_amdgcn_s_barrier();

        // ---- tile kt+1: buf 1, bqB ----
        if (kt + 2 < 64) PREF_B(bqA, kt + 2);
        COMPUTE(1, bqB);
        __builtin_amdgcn_s_barrier();
        if (kt + 3 < 64) {
            STAGE_A(kt + 3, 1);
            asm volatile("s_waitcnt vmcnt(2)" ::: "memory");
        } else {
            asm volatile("s_waitcnt vmcnt(0)" ::: "memory");
        }
        __builtin_amdgcn_s_barrier();
    }
#undef STAGE_A
#undef PREF_B
#undef COMPUTE
}

// GEMM1: hidden[4096][4096] @ Wqkv^T[6144][4096] -> scatter q/k (head layout)
// and V DIRECTLY TRANSPOSED into vt[b][kv][d][s] (packed 8B stores).
__global__ __launch_bounds__(512) void k_gemm_qkv(
    const f16* __restrict__ A, const f16* __restrict__ Bt,
    f16* __restrict__ q, f16* __restrict__ kk_, f16* __restrict__ vt) {
    __shared__ __align__(16) char L[32768];
    const int xcd = blockIdx.x & 7, i = blockIdx.x >> 3;   // i in [0,96)
    const int n0 = (xcd * 3 + (i >> 5)) * 256;
    const int m0 = (i & 31) * 128;
    f32x4 acc[4][4] = {};
    gemm_core(A, Bt, L, m0, n0, acc);

    const int lane = threadIdx.x & 63, wave = threadIdx.x >> 6;
    const int wm = wave >> 2, wn = wave & 3;
    const int fr = lane & 15, fg = lane >> 4;
#pragma unroll
    for (int mf = 0; mf < 4; ++mf) {
        int r0 = m0 + wm * 64 + mf * 16 + 4 * fg;
        int b = r0 >> 11, s = r0 & (Sn - 1);   // r0 multiple of 4: same b, s..s+3
#pragma unroll
        for (int nf = 0; nf < 4; ++nf) {
            int cc = n0 + wn * 64 + nf * 16 + fr;
            int d = cc & 127;
            if (cc < 4096) {
                int h = cc >> 7;
#pragma unroll
                for (int e = 0; e < 4; ++e)
                    q[(((long)b * NH + h) * Sn + s + e) * HD + d] = (f16)(acc[mf][nf][e] * QSC);
            } else if (cc < 5120) {
                int h = (cc - 4096) >> 7;
#pragma unroll
                for (int e = 0; e < 4; ++e)
                    kk_[(((long)b * NKV + h) * Sn + s + e) * HD + d] = (f16)acc[mf][nf][e];
            } else {
                int h = (cc - 5120) >> 7;
                uint2 w = {pk2(acc[mf][nf][0], acc[mf][nf][1]),
                           pk2(acc[mf][nf][2], acc[mf][nf][3])};
                *(uint2*)&vt[(((long)b * NKV + h) * HD + d) * Sn + s] = w;
            }
        }
    }
}

// GEMM2: attn_out[4096][4096] @ wo^T[4096][4096] -> d_out f32, grid 512
__global__ __launch_bounds__(512) void k_gemm_out(
    const f16* __restrict__ A, const f16* __restrict__ Bt,
    float* __restrict__ out) {
    __shared__ __align__(16) char L[32768];
    const int xcd = blockIdx.x & 7, i = blockIdx.x >> 3;   // i in [0,64)
    const int n0 = (xcd * 2 + (i >> 5)) * 256;
    const int m0 = (i & 31) * 128;
    f32x4 acc[4][4] = {};
    gemm_core(A, Bt, L, m0, n0, acc);

    const int lane = threadIdx.x & 63, wave = threadIdx.x >> 6;
    const int wm = wave >> 2, wn = wave & 3;
    const int fr = lane & 15, fg = lane >> 4;
#pragma unroll
    for (int mf = 0; mf < 4; ++mf) {
        int r0 = m0 + wm * 64 + mf * 16 + 4 * fg;
#pragma unroll
        for (int nf = 0; nf < 4; ++nf) {
            int cc = n0 + wn * 64 + nf * 16 + fr;
#pragma unroll
            for (int e = 0; e < 4; ++e)
                out[(long)(r0 + e) * 4096 + cc] = acc[mf][nf][e];
        }
    }
}

// ---------------------------------------------------------------------------
// Flash attention v4 (round-5 proven): swapped QK^T + in-lane softmax +
// defer-rescale, native v_exp, Psm[32][32] 2-phase PV, kvh-grouped grid,
// K/V dbuf + vmcnt(8) + XOR swizzle.

__device__ __forceinline__ f16x8 ld_sw256(const f16* base, int r, int c) {
    int byte = r * 256 + ((c * 2) ^ ((r & 7) << 4));
    return *(const f16x8*)((const char*)base + byte);
}
__device__ __forceinline__ f16x8 ld_sw128(const f16* base, int r, int c) {
    int byte = r * 128 + ((c * 2) ^ ((r & 7) << 4));
    return *(const f16x8*)((const char*)base + byte);
}

__device__ __forceinline__ void stage_k(const f16* __restrict__ Kb, f16* ksm,
                                        int k0, int wave, int lane) {
#pragma unroll
    for (int i = 0; i < 4; ++i) {
        int dbase = (i * 4 + wave) * 1024;
        int d = dbase + lane * 16;
        int row = d >> 8;
        int cb = (d & 255) ^ ((row & 7) << 4);
        async_ld16(Kb + (long)(k0 + row) * HD + (cb >> 1), (char*)ksm + dbase);
    }
}
__device__ __forceinline__ void stage_v(const f16* __restrict__ Vb, f16* vsm,
                                        int k0, int wave, int lane) {
#pragma unroll
    for (int i = 0; i < 4; ++i) {
        int dbase = (i * 4 + wave) * 1024;
        int d = dbase + lane * 16;
        int row = d >> 7;
        int cb = (d & 127) ^ ((row & 7) << 4);
        async_ld16(Vb + (long)row * Sn + k0 + (cb >> 1), (char*)vsm + dbase);
    }
}

__global__ __launch_bounds__(256) void k_attn(
    const f16* __restrict__ Q, const f16* __restrict__ K,
    const f16* __restrict__ Vt, f16* __restrict__ O) {
    __shared__ __align__(16) f16 Ksm[2][64 * 128];
    __shared__ __align__(16) f16 Vsm[2][128 * 64];
    __shared__ __align__(16) f16 Psm[4][32 * 32];

    const int id = blockIdx.x;
    const int kvh = id & 7;
    const int r_ = id >> 3;
    const int qt = 15 - (r_ & 15);
    const int hg = (r_ >> 4) & 3;
    const int b  = r_ >> 6;
    const int h  = kvh * 4 + hg;
    const int q0 = qt * 128;
    const int t = threadIdx.x, lane = t & 63, wave = t >> 6;
    const int q0w = q0 + wave * 32;
    const int fr = lane & 15, fg = lane >> 4;

    const f16* Qb = Q + ((long)(b * NH + h) * Sn) * HD;
    const f16* Kb = K + ((long)(b * NKV + kvh) * Sn) * HD;
    const f16* Vb = Vt + ((long)(b * NKV + kvh) * HD) * Sn;

    f16x8 qf[2][4];
#pragma unroll
    for (int mq = 0; mq < 2; ++mq)
#pragma unroll
        for (int kk = 0; kk < 4; ++kk)
            qf[mq][kk] = *(const f16x8*)&Qb[(long)(q0w + mq * 16 + fr) * HD + kk * 32 + 8 * fg];

    f32x4 oacc[2][8] = {};
    float mrun[2] = {-1e30f, -1e30f};
    float lrun[2] = {0.f, 0.f};

    const int nt = q0 / 64 + 2;
    stage_k(Kb, Ksm[0], 0, wave, lane);
    stage_v(Vb, Vsm[0], 0, wave, lane);

    for (int kt = 0; kt < nt; ++kt) {
        const int k0 = kt * 64;
        const int cur = kt & 1;
        if (kt + 1 < nt) {
            stage_k(Kb, Ksm[cur ^ 1], (kt + 1) * 64, wave, lane);
            stage_v(Vb, Vsm[cur ^ 1], (kt + 1) * 64, wave, lane);
            asm volatile("s_waitcnt vmcnt(8)" ::: "memory");
        } else {
            asm volatile("s_waitcnt vmcnt(0)" ::: "memory");
        }
        __builtin_amdgcn_s_barrier();

        if (k0 <= q0w + 31) {
            f32x4 st[4][2] = {};
#pragma unroll
            for (int kk = 0; kk < 4; ++kk)
#pragma unroll
                for (int nn = 0; nn < 4; ++nn) {
                    f16x8 kf = ld_sw256(Ksm[cur], nn * 16 + fr, kk * 32 + 8 * fg);
#pragma unroll
                    for (int mq = 0; mq < 2; ++mq)
                        st[nn][mq] = __builtin_amdgcn_mfma_f32_16x16x32_f16(
                            kf, qf[mq][kk], st[nn][mq], 0, 0, 0);
                }
            const bool full = (k0 + 63 <= q0w);
            if (!full) {
#pragma unroll
                for (int nn = 0; nn < 4; ++nn)
#pragma unroll
                    for (int mq = 0; mq < 2; ++mq)
#pragma unroll
                        for (int e = 0; e < 4; ++e) {
                            int kv = k0 + 16 * nn + 4 * fg + e;
                            int qq = q0w + 16 * mq + fr;
                            if (kv > qq) st[nn][mq][e] = -1e30f;
                        }
            }
            float pmax[2];
#pragma unroll
            for (int mq = 0; mq < 2; ++mq) {
                float m0v = fmaxf(fmaxf(st[0][mq][0], st[0][mq][1]),
                                  fmaxf(st[0][mq][2], st[0][mq][3]));
#pragma unroll
                for (int nn = 1; nn < 4; ++nn) {
                    float mv = fmaxf(fmaxf(st[nn][mq][0], st[nn][mq][1]),
                                     fmaxf(st[nn][mq][2], st[nn][mq][3]));
                    m0v = fmaxf(m0v, mv);
                }
                m0v = fmaxf(m0v, __shfl_xor(m0v, 16, 64));
                m0v = fmaxf(m0v, __shfl_xor(m0v, 32, 64));
                pmax[mq] = m0v;
            }
            bool need = (pmax[0] > mrun[0] + 8.f) || (pmax[1] > mrun[1] + 8.f);
            if (__any(need)) {
#pragma unroll
                for (int mq = 0; mq < 2; ++mq) {
                    float mn = fmaxf(mrun[mq], pmax[mq]);
                    float sc = fexp2(mrun[mq] - mn);
                    mrun[mq] = mn;
                    lrun[mq] *= sc;
                    float scr[4];
#pragma unroll
                    for (int e = 0; e < 4; ++e)
                        scr[e] = __shfl(sc, (lane & 48) | (4 * fg + e), 64);
#pragma unroll
                    for (int nd = 0; nd < 8; ++nd)
#pragma unroll
                        for (int e = 0; e < 4; ++e)
                            oacc[mq][nd][e] *= scr[e];
                }
            }
#pragma unroll
            for (int ph = 0; ph < 2; ++ph) {
#pragma unroll
                for (int mq = 0; mq < 2; ++mq) {
                    int row = 16 * mq + fr;
                    int rot = ((row >> 1) & 3) << 4;
                    char* pbase = (char*)&Psm[wave][0] + row * 64;
#pragma unroll
                    for (int nh = 0; nh < 2; ++nh) {
                        int nn = 2 * ph + nh;
                        float p0 = fexp2(st[nn][mq][0] - mrun[mq]);
                        float p1 = fexp2(st[nn][mq][1] - mrun[mq]);
                        float p2 = fexp2(st[nn][mq][2] - mrun[mq]);
                        float p3 = fexp2(st[nn][mq][3] - mrun[mq]);
                        lrun[mq] += (p0 + p1) + (p2 + p3);
                        uint2 w = {pk2(p0, p1), pk2(p2, p3)};
                        *(uint2*)(pbase + ((32 * nh + 8 * fg + rot) & 63)) = w;
                    }
                }
                asm volatile("s_waitcnt lgkmcnt(0)" ::: "memory");
                f16x8 pf[2];
#pragma unroll
                for (int mq = 0; mq < 2; ++mq) {
                    int row = 16 * mq + fr;
                    int rot = ((row >> 1) & 3) << 4;
                    pf[mq] = *(const f16x8*)((char*)&Psm[wave][0] + row * 64 +
                                             ((16 * fg + rot) & 63));
                }
#pragma unroll
                for (int nd = 0; nd < 8; ++nd) {
                    f16x8 vf = ld_sw128(Vsm[cur], nd * 16 + fr, ph * 32 + 8 * fg);
#pragma unroll
                    for (int mq = 0; mq < 2; ++mq)
                        oacc[mq][nd] = __builtin_amdgcn_mfma_f32_16x16x32_f16(
                            pf[mq], vf, oacc[mq][nd], 0, 0, 0);
                }
            }
        }
        __builtin_amdgcn_s_barrier();
    }

#pragma unroll
    for (int mq = 0; mq < 2; ++mq) {
        lrun[mq] += __shfl_xor(lrun[mq], 16, 64);
        lrun[mq] += __shfl_xor(lrun[mq], 32, 64);
    }
#pragma unroll
    for (int mq = 0; mq < 2; ++mq) {
        float li = 1.f / lrun[mq];
        float ir[4];
#pragma unroll
        for (int e = 0; e < 4; ++e)
            ir[e] = __shfl(li, (lane & 48) | (4 * fg + e), 64);
#pragma unroll
        for (int nd = 0; nd < 8; ++nd)
#pragma unroll
            for (int e = 0; e < 4; ++e) {
                int srow = q0w + mq * 16 + 4 * fg + e;
                long tok = (long)b * Sn + srow;
                O[tok * (NH * HD) + h * HD + nd * 16 + fr] = (f16)(oacc[mq][nd][e] * ir[e]);
            }
    }
}

// sentinel if workspace too small
__global__ void k_ws_fail(float* out) { out[0] = 1.0e9f; }

// ---------------------------------------------------------------------------
extern "C" void kernel_launch(void* const* d_in, const int* in_sizes, int n_in,
                              void* d_out, int out_size, void* d_ws, size_t ws_size,
                              hipStream_t stream) {
    const float* hs   = (const float*)d_in[0];
    const float* wq   = (const float*)d_in[1];
    const float* wk   = (const float*)d_in[2];
    const float* wv   = (const float*)d_in[3];
    const float* wo   = (const float*)d_in[4];
    const float* cosb = (const float*)d_in[5];
    const float* sinb = (const float*)d_in[6];
    float* out = (float*)d_out;

    const size_t OFF_WQKV = 0;
    const size_t OFF_WO   = 50331648;
    const size_t OFF_HID  = 83886080;
    const size_t OFF_Q    = 117440512;
    const size_t OFF_K    = 150994944;
    const size_t OFF_VT   = 167772160;
    const size_t WS_NEED  = 176160768;
    if (ws_size < WS_NEED) { k_ws_fail<<<1, 1, 0, stream>>>(out); return; }

    char* ws = (char*)d_ws;
    f16* wqkv_t = (f16*)(ws + OFF_WQKV);
    f16* wo_t   = (f16*)(ws + OFF_WO);
    f16* hid    = (f16*)(ws + OFF_HID);
    f16* qb     = (f16*)(ws + OFF_Q);
    f16* kb     = (f16*)(ws + OFF_K);
    f16* vtb    = (f16*)(ws + OFF_VT);

    dim3 tb(32, 8);
    k_cvt<<<dim3(16777216 / (256 * 8)), 256, 0, stream>>>(hs, hid, 16777216L);
    k_tcvt<<<dim3(128, 128), tb, 0, stream>>>(wq, wqkv_t, 4096, 4096, 4096);
    k_tcvt<<<dim3(32, 128),  tb, 0, stream>>>(wk, wqkv_t + (long)4096 * 4096, 4096, 1024, 4096);
    k_tcvt<<<dim3(32, 128),  tb, 0, stream>>>(wv, wqkv_t + (long)5120 * 4096, 4096, 1024, 4096);
    k_tcvt<<<dim3(128, 128), tb, 0, stream>>>(wo, wo_t, 4096, 4096, 4096);
    k_gemm_qkv<<<dim3(768), 512, 0, stream>>>(hid, wqkv_t, qb, kb, vtb);
    k_rope<<<dim3(2 * 32 * 2048 * 32 / 256), 256, 0, stream>>>(qb, cosb, sinb, NH);
    k_rope<<<dim3(2 * 8 * 2048 * 32 / 256), 256, 0, stream>>>(kb, cosb, sinb, NKV);
    k_attn<<<dim3(1024), 256, 0, stream>>>(qb, kb, vtb, hid);
    k_gemm_out<<<dim3(512), 512, 0, stream>>>(hid, wo_t, out);
}

// Round 10
// 645.103 us; speedup vs baseline: 1.8217x; 1.6537x over previous
//
#include <hip/hip_runtime.h>

// ============================================================================
// GLM4-MoE attention layer on MI355X (gfx950), fp16 MFMA pipeline.
// Round 10:
//   - GEMMs reverted to the r7 plateau structure (4 escape attempts r6-r9 all
//     neutral/regressed): 128x256, BK=64, single-buffer 48KB LDS, 2-3 blk/CU.
//   - GEMM1 epilogue writes V^T directly (r9-proven) -> k_tv eliminated.
//   - Attention v5: 32x32x16 MFMAs, P fully in-register (no Psm, no P-stalls):
//     swapped QK^T C-layout (col=lane&31=q) -> softmax in-lane; P A-fragments
//     assembled via v_cvt_pkrtz + one shfl_xor(32) per kstep (T12 pattern).
//     LDS 64KB (K/V dbuf only), ~32 b128 LDS ops/tile (was ~56 + 2 stalls).
// ============================================================================

typedef _Float16 f16;
typedef _Float16 f16x8 __attribute__((ext_vector_type(8)));
typedef float f32x4 __attribute__((ext_vector_type(4)));
typedef float f32x16 __attribute__((ext_vector_type(16)));

static constexpr int Bn = 2, Sn = 2048, Hn = 4096, NH = 32, NKV = 8, HD = 128;
static constexpr float QSC = 0.08838834764831845f * 1.44269504088896340736f; // 1/sqrt(128)*log2e

#define AS1 __attribute__((address_space(1)))
#define AS3 __attribute__((address_space(3)))

__device__ __forceinline__ void async_ld16(const void* g, void* l) {
    __builtin_amdgcn_global_load_lds((const AS1 void*)g, (AS3 void*)l, 16, 0, 0);
}

__device__ __forceinline__ unsigned pk2(float a, float b) {
    unsigned r;
    asm("v_cvt_pkrtz_f16_f32 %0, %1, %2" : "=v"(r) : "v"(a), "v"(b));
    return r;
}

// native exp2: v_exp_f32 computes 2^x
__device__ __forceinline__ float fexp2(float x) {
    float r;
    asm("v_exp_f32 %0, %1" : "=v"(r) : "v"(x));
    return r;
}

// ---------------------------------------------------------------------------
__global__ void k_cvt(const float* __restrict__ src, f16* __restrict__ dst, long n) {
    long i = ((long)blockIdx.x * blockDim.x + threadIdx.x) * 8;
    if (i >= n) return;
    float4 a = *(const float4*)(src + i);
    float4 b = *(const float4*)(src + i + 4);
    f16x8 o = {(f16)a.x, (f16)a.y, (f16)a.z, (f16)a.w,
               (f16)b.x, (f16)b.y, (f16)b.z, (f16)b.w};
    *(f16x8*)(dst + i) = o;
}

// ---------------------------------------------------------------------------
__global__ void k_tcvt(const float* __restrict__ src, f16* __restrict__ dst,
                       int K, int N, long rs) {
    __shared__ float tile[32][33];
    int k0 = blockIdx.y * 32, n0 = blockIdx.x * 32;
    int tx = threadIdx.x, ty = threadIdx.y;
#pragma unroll
    for (int r = ty; r < 32; r += 8)
        tile[r][tx] = src[(long)(k0 + r) * N + (n0 + tx)];
    __syncthreads();
#pragma unroll
    for (int r = ty; r < 32; r += 8)
        dst[(long)(n0 + r) * rs + (k0 + tx)] = (f16)tile[tx][r];
}

// ---------------------------------------------------------------------------
__global__ void k_rope(f16* __restrict__ x, const float* __restrict__ cosb,
                       const float* __restrict__ sinb, int nheads) {
    long idx = (long)blockIdx.x * blockDim.x + threadIdx.x;
    int i = (int)(idx & 31);
    long t = idx >> 5;
    int s = (int)(t & (Sn - 1));
    int bh = (int)(t >> 11);
    int b = bh / nheads;
    long base = t * HD + 2 * i;
    float c = cosb[((long)b * Sn + s) * 64 + i];
    float sv = sinb[((long)b * Sn + s) * 64 + i];
    float x0 = (float)x[base], x1 = (float)x[base + 1];
    x[base]     = (f16)(x0 * c - x1 * sv);
    x[base + 1] = (f16)(x1 * c + x0 * sv);
}

// ---------------------------------------------------------------------------
// 128x256 GEMM core (r7-proven), BK=64, 8 waves (2M x 4N, each 64x64), K=4096.
// Single-buffer LDS 48KB: A [128][64] at 0, B [256][64] at 16384; rows 128B,
// swizzled byte cb ^ ((r&7)<<4); staging keeps LDS dest linear and
// inverse-swizzles the global source. Per K-tile: STAGE(6) -> syncthreads
// -> 32 MFMA -> syncthreads. Cross-block TLP hides the stage drain.
__device__ __forceinline__ void gemm_core(
    const f16* __restrict__ A, const f16* __restrict__ Bt,
    char* L, int m0, int n0, f32x4 acc[4][4]) {
    const int t = threadIdx.x, lane = t & 63, wave = t >> 6;
    const int wm = wave >> 2, wn = wave & 3;
    const int fr = lane & 15, fg = lane >> 4;

    const f16* gsa[2];
    const f16* gsb[4];
#pragma unroll
    for (int i = 0; i < 2; ++i) {
        int d = i * 8192 + t * 16;
        int row = d >> 7, cb = (d & 127) ^ ((row & 7) << 4);
        gsa[i] = A + (long)(m0 + row) * 4096 + (cb >> 1);
    }
#pragma unroll
    for (int i = 0; i < 4; ++i) {
        int d = i * 8192 + t * 16;
        int row = d >> 7, cb = (d & 127) ^ ((row & 7) << 4);
        gsb[i] = Bt + (long)(n0 + row) * 4096 + (cb >> 1);
    }
    const int dst0 = wave * 1024;

    for (int kt = 0; kt < 64; ++kt) {
        const int ko = kt * 64;
#pragma unroll
        for (int i = 0; i < 2; ++i)
            async_ld16(gsa[i] + ko, L + i * 8192 + dst0);
#pragma unroll
        for (int i = 0; i < 4; ++i)
            async_ld16(gsb[i] + ko, L + 16384 + i * 8192 + dst0);
        __syncthreads();

#pragma unroll
        for (int ks = 0; ks < 2; ++ks) {
            const int cb = ks * 64 + 16 * fg;
            f16x8 bf[4], af[4];
#pragma unroll
            for (int nf = 0; nf < 4; ++nf) {
                int r = wn * 64 + nf * 16 + fr;
                bf[nf] = *(const f16x8*)(L + 16384 + r * 128 + (cb ^ ((r & 7) << 4)));
            }
#pragma unroll
            for (int mf = 0; mf < 4; ++mf) {
                int r = wm * 64 + mf * 16 + fr;
                af[mf] = *(const f16x8*)(L + r * 128 + (cb ^ ((r & 7) << 4)));
            }
            __builtin_amdgcn_s_setprio(1);
#pragma unroll
            for (int mf = 0; mf < 4; ++mf)
#pragma unroll
                for (int nf = 0; nf < 4; ++nf)
                    acc[mf][nf] = __builtin_amdgcn_mfma_f32_16x16x32_f16(
                        af[mf], bf[nf], acc[mf][nf], 0, 0, 0);
            __builtin_amdgcn_s_setprio(0);
        }
        __syncthreads();
    }
}

// GEMM1: hidden @ Wqkv^T -> q (pre-scaled), k (head layout), V^T (fused).
__global__ __launch_bounds__(512, 4) void k_gemm_qkv(
    const f16* __restrict__ A, const f16* __restrict__ Bt,
    f16* __restrict__ q, f16* __restrict__ kk_, f16* __restrict__ vt) {
    __shared__ __align__(16) char L[49152];
    const int xcd = blockIdx.x & 7, i = blockIdx.x >> 3;   // i in [0,96)
    const int n0 = (xcd * 3 + (i >> 5)) * 256;
    const int m0 = (i & 31) * 128;
    f32x4 acc[4][4] = {};
    gemm_core(A, Bt, L, m0, n0, acc);

    const int lane = threadIdx.x & 63, wave = threadIdx.x >> 6;
    const int wm = wave >> 2, wn = wave & 3;
    const int fr = lane & 15, fg = lane >> 4;
#pragma unroll
    for (int mf = 0; mf < 4; ++mf) {
        int r0 = m0 + wm * 64 + mf * 16 + 4 * fg;
        int b = r0 >> 11, s = r0 & (Sn - 1);   // r0 multiple of 4: same b, s..s+3
#pragma unroll
        for (int nf = 0; nf < 4; ++nf) {
            int cc = n0 + wn * 64 + nf * 16 + fr;
            int d = cc & 127;
            if (cc < 4096) {
                int h = cc >> 7;
#pragma unroll
                for (int e = 0; e < 4; ++e)
                    q[(((long)b * NH + h) * Sn + s + e) * HD + d] = (f16)(acc[mf][nf][e] * QSC);
            } else if (cc < 5120) {
                int h = (cc - 4096) >> 7;
#pragma unroll
                for (int e = 0; e < 4; ++e)
                    kk_[(((long)b * NKV + h) * Sn + s + e) * HD + d] = (f16)acc[mf][nf][e];
            } else {
                int h = (cc - 5120) >> 7;
                uint2 w = {pk2(acc[mf][nf][0], acc[mf][nf][1]),
                           pk2(acc[mf][nf][2], acc[mf][nf][3])};
                *(uint2*)&vt[(((long)b * NKV + h) * HD + d) * Sn + s] = w;
            }
        }
    }
}

// GEMM2: attn_out @ wo^T -> d_out f32, grid 512 = 2 blocks/CU.
__global__ __launch_bounds__(512, 4) void k_gemm_out(
    const f16* __restrict__ A, const f16* __restrict__ Bt,
    float* __restrict__ out) {
    __shared__ __align__(16) char L[49152];
    const int xcd = blockIdx.x & 7, i = blockIdx.x >> 3;   // i in [0,64)
    const int n0 = (xcd * 2 + (i >> 5)) * 256;
    const int m0 = (i & 31) * 128;
    f32x4 acc[4][4] = {};
    gemm_core(A, Bt, L, m0, n0, acc);

    const int lane = threadIdx.x & 63, wave = threadIdx.x >> 6;
    const int wm = wave >> 2, wn = wave & 3;
    const int fr = lane & 15, fg = lane >> 4;
#pragma unroll
    for (int mf = 0; mf < 4; ++mf) {
        int r0 = m0 + wm * 64 + mf * 16 + 4 * fg;
#pragma unroll
        for (int nf = 0; nf < 4; ++nf) {
            int cc = n0 + wn * 64 + nf * 16 + fr;
#pragma unroll
            for (int e = 0; e < 4; ++e)
                out[(long)(r0 + e) * 4096 + cc] = acc[mf][nf][e];
        }
    }
}

// ---------------------------------------------------------------------------
// Flash attention v5: 32x32x16 MFMA, in-register P, no Psm.
// Layouts (32x32x16, assumed A/B analog of verified 16x16x32; C verified):
//   A: row=lane&31, k=8*(lane>>5)+e     B: k=8*(lane>>5)+e, col=lane&31
//   C: col=lane&31, row=(reg&3)+8*(reg>>2)+4*(lane>>5)
// QK^T swapped (S^T = K·Q^T): q = col = lane&31 -> softmax in-lane.
// PV: O = P·V with P as A (q=lane&31 matches), V^T rows as B.

__device__ __forceinline__ f16x8 ld_sw256(const f16* base, int r, int c) {
    int byte = r * 256 + ((c * 2) ^ ((r & 7) << 4));
    return *(const f16x8*)((const char*)base + byte);
}
__device__ __forceinline__ f16x8 ld_sw128(const f16* base, int r, int c) {
    int byte = r * 128 + ((c * 2) ^ ((r & 7) << 4));
    return *(const f16x8*)((const char*)base + byte);
}

__device__ __forceinline__ void stage_k(const f16* __restrict__ Kb, f16* ksm,
                                        int k0, int wave, int lane) {
#pragma unroll
    for (int i = 0; i < 4; ++i) {
        int dbase = (i * 4 + wave) * 1024;
        int d = dbase + lane * 16;
        int row = d >> 8;
        int cb = (d & 255) ^ ((row & 7) << 4);
        async_ld16(Kb + (long)(k0 + row) * HD + (cb >> 1), (char*)ksm + dbase);
    }
}
__device__ __forceinline__ void stage_v(const f16* __restrict__ Vb, f16* vsm,
                                        int k0, int wave, int lane) {
#pragma unroll
    for (int i = 0; i < 4; ++i) {
        int dbase = (i * 4 + wave) * 1024;
        int d = dbase + lane * 16;
        int row = d >> 7;
        int cb = (d & 127) ^ ((row & 7) << 4);
        async_ld16(Vb + (long)row * Sn + k0 + (cb >> 1), (char*)vsm + dbase);
    }
}

__global__ __launch_bounds__(256) void k_attn(
    const f16* __restrict__ Q, const f16* __restrict__ K,
    const f16* __restrict__ Vt, f16* __restrict__ O) {
    __shared__ __align__(16) f16 Ksm[2][64 * 128];   // 32KB
    __shared__ __align__(16) f16 Vsm[2][128 * 64];   // 32KB

    const int id = blockIdx.x;
    const int kvh = id & 7;
    const int r_ = id >> 3;
    const int qt = 15 - (r_ & 15);          // heavy-first within kvh group
    const int hg = (r_ >> 4) & 3;
    const int b  = r_ >> 6;
    const int h  = kvh * 4 + hg;
    const int q0 = qt * 128;
    const int t = threadIdx.x, lane = t & 63, wave = t >> 6;
    const int q0w = q0 + wave * 32;
    const int lq = lane & 31, hi = lane >> 5;

    const f16* Qb = Q + ((long)(b * NH + h) * Sn) * HD;
    const f16* Kb = K + ((long)(b * NKV + kvh) * Sn) * HD;
    const f16* Vb = Vt + ((long)(b * NKV + kvh) * HD) * Sn;

    // Q B-fragments: qf[s] = Q[q0w+lq][16s+8hi .. +7], s=0..7 (d = 128)
    f16x8 qf[8];
#pragma unroll
    for (int s = 0; s < 8; ++s)
        qf[s] = *(const f16x8*)&Qb[(long)(q0w + lq) * HD + 16 * s + 8 * hi];

    f32x16 oacc[4] = {};
    float mrun = -1e30f, lrun = 0.f;

    const int nt = q0 / 64 + 2;
    stage_k(Kb, Ksm[0], 0, wave, lane);
    stage_v(Vb, Vsm[0], 0, wave, lane);

    for (int kt = 0; kt < nt; ++kt) {
        const int k0 = kt * 64;
        const int cur = kt & 1;
        if (kt + 1 < nt) {
            stage_k(Kb, Ksm[cur ^ 1], (kt + 1) * 64, wave, lane);
            stage_v(Vb, Vsm[cur ^ 1], (kt + 1) * 64, wave, lane);
            asm volatile("s_waitcnt vmcnt(8)" ::: "memory");
        } else {
            asm volatile("s_waitcnt vmcnt(0)" ::: "memory");
        }
        __builtin_amdgcn_s_barrier();

        if (k0 <= q0w + 31) {
            // ---- S^T = K . Q^T, 2 kv-tiles of 32, K-dim d=128 in 8 steps
            f32x16 st[2] = {};
#pragma unroll
            for (int s = 0; s < 8; ++s) {
                f16x8 kf0 = ld_sw256(Ksm[cur], lq,      16 * s + 8 * hi);
                f16x8 kf1 = ld_sw256(Ksm[cur], 32 + lq, 16 * s + 8 * hi);
                st[0] = __builtin_amdgcn_mfma_f32_32x32x16_f16(kf0, qf[s], st[0], 0, 0, 0);
                st[1] = __builtin_amdgcn_mfma_f32_32x32x16_f16(kf1, qf[s], st[1], 0, 0, 0);
            }
            // ---- causal mask (diagonal tile only)
            const bool full = (k0 + 63 <= q0w);
            if (!full) {
#pragma unroll
                for (int mt = 0; mt < 2; ++mt)
#pragma unroll
                    for (int r = 0; r < 16; ++r) {
                        int kvv = k0 + 32 * mt + (r & 3) + 8 * (r >> 2) + 4 * hi;
                        if (kvv > q0w + lq) st[mt][r] = -1e30f;
                    }
            }
            // ---- row max: 31 in-lane fmax + 1 cross-half shfl
            float pm = st[0][0];
#pragma unroll
            for (int r = 1; r < 16; ++r) pm = fmaxf(pm, st[0][r]);
#pragma unroll
            for (int r = 0; r < 16; ++r) pm = fmaxf(pm, st[1][r]);
            pm = fmaxf(pm, __shfl_xor(pm, 32, 64));
            // ---- defer-rescale (T13)
            if (__any(pm > mrun + 8.f)) {
                float mn = fmaxf(mrun, pm);
                float sc = fexp2(mrun - mn);
                mrun = mn;
                lrun *= sc;
                float scr[16];
#pragma unroll
                for (int r = 0; r < 16; ++r)
                    scr[r] = __shfl(sc, (r & 3) + 8 * (r >> 2) + 4 * hi, 64);
#pragma unroll
                for (int db = 0; db < 4; ++db)
#pragma unroll
                    for (int r = 0; r < 16; ++r)
                        oacc[db][r] *= scr[r];
            }
            // ---- P = exp2(st - mrun), packed to f16 pairs in-register
            unsigned pw[2][8];
#pragma unroll
            for (int mt = 0; mt < 2; ++mt)
#pragma unroll
                for (int i = 0; i < 8; ++i) {
                    float p0 = fexp2(st[mt][2 * i]     - mrun);
                    float p1 = fexp2(st[mt][2 * i + 1] - mrun);
                    lrun += p0 + p1;
                    pw[mt][i] = pk2(p0, p1);
                }
            // ---- PV: O += P(32q x 64kv) . V(64kv x 128d), 4 ksteps x 4 d-blocks
#pragma unroll
            for (int s = 0; s < 4; ++s) {
                const int mt = s >> 1, sl = s & 1;
                unsigned a0 = pw[mt][4 * sl], a1 = pw[mt][4 * sl + 1];
                unsigned a2 = pw[mt][4 * sl + 2], a3 = pw[mt][4 * sl + 3];
                unsigned own0 = hi ? a2 : a0, own1 = hi ? a3 : a1;
                unsigned snd0 = hi ? a0 : a2, snd1 = hi ? a1 : a3;
                unsigned rx0 = (unsigned)__shfl_xor((int)snd0, 32, 64);
                unsigned rx1 = (unsigned)__shfl_xor((int)snd1, 32, 64);
                union { unsigned u[4]; f16x8 v; } pu;
                pu.u[0] = hi ? rx0 : own0;
                pu.u[1] = hi ? rx1 : own1;
                pu.u[2] = hi ? own0 : rx0;
                pu.u[3] = hi ? own1 : rx1;
#pragma unroll
                for (int db = 0; db < 4; ++db) {
                    f16x8 vf = ld_sw128(Vsm[cur], 32 * db + lq, 16 * s + 8 * hi);
                    oacc[db] = __builtin_amdgcn_mfma_f32_32x32x16_f16(pu.v, vf, oacc[db], 0, 0, 0);
                }
            }
        }
        __builtin_amdgcn_s_barrier();
    }

    // ---- epilogue: merge l across halves, redistribute 1/l by q-row, store
    lrun += __shfl_xor(lrun, 32, 64);
    float li = 1.f / lrun;
    float ir[16];
#pragma unroll
    for (int r = 0; r < 16; ++r)
        ir[r] = __shfl(li, (r & 3) + 8 * (r >> 2) + 4 * hi, 64);
#pragma unroll
    for (int db = 0; db < 4; ++db)
#pragma unroll
        for (int r = 0; r < 16; ++r) {
            int qloc = (r & 3) + 8 * (r >> 2) + 4 * hi;
            long tok = (long)b * Sn + q0w + qloc;
            O[tok * (NH * HD) + h * HD + 32 * db + lq] = (f16)(oacc[db][r] * ir[r]);
        }
}

// sentinel if workspace too small
__global__ void k_ws_fail(float* out) { out[0] = 1.0e9f; }

// ---------------------------------------------------------------------------
extern "C" void kernel_launch(void* const* d_in, const int* in_sizes, int n_in,
                              void* d_out, int out_size, void* d_ws, size_t ws_size,
                              hipStream_t stream) {
    const float* hs   = (const float*)d_in[0];
    const float* wq   = (const float*)d_in[1];
    const float* wk   = (const float*)d_in[2];
    const float* wv   = (const float*)d_in[3];
    const float* wo   = (const float*)d_in[4];
    const float* cosb = (const float*)d_in[5];
    const float* sinb = (const float*)d_in[6];
    float* out = (float*)d_out;

    const size_t OFF_WQKV = 0;
    const size_t OFF_WO   = 50331648;
    const size_t OFF_HID  = 83886080;
    const size_t OFF_Q    = 117440512;
    const size_t OFF_K    = 150994944;
    const size_t OFF_VT   = 167772160;
    const size_t WS_NEED  = 176160768;
    if (ws_size < WS_NEED) { k_ws_fail<<<1, 1, 0, stream>>>(out); return; }

    char* ws = (char*)d_ws;
    f16* wqkv_t = (f16*)(ws + OFF_WQKV);
    f16* wo_t   = (f16*)(ws + OFF_WO);
    f16* hid    = (f16*)(ws + OFF_HID);
    f16* qb     = (f16*)(ws + OFF_Q);
    f16* kb     = (f16*)(ws + OFF_K);
    f16* vtb    = (f16*)(ws + OFF_VT);

    dim3 tb(32, 8);
    k_cvt<<<dim3(16777216 / (256 * 8)), 256, 0, stream>>>(hs, hid, 16777216L);
    k_tcvt<<<dim3(128, 128), tb, 0, stream>>>(wq, wqkv_t, 4096, 4096, 4096);
    k_tcvt<<<dim3(32, 128),  tb, 0, stream>>>(wk, wqkv_t + (long)4096 * 4096, 4096, 1024, 4096);
    k_tcvt<<<dim3(32, 128),  tb, 0, stream>>>(wv, wqkv_t + (long)5120 * 4096, 4096, 1024, 4096);
    k_tcvt<<<dim3(128, 128), tb, 0, stream>>>(wo, wo_t, 4096, 4096, 4096);
    k_gemm_qkv<<<dim3(768), 512, 0, stream>>>(hid, wqkv_t, qb, kb, vtb);
    k_rope<<<dim3(2 * 32 * 2048 * 32 / 256), 256, 0, stream>>>(qb, cosb, sinb, NH);
    k_rope<<<dim3(2 * 8 * 2048 * 32 / 256), 256, 0, stream>>>(kb, cosb, sinb, NKV);
    k_attn<<<dim3(1024), 256, 0, stream>>>(qb, kb, vtb, hid);
    k_gemm_out<<<dim3(512), 512, 0, stream>>>(hid, wo_t, out);
}

// Round 11
// 627.787 us; speedup vs baseline: 1.8720x; 1.0276x over previous
//
#include <hip/hip_runtime.h>

// ============================================================================
// GLM4-MoE attention layer on MI355X (gfx950), fp16 MFMA pipeline.
// Round 11: GEMM = faithful 8-phase/counted-vmcnt template (m201-class).
// Key insight from r4-r7 nulls: r4 was 8-phase+drain0 (documented failure),
// r6 was counted-vmcnt+coarse (documented failure). This round combines
// per-phase {ds_read || stage-1-half-tile || 16 MFMA} with vmcnt(6) once per
// K-tile (never 0 mid-loop). Staging dead-region ledger:
//   buf[c] tile t: B dead after ph0; A rows[0,64)+[128,192) dead after ph1.
//   ph0 stages t+1:A-hi -> buf[c^1] (dead since t-1); ph1/2 stage t+2:B0/B1
//   -> buf[c].B; ph3 stages t+2:A-lo -> buf[c].A (disjoint from ph3 reads).
//   vmcnt(6) after ph3 MFMA retires exactly tile t+1 (8 loads), keeps t+2's
//   6 in flight. Tail: t==62 -> vmcnt(0), t==63 -> none.
// Attention v5 (r10-proven, 32x32 MFMA + in-register P) and aux unchanged.
// ============================================================================

typedef _Float16 f16;
typedef _Float16 f16x8 __attribute__((ext_vector_type(8)));
typedef float f32x4 __attribute__((ext_vector_type(4)));
typedef float f32x16 __attribute__((ext_vector_type(16)));

static constexpr int Bn = 2, Sn = 2048, Hn = 4096, NH = 32, NKV = 8, HD = 128;
static constexpr float QSC = 0.08838834764831845f * 1.44269504088896340736f; // 1/sqrt(128)*log2e

#define AS1 __attribute__((address_space(1)))
#define AS3 __attribute__((address_space(3)))

__device__ __forceinline__ void async_ld16(const void* g, void* l) {
    __builtin_amdgcn_global_load_lds((const AS1 void*)g, (AS3 void*)l, 16, 0, 0);
}

__device__ __forceinline__ unsigned pk2(float a, float b) {
    unsigned r;
    asm("v_cvt_pkrtz_f16_f32 %0, %1, %2" : "=v"(r) : "v"(a), "v"(b));
    return r;
}

// native exp2: v_exp_f32 computes 2^x
__device__ __forceinline__ float fexp2(float x) {
    float r;
    asm("v_exp_f32 %0, %1" : "=v"(r) : "v"(x));
    return r;
}

// ---------------------------------------------------------------------------
__global__ void k_cvt(const float* __restrict__ src, f16* __restrict__ dst, long n) {
    long i = ((long)blockIdx.x * blockDim.x + threadIdx.x) * 8;
    if (i >= n) return;
    float4 a = *(const float4*)(src + i);
    float4 b = *(const float4*)(src + i + 4);
    f16x8 o = {(f16)a.x, (f16)a.y, (f16)a.z, (f16)a.w,
               (f16)b.x, (f16)b.y, (f16)b.z, (f16)b.w};
    *(f16x8*)(dst + i) = o;
}

// ---------------------------------------------------------------------------
__global__ void k_tcvt(const float* __restrict__ src, f16* __restrict__ dst,
                       int K, int N, long rs) {
    __shared__ float tile[32][33];
    int k0 = blockIdx.y * 32, n0 = blockIdx.x * 32;
    int tx = threadIdx.x, ty = threadIdx.y;
#pragma unroll
    for (int r = ty; r < 32; r += 8)
        tile[r][tx] = src[(long)(k0 + r) * N + (n0 + tx)];
    __syncthreads();
#pragma unroll
    for (int r = ty; r < 32; r += 8)
        dst[(long)(n0 + r) * rs + (k0 + tx)] = (f16)tile[tx][r];
}

// ---------------------------------------------------------------------------
__global__ void k_rope(f16* __restrict__ x, const float* __restrict__ cosb,
                       const float* __restrict__ sinb, int nheads) {
    long idx = (long)blockIdx.x * blockDim.x + threadIdx.x;
    int i = (int)(idx & 31);
    long t = idx >> 5;
    int s = (int)(t & (Sn - 1));
    int bh = (int)(t >> 11);
    int b = bh / nheads;
    long base = t * HD + 2 * i;
    float c = cosb[((long)b * Sn + s) * 64 + i];
    float sv = sinb[((long)b * Sn + s) * 64 + i];
    float x0 = (float)x[base], x1 = (float)x[base + 1];
    x[base]     = (f16)(x0 * c - x1 * sv);
    x[base + 1] = (f16)(x1 * c + x0 * sv);
}

// ---------------------------------------------------------------------------
// 256x256 GEMM core, BK=64, 8 waves (2M x 4N, per-wave 128x64), K=4096.
// LDS 128KB: buf c at c*65536, A [256 rows][128B] at +0, B at +32768.
// Rows swizzled: logical colbyte cb at byte cb ^ ((row&7)<<4).
__device__ __forceinline__ void gemm256_core(
    const f16* __restrict__ A, const f16* __restrict__ Bt,
    char* L, int m0, int n0, f32x4 acc[8][4]) {
    const int t = threadIdx.x, lane = t & 63, wave = t >> 6;
    const int wm = wave >> 2, wn = wave & 3;
    const int fr = lane & 15, fg = lane >> 4;

    // staging: one gload_lds per wave = 1KB = 8 rows; row%8 == lane>>3, so
    // the inverse-swizzled source col is row0-independent.
    const int srowL = wave * 8 + (lane >> 3);
    const int scol  = 8 * ((lane & 7) ^ (lane >> 3));
    const f16* ga = A  + (long)(m0 + srowL) * 4096 + scol;
    const f16* gb = Bt + (long)(n0 + srowL) * 4096 + scol;
    const int woff = wave * 1024;

    // stage 64 rows [row0,row0+64) of region sel (0=A,1=B), K-tile kt, buf c
    auto ST = [&](int sel, int c, int row0, int kt) {
        const f16* g = sel ? gb : ga;
        async_ld16(g + (long)row0 * 4096 + kt * 64,
                   L + c * 65536 + sel * 32768 + row0 * 128 + woff);
    };

    // prologue: tile0 complete (8 loads), tile1 B-all + A rows[0,64)+[128,192)
    ST(0, 0, 0, 0);   ST(0, 0, 64, 0);  ST(0, 0, 128, 0); ST(0, 0, 192, 0);
    ST(1, 0, 0, 0);   ST(1, 0, 64, 0);  ST(1, 0, 128, 0); ST(1, 0, 192, 0);
    ST(1, 1, 0, 1);   ST(1, 1, 64, 1);  ST(1, 1, 128, 1); ST(1, 1, 192, 1);
    ST(0, 1, 0, 1);   ST(0, 1, 128, 1);
    asm volatile("s_waitcnt vmcnt(6)" ::: "memory");  // tile0 landed; 6 in flight
    __builtin_amdgcn_s_barrier();

    const int abase = wm * 128;
    const int bbase = wn * 64;

    for (int tt = 0; tt < 64; ++tt) {
        const int c = tt & 1;
        const char* bufA = L + c * 65536;
        const char* bufB = bufA + 32768;
        f16x8 bf[2][4];

#pragma unroll
        for (int q = 0; q < 4; ++q) {
            // ---- ds_read: A quadrant q (4); phase 0 also all B-frags (8)
            if (q == 0) {
#pragma unroll
                for (int ks = 0; ks < 2; ++ks)
#pragma unroll
                    for (int nf = 0; nf < 4; ++nf) {
                        int r = bbase + nf * 16 + fr;
                        bf[ks][nf] = *(const f16x8*)(bufB + r * 128 +
                                        ((ks * 64 + 16 * fg) ^ ((r & 7) << 4)));
                    }
            }
            f16x8 af[2][2];
#pragma unroll
            for (int ks = 0; ks < 2; ++ks)
#pragma unroll
                for (int i = 0; i < 2; ++i) {
                    int r = abase + (2 * q + i) * 16 + fr;
                    af[ks][i] = *(const f16x8*)(bufA + r * 128 +
                                    ((ks * 64 + 16 * fg) ^ ((r & 7) << 4)));
                }
            // ---- stage one half-tile (dead-region ledger in header)
            if (q == 0) { if (tt + 1 < 64) { ST(0, c ^ 1,  64, tt + 1);
                                             ST(0, c ^ 1, 192, tt + 1); } }
            if (q == 1) { if (tt + 2 < 64) { ST(1, c,   0, tt + 2);
                                             ST(1, c,  64, tt + 2); } }
            if (q == 2) { if (tt + 2 < 64) { ST(1, c, 128, tt + 2);
                                             ST(1, c, 192, tt + 2); } }
            if (q == 3) { if (tt + 2 < 64) { ST(0, c,   0, tt + 2);
                                             ST(0, c, 128, tt + 2); } }
            __builtin_amdgcn_s_barrier();
            // ---- 16 MFMA (quadrant q x K=64)
            __builtin_amdgcn_s_setprio(1);
#pragma unroll
            for (int ks = 0; ks < 2; ++ks)
#pragma unroll
                for (int i = 0; i < 2; ++i)
#pragma unroll
                    for (int nf = 0; nf < 4; ++nf)
                        acc[2 * q + i][nf] = __builtin_amdgcn_mfma_f32_16x16x32_f16(
                            af[ks][i], bf[ks][nf], acc[2 * q + i][nf], 0, 0, 0);
            __builtin_amdgcn_s_setprio(0);
            // ---- once per K-tile: counted drain (never 0 mid-loop)
            if (q == 3) {
                if (tt < 62)       asm volatile("s_waitcnt vmcnt(6)" ::: "memory");
                else if (tt == 62) asm volatile("s_waitcnt vmcnt(0)" ::: "memory");
            }
            __builtin_amdgcn_s_barrier();
        }
    }
}

// GEMM1: hidden @ Wqkv^T -> q (pre-scaled), k (head layout), V^T (fused).
__global__ __launch_bounds__(512) void k_gemm_qkv(
    const f16* __restrict__ A, const f16* __restrict__ Bt,
    f16* __restrict__ q, f16* __restrict__ kk_, f16* __restrict__ vt) {
    __shared__ __align__(16) char L[131072];
    const int bid = blockIdx.x;                    // 384 = 16m x 24n
    const int swzb = (bid & 7) * 48 + (bid >> 3);  // XCD-bijective
    const int m0 = (swzb / 24) * 256, n0 = (swzb % 24) * 256;
    f32x4 acc[8][4] = {};
    gemm256_core(A, Bt, L, m0, n0, acc);

    const int lane = threadIdx.x & 63, wave = threadIdx.x >> 6;
    const int wm = wave >> 2, wn = wave & 3;
    const int fr = lane & 15, fg = lane >> 4;
#pragma unroll
    for (int mf = 0; mf < 8; ++mf) {
        int r0 = m0 + wm * 128 + mf * 16 + 4 * fg;
        int b = r0 >> 11, s = r0 & (Sn - 1);   // r0 multiple of 4: same b, s..s+3
#pragma unroll
        for (int nf = 0; nf < 4; ++nf) {
            int cc = n0 + wn * 64 + nf * 16 + fr;
            int d = cc & 127;
            if (cc < 4096) {
                int h = cc >> 7;
#pragma unroll
                for (int e = 0; e < 4; ++e)
                    q[(((long)b * NH + h) * Sn + s + e) * HD + d] = (f16)(acc[mf][nf][e] * QSC);
            } else if (cc < 5120) {
                int h = (cc - 4096) >> 7;
#pragma unroll
                for (int e = 0; e < 4; ++e)
                    kk_[(((long)b * NKV + h) * Sn + s + e) * HD + d] = (f16)acc[mf][nf][e];
            } else {
                int h = (cc - 5120) >> 7;
                uint2 w = {pk2(acc[mf][nf][0], acc[mf][nf][1]),
                           pk2(acc[mf][nf][2], acc[mf][nf][3])};
                *(uint2*)&vt[(((long)b * NKV + h) * HD + d) * Sn + s] = w;
            }
        }
    }
}

// GEMM2: attn_out @ wo^T -> d_out f32, 256 blocks (16x16)
__global__ __launch_bounds__(512) void k_gemm_out(
    const f16* __restrict__ A, const f16* __restrict__ Bt,
    float* __restrict__ out) {
    __shared__ __align__(16) char L[131072];
    const int bid = blockIdx.x;
    const int swzb = (bid & 7) * 32 + (bid >> 3);
    const int m0 = (swzb >> 4) * 256, n0 = (swzb & 15) * 256;
    f32x4 acc[8][4] = {};
    gemm256_core(A, Bt, L, m0, n0, acc);

    const int lane = threadIdx.x & 63, wave = threadIdx.x >> 6;
    const int wm = wave >> 2, wn = wave & 3;
    const int fr = lane & 15, fg = lane >> 4;
#pragma unroll
    for (int mf = 0; mf < 8; ++mf) {
        int r0 = m0 + wm * 128 + mf * 16 + 4 * fg;
#pragma unroll
        for (int nf = 0; nf < 4; ++nf) {
            int cc = n0 + wn * 64 + nf * 16 + fr;
#pragma unroll
            for (int e = 0; e < 4; ++e)
                out[(long)(r0 + e) * 4096 + cc] = acc[mf][nf][e];
        }
    }
}

// ---------------------------------------------------------------------------
// Flash attention v5 (r10-proven): 32x32x16 MFMA, in-register P, no Psm.
//   A: row=lane&31, k=8*(lane>>5)+e   B: k=8*(lane>>5)+e, col=lane&31
//   C: col=lane&31, row=(reg&3)+8*(reg>>2)+4*(lane>>5)
// QK^T swapped -> q lane-local; PV with P assembled via pk2 + shfl_xor(32).

__device__ __forceinline__ f16x8 ld_sw256(const f16* base, int r, int c) {
    int byte = r * 256 + ((c * 2) ^ ((r & 7) << 4));
    return *(const f16x8*)((const char*)base + byte);
}
__device__ __forceinline__ f16x8 ld_sw128(const f16* base, int r, int c) {
    int byte = r * 128 + ((c * 2) ^ ((r & 7) << 4));
    return *(const f16x8*)((const char*)base + byte);
}

__device__ __forceinline__ void stage_k(const f16* __restrict__ Kb, f16* ksm,
                                        int k0, int wave, int lane) {
#pragma unroll
    for (int i = 0; i < 4; ++i) {
        int dbase = (i * 4 + wave) * 1024;
        int d = dbase + lane * 16;
        int row = d >> 8;
        int cb = (d & 255) ^ ((row & 7) << 4);
        async_ld16(Kb + (long)(k0 + row) * HD + (cb >> 1), (char*)ksm + dbase);
    }
}
__device__ __forceinline__ void stage_v(const f16* __restrict__ Vb, f16* vsm,
                                        int k0, int wave, int lane) {
#pragma unroll
    for (int i = 0; i < 4; ++i) {
        int dbase = (i * 4 + wave) * 1024;
        int d = dbase + lane * 16;
        int row = d >> 7;
        int cb = (d & 127) ^ ((row & 7) << 4);
        async_ld16(Vb + (long)row * Sn + k0 + (cb >> 1), (char*)vsm + dbase);
    }
}

__global__ __launch_bounds__(256) void k_attn(
    const f16* __restrict__ Q, const f16* __restrict__ K,
    const f16* __restrict__ Vt, f16* __restrict__ O) {
    __shared__ __align__(16) f16 Ksm[2][64 * 128];   // 32KB
    __shared__ __align__(16) f16 Vsm[2][128 * 64];   // 32KB

    const int id = blockIdx.x;
    const int kvh = id & 7;
    const int r_ = id >> 3;
    const int qt = 15 - (r_ & 15);          // heavy-first within kvh group
    const int hg = (r_ >> 4) & 3;
    const int b  = r_ >> 6;
    const int h  = kvh * 4 + hg;
    const int q0 = qt * 128;
    const int t = threadIdx.x, lane = t & 63, wave = t >> 6;
    const int q0w = q0 + wave * 32;
    const int lq = lane & 31, hi = lane >> 5;

    const f16* Qb = Q + ((long)(b * NH + h) * Sn) * HD;
    const f16* Kb = K + ((long)(b * NKV + kvh) * Sn) * HD;
    const f16* Vb = Vt + ((long)(b * NKV + kvh) * HD) * Sn;

    f16x8 qf[8];
#pragma unroll
    for (int s = 0; s < 8; ++s)
        qf[s] = *(const f16x8*)&Qb[(long)(q0w + lq) * HD + 16 * s + 8 * hi];

    f32x16 oacc[4] = {};
    float mrun = -1e30f, lrun = 0.f;

    const int nt = q0 / 64 + 2;
    stage_k(Kb, Ksm[0], 0, wave, lane);
    stage_v(Vb, Vsm[0], 0, wave, lane);

    for (int kt = 0; kt < nt; ++kt) {
        const int k0 = kt * 64;
        const int cur = kt & 1;
        if (kt + 1 < nt) {
            stage_k(Kb, Ksm[cur ^ 1], (kt + 1) * 64, wave, lane);
            stage_v(Vb, Vsm[cur ^ 1], (kt + 1) * 64, wave, lane);
            asm volatile("s_waitcnt vmcnt(8)" ::: "memory");
        } else {
            asm volatile("s_waitcnt vmcnt(0)" ::: "memory");
        }
        __builtin_amdgcn_s_barrier();

        if (k0 <= q0w + 31) {
            f32x16 st[2] = {};
#pragma unroll
            for (int s = 0; s < 8; ++s) {
                f16x8 kf0 = ld_sw256(Ksm[cur], lq,      16 * s + 8 * hi);
                f16x8 kf1 = ld_sw256(Ksm[cur], 32 + lq, 16 * s + 8 * hi);
                st[0] = __builtin_amdgcn_mfma_f32_32x32x16_f16(kf0, qf[s], st[0], 0, 0, 0);
                st[1] = __builtin_amdgcn_mfma_f32_32x32x16_f16(kf1, qf[s], st[1], 0, 0, 0);
            }
            const bool full = (k0 + 63 <= q0w);
            if (!full) {
#pragma unroll
                for (int mt = 0; mt < 2; ++mt)
#pragma unroll
                    for (int r = 0; r < 16; ++r) {
                        int kvv = k0 + 32 * mt + (r & 3) + 8 * (r >> 2) + 4 * hi;
                        if (kvv > q0w + lq) st[mt][r] = -1e30f;
                    }
            }
            float pm = st[0][0];
#pragma unroll
            for (int r = 1; r < 16; ++r) pm = fmaxf(pm, st[0][r]);
#pragma unroll
            for (int r = 0; r < 16; ++r) pm = fmaxf(pm, st[1][r]);
            pm = fmaxf(pm, __shfl_xor(pm, 32, 64));
            if (__any(pm > mrun + 8.f)) {
                float mn = fmaxf(mrun, pm);
                float sc = fexp2(mrun - mn);
                mrun = mn;
                lrun *= sc;
                float scr[16];
#pragma unroll
                for (int r = 0; r < 16; ++r)
                    scr[r] = __shfl(sc, (r & 3) + 8 * (r >> 2) + 4 * hi, 64);
#pragma unroll
                for (int db = 0; db < 4; ++db)
#pragma unroll
                    for (int r = 0; r < 16; ++r)
                        oacc[db][r] *= scr[r];
            }
            unsigned pw[2][8];
#pragma unroll
            for (int mt = 0; mt < 2; ++mt)
#pragma unroll
                for (int i = 0; i < 8; ++i) {
                    float p0 = fexp2(st[mt][2 * i]     - mrun);
                    float p1 = fexp2(st[mt][2 * i + 1] - mrun);
                    lrun += p0 + p1;
                    pw[mt][i] = pk2(p0, p1);
                }
#pragma unroll
            for (int s = 0; s < 4; ++s) {
                const int mt = s >> 1, sl = s & 1;
                unsigned a0 = pw[mt][4 * sl], a1 = pw[mt][4 * sl + 1];
                unsigned a2 = pw[mt][4 * sl + 2], a3 = pw[mt][4 * sl + 3];
                unsigned own0 = hi ? a2 : a0, own1 = hi ? a3 : a1;
                unsigned snd0 = hi ? a0 : a2, snd1 = hi ? a1 : a3;
                unsigned rx0 = (unsigned)__shfl_xor((int)snd0, 32, 64);
                unsigned rx1 = (unsigned)__shfl_xor((int)snd1, 32, 64);
                union { unsigned u[4]; f16x8 v; } pu;
                pu.u[0] = hi ? rx0 : own0;
                pu.u[1] = hi ? rx1 : own1;
                pu.u[2] = hi ? own0 : rx0;
                pu.u[3] = hi ? own1 : rx1;
#pragma unroll
                for (int db = 0; db < 4; ++db) {
                    f16x8 vf = ld_sw128(Vsm[cur], 32 * db + lq, 16 * s + 8 * hi);
                    oacc[db] = __builtin_amdgcn_mfma_f32_32x32x16_f16(pu.v, vf, oacc[db], 0, 0, 0);
                }
            }
        }
        __builtin_amdgcn_s_barrier();
    }

    lrun += __shfl_xor(lrun, 32, 64);
    float li = 1.f / lrun;
    float ir[16];
#pragma unroll
    for (int r = 0; r < 16; ++r)
        ir[r] = __shfl(li, (r & 3) + 8 * (r >> 2) + 4 * hi, 64);
#pragma unroll
    for (int db = 0; db < 4; ++db)
#pragma unroll
        for (int r = 0; r < 16; ++r) {
            int qloc = (r & 3) + 8 * (r >> 2) + 4 * hi;
            long tok = (long)b * Sn + q0w + qloc;
            O[tok * (NH * HD) + h * HD + 32 * db + lq] = (f16)(oacc[db][r] * ir[r]);
        }
}

// sentinel if workspace too small
__global__ void k_ws_fail(float* out) { out[0] = 1.0e9f; }

// ---------------------------------------------------------------------------
extern "C" void kernel_launch(void* const* d_in, const int* in_sizes, int n_in,
                              void* d_out, int out_size, void* d_ws, size_t ws_size,
                              hipStream_t stream) {
    const float* hs   = (const float*)d_in[0];
    const float* wq   = (const float*)d_in[1];
    const float* wk   = (const float*)d_in[2];
    const float* wv   = (const float*)d_in[3];
    const float* wo   = (const float*)d_in[4];
    const float* cosb = (const float*)d_in[5];
    const float* sinb = (const float*)d_in[6];
    float* out = (float*)d_out;

    const size_t OFF_WQKV = 0;
    const size_t OFF_WO   = 50331648;
    const size_t OFF_HID  = 83886080;
    const size_t OFF_Q    = 117440512;
    const size_t OFF_K    = 150994944;
    const size_t OFF_VT   = 167772160;
    const size_t WS_NEED  = 176160768;
    if (ws_size < WS_NEED) { k_ws_fail<<<1, 1, 0, stream>>>(out); return; }

    char* ws = (char*)d_ws;
    f16* wqkv_t = (f16*)(ws + OFF_WQKV);
    f16* wo_t   = (f16*)(ws + OFF_WO);
    f16* hid    = (f16*)(ws + OFF_HID);
    f16* qb     = (f16*)(ws + OFF_Q);
    f16* kb     = (f16*)(ws + OFF_K);
    f16* vtb    = (f16*)(ws + OFF_VT);

    dim3 tb(32, 8);
    k_cvt<<<dim3(16777216 / (256 * 8)), 256, 0, stream>>>(hs, hid, 16777216L);
    k_tcvt<<<dim3(128, 128), tb, 0, stream>>>(wq, wqkv_t, 4096, 4096, 4096);
    k_tcvt<<<dim3(32, 128),  tb, 0, stream>>>(wk, wqkv_t + (long)4096 * 4096, 4096, 1024, 4096);
    k_tcvt<<<dim3(32, 128),  tb, 0, stream>>>(wv, wqkv_t + (long)5120 * 4096, 4096, 1024, 4096);
    k_tcvt<<<dim3(128, 128), tb, 0, stream>>>(wo, wo_t, 4096, 4096, 4096);
    k_gemm_qkv<<<dim3(384), 512, 0, stream>>>(hid, wqkv_t, qb, kb, vtb);
    k_rope<<<dim3(2 * 32 * 2048 * 32 / 256), 256, 0, stream>>>(qb, cosb, sinb, NH);
    k_rope<<<dim3(2 * 8 * 2048 * 32 / 256), 256, 0, stream>>>(kb, cosb, sinb, NKV);
    k_attn<<<dim3(1024), 256, 0, stream>>>(qb, kb, vtb, hid);
    k_gemm_out<<<dim3(256), 512, 0, stream>>>(hid, wo_t, out);
}

// Round 12
// 612.382 us; speedup vs baseline: 1.9190x; 1.0252x over previous
//
#include <hip/hip_runtime.h>

// ============================================================================
// GLM4-MoE attention layer on MI355X (gfx950), fp16 MFMA pipeline.
// Round 12: aux harvest.
//   - RoPE fused into GEMM1 epilogue (rotation commutes with QSC scale;
//     pair partner d^1 = lane^1 via shfl_xor(1); cos/sin f32 loads per frag).
//     k_rope kernels + 168MB of q/k round-trip eliminated.
//   - k_tcvt v2: 64x64 tiles, (64,4) threads, 128B-contiguous f16 writes,
//     LDS [64][65] conflict-free.
// GEMM = r11 8-phase/counted-vmcnt 256x256 (best measured: 236us, 38.5%).
// Attention v5 = r10 (32x32 MFMA, in-register P). k_cvt unchanged.
// ============================================================================

typedef _Float16 f16;
typedef _Float16 f16x8 __attribute__((ext_vector_type(8)));
typedef float f32x4 __attribute__((ext_vector_type(4)));
typedef float f32x16 __attribute__((ext_vector_type(16)));

static constexpr int Bn = 2, Sn = 2048, Hn = 4096, NH = 32, NKV = 8, HD = 128;
static constexpr float QSC = 0.08838834764831845f * 1.44269504088896340736f; // 1/sqrt(128)*log2e

#define AS1 __attribute__((address_space(1)))
#define AS3 __attribute__((address_space(3)))

__device__ __forceinline__ void async_ld16(const void* g, void* l) {
    __builtin_amdgcn_global_load_lds((const AS1 void*)g, (AS3 void*)l, 16, 0, 0);
}

__device__ __forceinline__ unsigned pk2(float a, float b) {
    unsigned r;
    asm("v_cvt_pkrtz_f16_f32 %0, %1, %2" : "=v"(r) : "v"(a), "v"(b));
    return r;
}

// native exp2: v_exp_f32 computes 2^x
__device__ __forceinline__ float fexp2(float x) {
    float r;
    asm("v_exp_f32 %0, %1" : "=v"(r) : "v"(x));
    return r;
}

// ---------------------------------------------------------------------------
__global__ void k_cvt(const float* __restrict__ src, f16* __restrict__ dst, long n) {
    long i = ((long)blockIdx.x * blockDim.x + threadIdx.x) * 8;
    if (i >= n) return;
    float4 a = *(const float4*)(src + i);
    float4 b = *(const float4*)(src + i + 4);
    f16x8 o = {(f16)a.x, (f16)a.y, (f16)a.z, (f16)a.w,
               (f16)b.x, (f16)b.y, (f16)b.z, (f16)b.w};
    *(f16x8*)(dst + i) = o;
}

// ---------------------------------------------------------------------------
// transpose + convert v2: src f32 [K][N] -> dst f16 [N][K]; 64x64 tiles.
__global__ void k_tcvt(const float* __restrict__ src, f16* __restrict__ dst,
                       int K, int N, long rs) {
    __shared__ float tile[64][65];
    int k0 = blockIdx.y * 64, n0 = blockIdx.x * 64;
    int tx = threadIdx.x, ty = threadIdx.y;   // (64,4)
#pragma unroll
    for (int r = ty; r < 64; r += 4)
        tile[r][tx] = src[(long)(k0 + r) * N + (n0 + tx)];
    __syncthreads();
#pragma unroll
    for (int r = ty; r < 64; r += 4)
        dst[(long)(n0 + r) * rs + (k0 + tx)] = (f16)tile[tx][r];
}

// ---------------------------------------------------------------------------
// 256x256 GEMM core (r11-proven), BK=64, 8 waves, K=4096. 8-phase interleave,
// counted vmcnt(6) once per K-tile. See r11 header for the dead-region ledger.
__device__ __forceinline__ void gemm256_core(
    const f16* __restrict__ A, const f16* __restrict__ Bt,
    char* L, int m0, int n0, f32x4 acc[8][4]) {
    const int t = threadIdx.x, lane = t & 63, wave = t >> 6;
    const int wm = wave >> 2, wn = wave & 3;
    const int fr = lane & 15, fg = lane >> 4;

    const int srowL = wave * 8 + (lane >> 3);
    const int scol  = 8 * ((lane & 7) ^ (lane >> 3));
    const f16* ga = A  + (long)(m0 + srowL) * 4096 + scol;
    const f16* gb = Bt + (long)(n0 + srowL) * 4096 + scol;
    const int woff = wave * 1024;

    auto ST = [&](int sel, int c, int row0, int kt) {
        const f16* g = sel ? gb : ga;
        async_ld16(g + (long)row0 * 4096 + kt * 64,
                   L + c * 65536 + sel * 32768 + row0 * 128 + woff);
    };

    ST(0, 0, 0, 0);   ST(0, 0, 64, 0);  ST(0, 0, 128, 0); ST(0, 0, 192, 0);
    ST(1, 0, 0, 0);   ST(1, 0, 64, 0);  ST(1, 0, 128, 0); ST(1, 0, 192, 0);
    ST(1, 1, 0, 1);   ST(1, 1, 64, 1);  ST(1, 1, 128, 1); ST(1, 1, 192, 1);
    ST(0, 1, 0, 1);   ST(0, 1, 128, 1);
    asm volatile("s_waitcnt vmcnt(6)" ::: "memory");
    __builtin_amdgcn_s_barrier();

    const int abase = wm * 128;
    const int bbase = wn * 64;

    for (int tt = 0; tt < 64; ++tt) {
        const int c = tt & 1;
        const char* bufA = L + c * 65536;
        const char* bufB = bufA + 32768;
        f16x8 bf[2][4];

#pragma unroll
        for (int q = 0; q < 4; ++q) {
            if (q == 0) {
#pragma unroll
                for (int ks = 0; ks < 2; ++ks)
#pragma unroll
                    for (int nf = 0; nf < 4; ++nf) {
                        int r = bbase + nf * 16 + fr;
                        bf[ks][nf] = *(const f16x8*)(bufB + r * 128 +
                                        ((ks * 64 + 16 * fg) ^ ((r & 7) << 4)));
                    }
            }
            f16x8 af[2][2];
#pragma unroll
            for (int ks = 0; ks < 2; ++ks)
#pragma unroll
                for (int i = 0; i < 2; ++i) {
                    int r = abase + (2 * q + i) * 16 + fr;
                    af[ks][i] = *(const f16x8*)(bufA + r * 128 +
                                    ((ks * 64 + 16 * fg) ^ ((r & 7) << 4)));
                }
            if (q == 0) { if (tt + 1 < 64) { ST(0, c ^ 1,  64, tt + 1);
                                             ST(0, c ^ 1, 192, tt + 1); } }
            if (q == 1) { if (tt + 2 < 64) { ST(1, c,   0, tt + 2);
                                             ST(1, c,  64, tt + 2); } }
            if (q == 2) { if (tt + 2 < 64) { ST(1, c, 128, tt + 2);
                                             ST(1, c, 192, tt + 2); } }
            if (q == 3) { if (tt + 2 < 64) { ST(0, c,   0, tt + 2);
                                             ST(0, c, 128, tt + 2); } }
            __builtin_amdgcn_s_barrier();
            __builtin_amdgcn_s_setprio(1);
#pragma unroll
            for (int ks = 0; ks < 2; ++ks)
#pragma unroll
                for (int i = 0; i < 2; ++i)
#pragma unroll
                    for (int nf = 0; nf < 4; ++nf)
                        acc[2 * q + i][nf] = __builtin_amdgcn_mfma_f32_16x16x32_f16(
                            af[ks][i], bf[ks][nf], acc[2 * q + i][nf], 0, 0, 0);
            __builtin_amdgcn_s_setprio(0);
            if (q == 3) {
                if (tt < 62)       asm volatile("s_waitcnt vmcnt(6)" ::: "memory");
                else if (tt == 62) asm volatile("s_waitcnt vmcnt(0)" ::: "memory");
            }
            __builtin_amdgcn_s_barrier();
        }
    }
}

// GEMM1: hidden @ Wqkv^T -> q (RoPE+scale fused), k (RoPE fused), V^T (fused).
__global__ __launch_bounds__(512) void k_gemm_qkv(
    const f16* __restrict__ A, const f16* __restrict__ Bt,
    f16* __restrict__ q, f16* __restrict__ kk_, f16* __restrict__ vt,
    const float* __restrict__ cosb, const float* __restrict__ sinb) {
    __shared__ __align__(16) char L[131072];
    const int bid = blockIdx.x;                    // 384 = 16m x 24n
    const int swzb = (bid & 7) * 48 + (bid >> 3);  // XCD-bijective
    const int m0 = (swzb / 24) * 256, n0 = (swzb % 24) * 256;
    f32x4 acc[8][4] = {};
    gemm256_core(A, Bt, L, m0, n0, acc);

    const int lane = threadIdx.x & 63, wave = threadIdx.x >> 6;
    const int wm = wave >> 2, wn = wave & 3;
    const int fr = lane & 15, fg = lane >> 4;
#pragma unroll
    for (int mf = 0; mf < 8; ++mf) {
        int r0 = m0 + wm * 128 + mf * 16 + 4 * fg;
        int b = r0 >> 11, s = r0 & (Sn - 1);   // r0 multiple of 4: same b, s..s+3
        const float* cb_ = cosb + ((long)b * Sn + s) * 64;
        const float* sb_ = sinb + ((long)b * Sn + s) * 64;
#pragma unroll
        for (int nf = 0; nf < 4; ++nf) {
            int cc = n0 + wn * 64 + nf * 16 + fr;
            int d = cc & 127;
            if (cc < 5120) {
                // q or k head: partial interleaved RoPE on d<64 (frag-uniform)
                float vals[4];
#pragma unroll
                for (int e = 0; e < 4; ++e) vals[e] = acc[mf][nf][e];
                if (d < 64) {
                    int ci = d >> 1;
                    bool odd = (d & 1);
#pragma unroll
                    for (int e = 0; e < 4; ++e) {
                        float p = __shfl_xor(vals[e], 1, 64);   // lane^1 = d^1
                        float c = cb_[e * 64 + ci], sv = sb_[e * 64 + ci];
                        vals[e] = odd ? (vals[e] * c + p * sv)
                                      : (vals[e] * c - p * sv);
                    }
                }
                if (cc < 4096) {
                    int h = cc >> 7;
#pragma unroll
                    for (int e = 0; e < 4; ++e)
                        q[(((long)b * NH + h) * Sn + s + e) * HD + d] =
                            (f16)(vals[e] * QSC);
                } else {
                    int h = (cc - 4096) >> 7;
#pragma unroll
                    for (int e = 0; e < 4; ++e)
                        kk_[(((long)b * NKV + h) * Sn + s + e) * HD + d] =
                            (f16)vals[e];
                }
            } else {
                int h = (cc - 5120) >> 7;
                uint2 w = {pk2(acc[mf][nf][0], acc[mf][nf][1]),
                           pk2(acc[mf][nf][2], acc[mf][nf][3])};
                *(uint2*)&vt[(((long)b * NKV + h) * HD + d) * Sn + s] = w;
            }
        }
    }
}

// GEMM2: attn_out @ wo^T -> d_out f32, 256 blocks (16x16)
__global__ __launch_bounds__(512) void k_gemm_out(
    const f16* __restrict__ A, const f16* __restrict__ Bt,
    float* __restrict__ out) {
    __shared__ __align__(16) char L[131072];
    const int bid = blockIdx.x;
    const int swzb = (bid & 7) * 32 + (bid >> 3);
    const int m0 = (swzb >> 4) * 256, n0 = (swzb & 15) * 256;
    f32x4 acc[8][4] = {};
    gemm256_core(A, Bt, L, m0, n0, acc);

    const int lane = threadIdx.x & 63, wave = threadIdx.x >> 6;
    const int wm = wave >> 2, wn = wave & 3;
    const int fr = lane & 15, fg = lane >> 4;
#pragma unroll
    for (int mf = 0; mf < 8; ++mf) {
        int r0 = m0 + wm * 128 + mf * 16 + 4 * fg;
#pragma unroll
        for (int nf = 0; nf < 4; ++nf) {
            int cc = n0 + wn * 64 + nf * 16 + fr;
#pragma unroll
            for (int e = 0; e < 4; ++e)
                out[(long)(r0 + e) * 4096 + cc] = acc[mf][nf][e];
        }
    }
}

// ---------------------------------------------------------------------------
// Flash attention v5 (r10-proven): 32x32x16 MFMA, in-register P, no Psm.
//   A: row=lane&31, k=8*(lane>>5)+e   B: k=8*(lane>>5)+e, col=lane&31
//   C: col=lane&31, row=(reg&3)+8*(reg>>2)+4*(lane>>5)
// QK^T swapped -> q lane-local; PV with P assembled via pk2 + shfl_xor(32).

__device__ __forceinline__ f16x8 ld_sw256(const f16* base, int r, int c) {
    int byte = r * 256 + ((c * 2) ^ ((r & 7) << 4));
    return *(const f16x8*)((const char*)base + byte);
}
__device__ __forceinline__ f16x8 ld_sw128(const f16* base, int r, int c) {
    int byte = r * 128 + ((c * 2) ^ ((r & 7) << 4));
    return *(const f16x8*)((const char*)base + byte);
}

__device__ __forceinline__ void stage_k(const f16* __restrict__ Kb, f16* ksm,
                                        int k0, int wave, int lane) {
#pragma unroll
    for (int i = 0; i < 4; ++i) {
        int dbase = (i * 4 + wave) * 1024;
        int d = dbase + lane * 16;
        int row = d >> 8;
        int cb = (d & 255) ^ ((row & 7) << 4);
        async_ld16(Kb + (long)(k0 + row) * HD + (cb >> 1), (char*)ksm + dbase);
    }
}
__device__ __forceinline__ void stage_v(const f16* __restrict__ Vb, f16* vsm,
                                        int k0, int wave, int lane) {
#pragma unroll
    for (int i = 0; i < 4; ++i) {
        int dbase = (i * 4 + wave) * 1024;
        int d = dbase + lane * 16;
        int row = d >> 7;
        int cb = (d & 127) ^ ((row & 7) << 4);
        async_ld16(Vb + (long)row * Sn + k0 + (cb >> 1), (char*)vsm + dbase);
    }
}

__global__ __launch_bounds__(256) void k_attn(
    const f16* __restrict__ Q, const f16* __restrict__ K,
    const f16* __restrict__ Vt, f16* __restrict__ O) {
    __shared__ __align__(16) f16 Ksm[2][64 * 128];   // 32KB
    __shared__ __align__(16) f16 Vsm[2][128 * 64];   // 32KB

    const int id = blockIdx.x;
    const int kvh = id & 7;
    const int r_ = id >> 3;
    const int qt = 15 - (r_ & 15);          // heavy-first within kvh group
    const int hg = (r_ >> 4) & 3;
    const int b  = r_ >> 6;
    const int h  = kvh * 4 + hg;
    const int q0 = qt * 128;
    const int t = threadIdx.x, lane = t & 63, wave = t >> 6;
    const int q0w = q0 + wave * 32;
    const int lq = lane & 31, hi = lane >> 5;

    const f16* Qb = Q + ((long)(b * NH + h) * Sn) * HD;
    const f16* Kb = K + ((long)(b * NKV + kvh) * Sn) * HD;
    const f16* Vb = Vt + ((long)(b * NKV + kvh) * HD) * Sn;

    f16x8 qf[8];
#pragma unroll
    for (int s = 0; s < 8; ++s)
        qf[s] = *(const f16x8*)&Qb[(long)(q0w + lq) * HD + 16 * s + 8 * hi];

    f32x16 oacc[4] = {};
    float mrun = -1e30f, lrun = 0.f;

    const int nt = q0 / 64 + 2;
    stage_k(Kb, Ksm[0], 0, wave, lane);
    stage_v(Vb, Vsm[0], 0, wave, lane);

    for (int kt = 0; kt < nt; ++kt) {
        const int k0 = kt * 64;
        const int cur = kt & 1;
        if (kt + 1 < nt) {
            stage_k(Kb, Ksm[cur ^ 1], (kt + 1) * 64, wave, lane);
            stage_v(Vb, Vsm[cur ^ 1], (kt + 1) * 64, wave, lane);
            asm volatile("s_waitcnt vmcnt(8)" ::: "memory");
        } else {
            asm volatile("s_waitcnt vmcnt(0)" ::: "memory");
        }
        __builtin_amdgcn_s_barrier();

        if (k0 <= q0w + 31) {
            f32x16 st[2] = {};
#pragma unroll
            for (int s = 0; s < 8; ++s) {
                f16x8 kf0 = ld_sw256(Ksm[cur], lq,      16 * s + 8 * hi);
                f16x8 kf1 = ld_sw256(Ksm[cur], 32 + lq, 16 * s + 8 * hi);
                st[0] = __builtin_amdgcn_mfma_f32_32x32x16_f16(kf0, qf[s], st[0], 0, 0, 0);
                st[1] = __builtin_amdgcn_mfma_f32_32x32x16_f16(kf1, qf[s], st[1], 0, 0, 0);
            }
            const bool full = (k0 + 63 <= q0w);
            if (!full) {
#pragma unroll
                for (int mt = 0; mt < 2; ++mt)
#pragma unroll
                    for (int r = 0; r < 16; ++r) {
                        int kvv = k0 + 32 * mt + (r & 3) + 8 * (r >> 2) + 4 * hi;
                        if (kvv > q0w + lq) st[mt][r] = -1e30f;
                    }
            }
            float pm = st[0][0];
#pragma unroll
            for (int r = 1; r < 16; ++r) pm = fmaxf(pm, st[0][r]);
#pragma unroll
            for (int r = 0; r < 16; ++r) pm = fmaxf(pm, st[1][r]);
            pm = fmaxf(pm, __shfl_xor(pm, 32, 64));
            if (__any(pm > mrun + 8.f)) {
                float mn = fmaxf(mrun, pm);
                float sc = fexp2(mrun - mn);
                mrun = mn;
                lrun *= sc;
                float scr[16];
#pragma unroll
                for (int r = 0; r < 16; ++r)
                    scr[r] = __shfl(sc, (r & 3) + 8 * (r >> 2) + 4 * hi, 64);
#pragma unroll
                for (int db = 0; db < 4; ++db)
#pragma unroll
                    for (int r = 0; r < 16; ++r)
                        oacc[db][r] *= scr[r];
            }
            unsigned pw[2][8];
#pragma unroll
            for (int mt = 0; mt < 2; ++mt)
#pragma unroll
                for (int i = 0; i < 8; ++i) {
                    float p0 = fexp2(st[mt][2 * i]     - mrun);
                    float p1 = fexp2(st[mt][2 * i + 1] - mrun);
                    lrun += p0 + p1;
                    pw[mt][i] = pk2(p0, p1);
                }
#pragma unroll
            for (int s = 0; s < 4; ++s) {
                const int mt = s >> 1, sl = s & 1;
                unsigned a0 = pw[mt][4 * sl], a1 = pw[mt][4 * sl + 1];
                unsigned a2 = pw[mt][4 * sl + 2], a3 = pw[mt][4 * sl + 3];
                unsigned own0 = hi ? a2 : a0, own1 = hi ? a3 : a1;
                unsigned snd0 = hi ? a0 : a2, snd1 = hi ? a1 : a3;
                unsigned rx0 = (unsigned)__shfl_xor((int)snd0, 32, 64);
                unsigned rx1 = (unsigned)__shfl_xor((int)snd1, 32, 64);
                union { unsigned u[4]; f16x8 v; } pu;
                pu.u[0] = hi ? rx0 : own0;
                pu.u[1] = hi ? rx1 : own1;
                pu.u[2] = hi ? own0 : rx0;
                pu.u[3] = hi ? own1 : rx1;
#pragma unroll
                for (int db = 0; db < 4; ++db) {
                    f16x8 vf = ld_sw128(Vsm[cur], 32 * db + lq, 16 * s + 8 * hi);
                    oacc[db] = __builtin_amdgcn_mfma_f32_32x32x16_f16(pu.v, vf, oacc[db], 0, 0, 0);
                }
            }
        }
        __builtin_amdgcn_s_barrier();
    }

    lrun += __shfl_xor(lrun, 32, 64);
    float li = 1.f / lrun;
    float ir[16];
#pragma unroll
    for (int r = 0; r < 16; ++r)
        ir[r] = __shfl(li, (r & 3) + 8 * (r >> 2) + 4 * hi, 64);
#pragma unroll
    for (int db = 0; db < 4; ++db)
#pragma unroll
        for (int r = 0; r < 16; ++r) {
            int qloc = (r & 3) + 8 * (r >> 2) + 4 * hi;
            long tok = (long)b * Sn + q0w + qloc;
            O[tok * (NH * HD) + h * HD + 32 * db + lq] = (f16)(oacc[db][r] * ir[r]);
        }
}

// sentinel if workspace too small
__global__ void k_ws_fail(float* out) { out[0] = 1.0e9f; }

// ---------------------------------------------------------------------------
extern "C" void kernel_launch(void* const* d_in, const int* in_sizes, int n_in,
                              void* d_out, int out_size, void* d_ws, size_t ws_size,
                              hipStream_t stream) {
    const float* hs   = (const float*)d_in[0];
    const float* wq   = (const float*)d_in[1];
    const float* wk   = (const float*)d_in[2];
    const float* wv   = (const float*)d_in[3];
    const float* wo   = (const float*)d_in[4];
    const float* cosb = (const float*)d_in[5];
    const float* sinb = (const float*)d_in[6];
    float* out = (float*)d_out;

    const size_t OFF_WQKV = 0;
    const size_t OFF_WO   = 50331648;
    const size_t OFF_HID  = 83886080;
    const size_t OFF_Q    = 117440512;
    const size_t OFF_K    = 150994944;
    const size_t OFF_VT   = 167772160;
    const size_t WS_NEED  = 176160768;
    if (ws_size < WS_NEED) { k_ws_fail<<<1, 1, 0, stream>>>(out); return; }

    char* ws = (char*)d_ws;
    f16* wqkv_t = (f16*)(ws + OFF_WQKV);
    f16* wo_t   = (f16*)(ws + OFF_WO);
    f16* hid    = (f16*)(ws + OFF_HID);
    f16* qb     = (f16*)(ws + OFF_Q);
    f16* kb     = (f16*)(ws + OFF_K);
    f16* vtb    = (f16*)(ws + OFF_VT);

    dim3 tb64(64, 4);
    k_cvt<<<dim3(16777216 / (256 * 8)), 256, 0, stream>>>(hs, hid, 16777216L);
    k_tcvt<<<dim3(64, 64), tb64, 0, stream>>>(wq, wqkv_t, 4096, 4096, 4096);
    k_tcvt<<<dim3(16, 64), tb64, 0, stream>>>(wk, wqkv_t + (long)4096 * 4096, 4096, 1024, 4096);
    k_tcvt<<<dim3(16, 64), tb64, 0, stream>>>(wv, wqkv_t + (long)5120 * 4096, 4096, 1024, 4096);
    k_tcvt<<<dim3(64, 64), tb64, 0, stream>>>(wo, wo_t, 4096, 4096, 4096);
    k_gemm_qkv<<<dim3(384), 512, 0, stream>>>(hid, wqkv_t, qb, kb, vtb, cosb, sinb);
    k_attn<<<dim3(1024), 256, 0, stream>>>(qb, kb, vtb, hid);
    k_gemm_out<<<dim3(256), 512, 0, stream>>>(hid, wo_t, out);
}

// Round 13
// 580.978 us; speedup vs baseline: 2.0228x; 1.0541x over previous
//
#include <hip/hip_runtime.h>

// ============================================================================
// GLM4-MoE attention layer on MI355X (gfx950), fp16 MFMA pipeline.
// Round 13: attention QBLK=256 (8 waves x 32 q-rows, 512 threads):
//   - K/V staging volume per (b,h): 272 -> 144 tile-stagings (-47%)
//   - grid 512 = exactly 2 blocks/CU; blocks paired (heavy qt, light qt)
//     so each CU's pair sums to ~constant work (qt + (7-qt))
//   - stage split 8 waves x 2 chunks; per-wave vmcnt(4) (was 8)
// GEMMs (r11 8-phase + r12 RoPE/V^T-fused epilogues), cvt/tcvt unchanged.
// ============================================================================

typedef _Float16 f16;
typedef _Float16 f16x8 __attribute__((ext_vector_type(8)));
typedef float f32x4 __attribute__((ext_vector_type(4)));
typedef float f32x16 __attribute__((ext_vector_type(16)));

static constexpr int Bn = 2, Sn = 2048, Hn = 4096, NH = 32, NKV = 8, HD = 128;
static constexpr float QSC = 0.08838834764831845f * 1.44269504088896340736f; // 1/sqrt(128)*log2e

#define AS1 __attribute__((address_space(1)))
#define AS3 __attribute__((address_space(3)))

__device__ __forceinline__ void async_ld16(const void* g, void* l) {
    __builtin_amdgcn_global_load_lds((const AS1 void*)g, (AS3 void*)l, 16, 0, 0);
}

__device__ __forceinline__ unsigned pk2(float a, float b) {
    unsigned r;
    asm("v_cvt_pkrtz_f16_f32 %0, %1, %2" : "=v"(r) : "v"(a), "v"(b));
    return r;
}

// native exp2: v_exp_f32 computes 2^x
__device__ __forceinline__ float fexp2(float x) {
    float r;
    asm("v_exp_f32 %0, %1" : "=v"(r) : "v"(x));
    return r;
}

// ---------------------------------------------------------------------------
__global__ void k_cvt(const float* __restrict__ src, f16* __restrict__ dst, long n) {
    long i = ((long)blockIdx.x * blockDim.x + threadIdx.x) * 8;
    if (i >= n) return;
    float4 a = *(const float4*)(src + i);
    float4 b = *(const float4*)(src + i + 4);
    f16x8 o = {(f16)a.x, (f16)a.y, (f16)a.z, (f16)a.w,
               (f16)b.x, (f16)b.y, (f16)b.z, (f16)b.w};
    *(f16x8*)(dst + i) = o;
}

// ---------------------------------------------------------------------------
// transpose + convert v2: src f32 [K][N] -> dst f16 [N][K]; 64x64 tiles.
__global__ void k_tcvt(const float* __restrict__ src, f16* __restrict__ dst,
                       int K, int N, long rs) {
    __shared__ float tile[64][65];
    int k0 = blockIdx.y * 64, n0 = blockIdx.x * 64;
    int tx = threadIdx.x, ty = threadIdx.y;   // (64,4)
#pragma unroll
    for (int r = ty; r < 64; r += 4)
        tile[r][tx] = src[(long)(k0 + r) * N + (n0 + tx)];
    __syncthreads();
#pragma unroll
    for (int r = ty; r < 64; r += 4)
        dst[(long)(n0 + r) * rs + (k0 + tx)] = (f16)tile[tx][r];
}

// ---------------------------------------------------------------------------
// 256x256 GEMM core (r11-proven), BK=64, 8 waves, K=4096. 8-phase interleave,
// counted vmcnt(6) once per K-tile. See r11 header for the dead-region ledger.
__device__ __forceinline__ void gemm256_core(
    const f16* __restrict__ A, const f16* __restrict__ Bt,
    char* L, int m0, int n0, f32x4 acc[8][4]) {
    const int t = threadIdx.x, lane = t & 63, wave = t >> 6;
    const int wm = wave >> 2, wn = wave & 3;
    const int fr = lane & 15, fg = lane >> 4;

    const int srowL = wave * 8 + (lane >> 3);
    const int scol  = 8 * ((lane & 7) ^ (lane >> 3));
    const f16* ga = A  + (long)(m0 + srowL) * 4096 + scol;
    const f16* gb = Bt + (long)(n0 + srowL) * 4096 + scol;
    const int woff = wave * 1024;

    auto ST = [&](int sel, int c, int row0, int kt) {
        const f16* g = sel ? gb : ga;
        async_ld16(g + (long)row0 * 4096 + kt * 64,
                   L + c * 65536 + sel * 32768 + row0 * 128 + woff);
    };

    ST(0, 0, 0, 0);   ST(0, 0, 64, 0);  ST(0, 0, 128, 0); ST(0, 0, 192, 0);
    ST(1, 0, 0, 0);   ST(1, 0, 64, 0);  ST(1, 0, 128, 0); ST(1, 0, 192, 0);
    ST(1, 1, 0, 1);   ST(1, 1, 64, 1);  ST(1, 1, 128, 1); ST(1, 1, 192, 1);
    ST(0, 1, 0, 1);   ST(0, 1, 128, 1);
    asm volatile("s_waitcnt vmcnt(6)" ::: "memory");
    __builtin_amdgcn_s_barrier();

    const int abase = wm * 128;
    const int bbase = wn * 64;

    for (int tt = 0; tt < 64; ++tt) {
        const int c = tt & 1;
        const char* bufA = L + c * 65536;
        const char* bufB = bufA + 32768;
        f16x8 bf[2][4];

#pragma unroll
        for (int q = 0; q < 4; ++q) {
            if (q == 0) {
#pragma unroll
                for (int ks = 0; ks < 2; ++ks)
#pragma unroll
                    for (int nf = 0; nf < 4; ++nf) {
                        int r = bbase + nf * 16 + fr;
                        bf[ks][nf] = *(const f16x8*)(bufB + r * 128 +
                                        ((ks * 64 + 16 * fg) ^ ((r & 7) << 4)));
                    }
            }
            f16x8 af[2][2];
#pragma unroll
            for (int ks = 0; ks < 2; ++ks)
#pragma unroll
                for (int i = 0; i < 2; ++i) {
                    int r = abase + (2 * q + i) * 16 + fr;
                    af[ks][i] = *(const f16x8*)(bufA + r * 128 +
                                    ((ks * 64 + 16 * fg) ^ ((r & 7) << 4)));
                }
            if (q == 0) { if (tt + 1 < 64) { ST(0, c ^ 1,  64, tt + 1);
                                             ST(0, c ^ 1, 192, tt + 1); } }
            if (q == 1) { if (tt + 2 < 64) { ST(1, c,   0, tt + 2);
                                             ST(1, c,  64, tt + 2); } }
            if (q == 2) { if (tt + 2 < 64) { ST(1, c, 128, tt + 2);
                                             ST(1, c, 192, tt + 2); } }
            if (q == 3) { if (tt + 2 < 64) { ST(0, c,   0, tt + 2);
                                             ST(0, c, 128, tt + 2); } }
            __builtin_amdgcn_s_barrier();
            __builtin_amdgcn_s_setprio(1);
#pragma unroll
            for (int ks = 0; ks < 2; ++ks)
#pragma unroll
                for (int i = 0; i < 2; ++i)
#pragma unroll
                    for (int nf = 0; nf < 4; ++nf)
                        acc[2 * q + i][nf] = __builtin_amdgcn_mfma_f32_16x16x32_f16(
                            af[ks][i], bf[ks][nf], acc[2 * q + i][nf], 0, 0, 0);
            __builtin_amdgcn_s_setprio(0);
            if (q == 3) {
                if (tt < 62)       asm volatile("s_waitcnt vmcnt(6)" ::: "memory");
                else if (tt == 62) asm volatile("s_waitcnt vmcnt(0)" ::: "memory");
            }
            __builtin_amdgcn_s_barrier();
        }
    }
}

// GEMM1: hidden @ Wqkv^T -> q (RoPE+scale fused), k (RoPE fused), V^T (fused).
__global__ __launch_bounds__(512) void k_gemm_qkv(
    const f16* __restrict__ A, const f16* __restrict__ Bt,
    f16* __restrict__ q, f16* __restrict__ kk_, f16* __restrict__ vt,
    const float* __restrict__ cosb, const float* __restrict__ sinb) {
    __shared__ __align__(16) char L[131072];
    const int bid = blockIdx.x;                    // 384 = 16m x 24n
    const int swzb = (bid & 7) * 48 + (bid >> 3);  // XCD-bijective
    const int m0 = (swzb / 24) * 256, n0 = (swzb % 24) * 256;
    f32x4 acc[8][4] = {};
    gemm256_core(A, Bt, L, m0, n0, acc);

    const int lane = threadIdx.x & 63, wave = threadIdx.x >> 6;
    const int wm = wave >> 2, wn = wave & 3;
    const int fr = lane & 15, fg = lane >> 4;
#pragma unroll
    for (int mf = 0; mf < 8; ++mf) {
        int r0 = m0 + wm * 128 + mf * 16 + 4 * fg;
        int b = r0 >> 11, s = r0 & (Sn - 1);   // r0 multiple of 4: same b, s..s+3
        const float* cb_ = cosb + ((long)b * Sn + s) * 64;
        const float* sb_ = sinb + ((long)b * Sn + s) * 64;
#pragma unroll
        for (int nf = 0; nf < 4; ++nf) {
            int cc = n0 + wn * 64 + nf * 16 + fr;
            int d = cc & 127;
            if (cc < 5120) {
                float vals[4];
#pragma unroll
                for (int e = 0; e < 4; ++e) vals[e] = acc[mf][nf][e];
                if (d < 64) {
                    int ci = d >> 1;
                    bool odd = (d & 1);
#pragma unroll
                    for (int e = 0; e < 4; ++e) {
                        float p = __shfl_xor(vals[e], 1, 64);   // lane^1 = d^1
                        float c = cb_[e * 64 + ci], sv = sb_[e * 64 + ci];
                        vals[e] = odd ? (vals[e] * c + p * sv)
                                      : (vals[e] * c - p * sv);
                    }
                }
                if (cc < 4096) {
                    int h = cc >> 7;
#pragma unroll
                    for (int e = 0; e < 4; ++e)
                        q[(((long)b * NH + h) * Sn + s + e) * HD + d] =
                            (f16)(vals[e] * QSC);
                } else {
                    int h = (cc - 4096) >> 7;
#pragma unroll
                    for (int e = 0; e < 4; ++e)
                        kk_[(((long)b * NKV + h) * Sn + s + e) * HD + d] =
                            (f16)vals[e];
                }
            } else {
                int h = (cc - 5120) >> 7;
                uint2 w = {pk2(acc[mf][nf][0], acc[mf][nf][1]),
                           pk2(acc[mf][nf][2], acc[mf][nf][3])};
                *(uint2*)&vt[(((long)b * NKV + h) * HD + d) * Sn + s] = w;
            }
        }
    }
}

// GEMM2: attn_out @ wo^T -> d_out f32, 256 blocks (16x16)
__global__ __launch_bounds__(512) void k_gemm_out(
    const f16* __restrict__ A, const f16* __restrict__ Bt,
    float* __restrict__ out) {
    __shared__ __align__(16) char L[131072];
    const int bid = blockIdx.x;
    const int swzb = (bid & 7) * 32 + (bid >> 3);
    const int m0 = (swzb >> 4) * 256, n0 = (swzb & 15) * 256;
    f32x4 acc[8][4] = {};
    gemm256_core(A, Bt, L, m0, n0, acc);

    const int lane = threadIdx.x & 63, wave = threadIdx.x >> 6;
    const int wm = wave >> 2, wn = wave & 3;
    const int fr = lane & 15, fg = lane >> 4;
#pragma unroll
    for (int mf = 0; mf < 8; ++mf) {
        int r0 = m0 + wm * 128 + mf * 16 + 4 * fg;
#pragma unroll
        for (int nf = 0; nf < 4; ++nf) {
            int cc = n0 + wn * 64 + nf * 16 + fr;
#pragma unroll
            for (int e = 0; e < 4; ++e)
                out[(long)(r0 + e) * 4096 + cc] = acc[mf][nf][e];
        }
    }
}

// ---------------------------------------------------------------------------
// Flash attention v6: QBLK=256 (8 waves x 32 q), 32x32x16 MFMA, in-register P.
//   A: row=lane&31, k=8*(lane>>5)+e   B: k=8*(lane>>5)+e, col=lane&31
//   C: col=lane&31, row=(reg&3)+8*(reg>>2)+4*(lane>>5)
// QK^T swapped -> q lane-local; PV with P assembled via pk2 + shfl_xor(32).

__device__ __forceinline__ f16x8 ld_sw256(const f16* base, int r, int c) {
    int byte = r * 256 + ((c * 2) ^ ((r & 7) << 4));
    return *(const f16x8*)((const char*)base + byte);
}
__device__ __forceinline__ f16x8 ld_sw128(const f16* base, int r, int c) {
    int byte = r * 128 + ((c * 2) ^ ((r & 7) << 4));
    return *(const f16x8*)((const char*)base + byte);
}

// K tile [64 kv][128 d] f16 = 16KB = 16 chunks; 8 waves x 2 chunks
__device__ __forceinline__ void stage_k(const f16* __restrict__ Kb, f16* ksm,
                                        int k0, int wave, int lane) {
#pragma unroll
    for (int i = 0; i < 2; ++i) {
        int dbase = (i * 8 + wave) * 1024;
        int d = dbase + lane * 16;
        int row = d >> 8;
        int cb = (d & 255) ^ ((row & 7) << 4);
        async_ld16(Kb + (long)(k0 + row) * HD + (cb >> 1), (char*)ksm + dbase);
    }
}
__device__ __forceinline__ void stage_v(const f16* __restrict__ Vb, f16* vsm,
                                        int k0, int wave, int lane) {
#pragma unroll
    for (int i = 0; i < 2; ++i) {
        int dbase = (i * 8 + wave) * 1024;
        int d = dbase + lane * 16;
        int row = d >> 7;
        int cb = (d & 127) ^ ((row & 7) << 4);
        async_ld16(Vb + (long)row * Sn + k0 + (cb >> 1), (char*)vsm + dbase);
    }
}

__global__ __launch_bounds__(512) void k_attn(
    const f16* __restrict__ Q, const f16* __restrict__ K,
    const f16* __restrict__ Vt, f16* __restrict__ O) {
    __shared__ __align__(16) f16 Ksm[2][64 * 128];   // 32KB
    __shared__ __align__(16) f16 Vsm[2][128 * 64];   // 32KB

    // grid 512: id = ((b*4 + hg)*8 + pos)*8 + kvh; pos pairs (heavy, light)
    const int id = blockIdx.x;
    const int kvh = id & 7;                 // XCD-local KV
    const int r_ = id >> 3;
    const int pos = r_ & 7;
    const int qt = (pos & 1) ? (pos >> 1) : (7 - (pos >> 1)); // 7,0,6,1,5,2,4,3
    const int hg = (r_ >> 3) & 3;
    const int b  = r_ >> 5;
    const int h  = kvh * 4 + hg;
    const int q0 = qt * 256;
    const int t = threadIdx.x, lane = t & 63, wave = t >> 6;
    const int q0w = q0 + wave * 32;
    const int lq = lane & 31, hi = lane >> 5;

    const f16* Qb = Q + ((long)(b * NH + h) * Sn) * HD;
    const f16* Kb = K + ((long)(b * NKV + kvh) * Sn) * HD;
    const f16* Vb = Vt + ((long)(b * NKV + kvh) * HD) * Sn;

    f16x8 qf[8];
#pragma unroll
    for (int s = 0; s < 8; ++s)
        qf[s] = *(const f16x8*)&Qb[(long)(q0w + lq) * HD + 16 * s + 8 * hi];

    f32x16 oacc[4] = {};
    float mrun = -1e30f, lrun = 0.f;

    const int nt = q0 / 64 + 4;   // cover q0+255
    stage_k(Kb, Ksm[0], 0, wave, lane);
    stage_v(Vb, Vsm[0], 0, wave, lane);

    for (int kt = 0; kt < nt; ++kt) {
        const int k0 = kt * 64;
        const int cur = kt & 1;
        if (kt + 1 < nt) {
            stage_k(Kb, Ksm[cur ^ 1], (kt + 1) * 64, wave, lane);
            stage_v(Vb, Vsm[cur ^ 1], (kt + 1) * 64, wave, lane);
            asm volatile("s_waitcnt vmcnt(4)" ::: "memory"); // cur tile landed
        } else {
            asm volatile("s_waitcnt vmcnt(0)" ::: "memory");
        }
        __builtin_amdgcn_s_barrier();

        if (k0 <= q0w + 31) {
            f32x16 st[2] = {};
#pragma unroll
            for (int s = 0; s < 8; ++s) {
                f16x8 kf0 = ld_sw256(Ksm[cur], lq,      16 * s + 8 * hi);
                f16x8 kf1 = ld_sw256(Ksm[cur], 32 + lq, 16 * s + 8 * hi);
                st[0] = __builtin_amdgcn_mfma_f32_32x32x16_f16(kf0, qf[s], st[0], 0, 0, 0);
                st[1] = __builtin_amdgcn_mfma_f32_32x32x16_f16(kf1, qf[s], st[1], 0, 0, 0);
            }
            const bool full = (k0 + 63 <= q0w);
            if (!full) {
#pragma unroll
                for (int mt = 0; mt < 2; ++mt)
#pragma unroll
                    for (int r = 0; r < 16; ++r) {
                        int kvv = k0 + 32 * mt + (r & 3) + 8 * (r >> 2) + 4 * hi;
                        if (kvv > q0w + lq) st[mt][r] = -1e30f;
                    }
            }
            float pm = st[0][0];
#pragma unroll
            for (int r = 1; r < 16; ++r) pm = fmaxf(pm, st[0][r]);
#pragma unroll
            for (int r = 0; r < 16; ++r) pm = fmaxf(pm, st[1][r]);
            pm = fmaxf(pm, __shfl_xor(pm, 32, 64));
            if (__any(pm > mrun + 8.f)) {
                float mn = fmaxf(mrun, pm);
                float sc = fexp2(mrun - mn);
                mrun = mn;
                lrun *= sc;
                float scr[16];
#pragma unroll
                for (int r = 0; r < 16; ++r)
                    scr[r] = __shfl(sc, (r & 3) + 8 * (r >> 2) + 4 * hi, 64);
#pragma unroll
                for (int db = 0; db < 4; ++db)
#pragma unroll
                    for (int r = 0; r < 16; ++r)
                        oacc[db][r] *= scr[r];
            }
            unsigned pw[2][8];
#pragma unroll
            for (int mt = 0; mt < 2; ++mt)
#pragma unroll
                for (int i = 0; i < 8; ++i) {
                    float p0 = fexp2(st[mt][2 * i]     - mrun);
                    float p1 = fexp2(st[mt][2 * i + 1] - mrun);
                    lrun += p0 + p1;
                    pw[mt][i] = pk2(p0, p1);
                }
#pragma unroll
            for (int s = 0; s < 4; ++s) {
                const int mt = s >> 1, sl = s & 1;
                unsigned a0 = pw[mt][4 * sl], a1 = pw[mt][4 * sl + 1];
                unsigned a2 = pw[mt][4 * sl + 2], a3 = pw[mt][4 * sl + 3];
                unsigned own0 = hi ? a2 : a0, own1 = hi ? a3 : a1;
                unsigned snd0 = hi ? a0 : a2, snd1 = hi ? a1 : a3;
                unsigned rx0 = (unsigned)__shfl_xor((int)snd0, 32, 64);
                unsigned rx1 = (unsigned)__shfl_xor((int)snd1, 32, 64);
                union { unsigned u[4]; f16x8 v; } pu;
                pu.u[0] = hi ? rx0 : own0;
                pu.u[1] = hi ? rx1 : own1;
                pu.u[2] = hi ? own0 : rx0;
                pu.u[3] = hi ? own1 : rx1;
#pragma unroll
                for (int db = 0; db < 4; ++db) {
                    f16x8 vf = ld_sw128(Vsm[cur], 32 * db + lq, 16 * s + 8 * hi);
                    oacc[db] = __builtin_amdgcn_mfma_f32_32x32x16_f16(pu.v, vf, oacc[db], 0, 0, 0);
                }
            }
        }
        __builtin_amdgcn_s_barrier();
    }

    lrun += __shfl_xor(lrun, 32, 64);
    float li = 1.f / lrun;
    float ir[16];
#pragma unroll
    for (int r = 0; r < 16; ++r)
        ir[r] = __shfl(li, (r & 3) + 8 * (r >> 2) + 4 * hi, 64);
#pragma unroll
    for (int db = 0; db < 4; ++db)
#pragma unroll
        for (int r = 0; r < 16; ++r) {
            int qloc = (r & 3) + 8 * (r >> 2) + 4 * hi;
            long tok = (long)b * Sn + q0w + qloc;
            O[tok * (NH * HD) + h * HD + 32 * db + lq] = (f16)(oacc[db][r] * ir[r]);
        }
}

// sentinel if workspace too small
__global__ void k_ws_fail(float* out) { out[0] = 1.0e9f; }

// ---------------------------------------------------------------------------
extern "C" void kernel_launch(void* const* d_in, const int* in_sizes, int n_in,
                              void* d_out, int out_size, void* d_ws, size_t ws_size,
                              hipStream_t stream) {
    const float* hs   = (const float*)d_in[0];
    const float* wq   = (const float*)d_in[1];
    const float* wk   = (const float*)d_in[2];
    const float* wv   = (const float*)d_in[3];
    const float* wo   = (const float*)d_in[4];
    const float* cosb = (const float*)d_in[5];
    const float* sinb = (const float*)d_in[6];
    float* out = (float*)d_out;

    const size_t OFF_WQKV = 0;
    const size_t OFF_WO   = 50331648;
    const size_t OFF_HID  = 83886080;
    const size_t OFF_Q    = 117440512;
    const size_t OFF_K    = 150994944;
    const size_t OFF_VT   = 167772160;
    const size_t WS_NEED  = 176160768;
    if (ws_size < WS_NEED) { k_ws_fail<<<1, 1, 0, stream>>>(out); return; }

    char* ws = (char*)d_ws;
    f16* wqkv_t = (f16*)(ws + OFF_WQKV);
    f16* wo_t   = (f16*)(ws + OFF_WO);
    f16* hid    = (f16*)(ws + OFF_HID);
    f16* qb     = (f16*)(ws + OFF_Q);
    f16* kb     = (f16*)(ws + OFF_K);
    f16* vtb    = (f16*)(ws + OFF_VT);

    dim3 tb64(64, 4);
    k_cvt<<<dim3(16777216 / (256 * 8)), 256, 0, stream>>>(hs, hid, 16777216L);
    k_tcvt<<<dim3(64, 64), tb64, 0, stream>>>(wq, wqkv_t, 4096, 4096, 4096);
    k_tcvt<<<dim3(16, 64), tb64, 0, stream>>>(wk, wqkv_t + (long)4096 * 4096, 4096, 1024, 4096);
    k_tcvt<<<dim3(16, 64), tb64, 0, stream>>>(wv, wqkv_t + (long)5120 * 4096, 4096, 1024, 4096);
    k_tcvt<<<dim3(64, 64), tb64, 0, stream>>>(wo, wo_t, 4096, 4096, 4096);
    k_gemm_qkv<<<dim3(384), 512, 0, stream>>>(hid, wqkv_t, qb, kb, vtb, cosb, sinb);
    k_attn<<<dim3(512), 512, 0, stream>>>(qb, kb, vtb, hid);
    k_gemm_out<<<dim3(256), 512, 0, stream>>>(hid, wo_t, out);
}

// Round 14
// 561.852 us; speedup vs baseline: 2.0916x; 1.0340x over previous
//
#include <hip/hip_runtime.h>

// ============================================================================
// GLM4-MoE attention layer on MI355X (gfx950), fp16 MFMA pipeline.
// Round 14: prep merge. The 5 independent memory-bound prep kernels
// (f32->f16 convert + 4 transpose-converts) become ONE grid-partitioned
// dispatch (18432 blocks): kills ~4 launch/drain bubbles (~20 us) with zero
// algorithmic change. Pipeline is now 4 dispatches:
//   k_prep -> k_gemm_qkv (RoPE+V^T fused) -> k_attn (QBLK=256) -> k_gemm_out
// GEMM = r11 8-phase/counted-vmcnt 256x256 (35-39% MfmaUtil plateau, 7
// structures tried — closed). Attention = r13 (32x32 MFMA, in-register P,
// QBLK=256, heavy/light pairing). Epilogues = r12 (RoPE, V^T, QSC fused).
// ============================================================================

typedef _Float16 f16;
typedef _Float16 f16x8 __attribute__((ext_vector_type(8)));
typedef float f32x4 __attribute__((ext_vector_type(4)));
typedef float f32x16 __attribute__((ext_vector_type(16)));

static constexpr int Bn = 2, Sn = 2048, Hn = 4096, NH = 32, NKV = 8, HD = 128;
static constexpr float QSC = 0.08838834764831845f * 1.44269504088896340736f; // 1/sqrt(128)*log2e

#define AS1 __attribute__((address_space(1)))
#define AS3 __attribute__((address_space(3)))

__device__ __forceinline__ void async_ld16(const void* g, void* l) {
    __builtin_amdgcn_global_load_lds((const AS1 void*)g, (AS3 void*)l, 16, 0, 0);
}

__device__ __forceinline__ unsigned pk2(float a, float b) {
    unsigned r;
    asm("v_cvt_pkrtz_f16_f32 %0, %1, %2" : "=v"(r) : "v"(a), "v"(b));
    return r;
}

// native exp2: v_exp_f32 computes 2^x
__device__ __forceinline__ float fexp2(float x) {
    float r;
    asm("v_exp_f32 %0, %1" : "=v"(r) : "v"(x));
    return r;
}

// ---------------------------------------------------------------------------
// Merged prep: blocks [0,8192) = hidden f32->f16 convert (8 elems/thread);
// blocks [8192,18432) = four 64x64 transpose-converts (wq/wk/wv/wo).
__global__ __launch_bounds__(256) void k_prep(
    const float* __restrict__ hs, f16* __restrict__ hid,
    const float* __restrict__ wq, const float* __restrict__ wk,
    const float* __restrict__ wv, const float* __restrict__ wo,
    f16* __restrict__ wqkv_t, f16* __restrict__ wo_t) {
    int bid = blockIdx.x;
    if (bid < 8192) {
        long i = ((long)bid * 256 + threadIdx.x) * 8;
        float4 a = *(const float4*)(hs + i);
        float4 b = *(const float4*)(hs + i + 4);
        f16x8 o = {(f16)a.x, (f16)a.y, (f16)a.z, (f16)a.w,
                   (f16)b.x, (f16)b.y, (f16)b.z, (f16)b.w};
        *(f16x8*)(hid + i) = o;
        return;
    }
    bid -= 8192;
    const float* src;
    f16* dst;
    int N, bx, by;
    if (bid < 4096)      { src = wq; dst = wqkv_t;                    N = 4096; bx = bid & 63; by = bid >> 6; }
    else if (bid < 5120) { bid -= 4096; src = wk; dst = wqkv_t + (long)4096 * 4096; N = 1024; bx = bid & 15; by = bid >> 4; }
    else if (bid < 6144) { bid -= 5120; src = wv; dst = wqkv_t + (long)5120 * 4096; N = 1024; bx = bid & 15; by = bid >> 4; }
    else                 { bid -= 6144; src = wo; dst = wo_t;         N = 4096; bx = bid & 63; by = bid >> 6; }
    __shared__ float tile[64][65];
    const int k0 = by * 64, n0 = bx * 64;
    const int tx = threadIdx.x & 63, ty = threadIdx.x >> 6;   // (64,4)
#pragma unroll
    for (int r = ty; r < 64; r += 4)
        tile[r][tx] = src[(long)(k0 + r) * N + (n0 + tx)];
    __syncthreads();
#pragma unroll
    for (int r = ty; r < 64; r += 4)
        dst[(long)(n0 + r) * 4096 + (k0 + tx)] = (f16)tile[tx][r];
}

// ---------------------------------------------------------------------------
// 256x256 GEMM core (r11-proven), BK=64, 8 waves, K=4096. 8-phase interleave,
// counted vmcnt(6) once per K-tile. See r11 header for the dead-region ledger.
__device__ __forceinline__ void gemm256_core(
    const f16* __restrict__ A, const f16* __restrict__ Bt,
    char* L, int m0, int n0, f32x4 acc[8][4]) {
    const int t = threadIdx.x, lane = t & 63, wave = t >> 6;
    const int wm = wave >> 2, wn = wave & 3;
    const int fr = lane & 15, fg = lane >> 4;

    const int srowL = wave * 8 + (lane >> 3);
    const int scol  = 8 * ((lane & 7) ^ (lane >> 3));
    const f16* ga = A  + (long)(m0 + srowL) * 4096 + scol;
    const f16* gb = Bt + (long)(n0 + srowL) * 4096 + scol;
    const int woff = wave * 1024;

    auto ST = [&](int sel, int c, int row0, int kt) {
        const f16* g = sel ? gb : ga;
        async_ld16(g + (long)row0 * 4096 + kt * 64,
                   L + c * 65536 + sel * 32768 + row0 * 128 + woff);
    };

    ST(0, 0, 0, 0);   ST(0, 0, 64, 0);  ST(0, 0, 128, 0); ST(0, 0, 192, 0);
    ST(1, 0, 0, 0);   ST(1, 0, 64, 0);  ST(1, 0, 128, 0); ST(1, 0, 192, 0);
    ST(1, 1, 0, 1);   ST(1, 1, 64, 1);  ST(1, 1, 128, 1); ST(1, 1, 192, 1);
    ST(0, 1, 0, 1);   ST(0, 1, 128, 1);
    asm volatile("s_waitcnt vmcnt(6)" ::: "memory");
    __builtin_amdgcn_s_barrier();

    const int abase = wm * 128;
    const int bbase = wn * 64;

    for (int tt = 0; tt < 64; ++tt) {
        const int c = tt & 1;
        const char* bufA = L + c * 65536;
        const char* bufB = bufA + 32768;
        f16x8 bf[2][4];

#pragma unroll
        for (int q = 0; q < 4; ++q) {
            if (q == 0) {
#pragma unroll
                for (int ks = 0; ks < 2; ++ks)
#pragma unroll
                    for (int nf = 0; nf < 4; ++nf) {
                        int r = bbase + nf * 16 + fr;
                        bf[ks][nf] = *(const f16x8*)(bufB + r * 128 +
                                        ((ks * 64 + 16 * fg) ^ ((r & 7) << 4)));
                    }
            }
            f16x8 af[2][2];
#pragma unroll
            for (int ks = 0; ks < 2; ++ks)
#pragma unroll
                for (int i = 0; i < 2; ++i) {
                    int r = abase + (2 * q + i) * 16 + fr;
                    af[ks][i] = *(const f16x8*)(bufA + r * 128 +
                                    ((ks * 64 + 16 * fg) ^ ((r & 7) << 4)));
                }
            if (q == 0) { if (tt + 1 < 64) { ST(0, c ^ 1,  64, tt + 1);
                                             ST(0, c ^ 1, 192, tt + 1); } }
            if (q == 1) { if (tt + 2 < 64) { ST(1, c,   0, tt + 2);
                                             ST(1, c,  64, tt + 2); } }
            if (q == 2) { if (tt + 2 < 64) { ST(1, c, 128, tt + 2);
                                             ST(1, c, 192, tt + 2); } }
            if (q == 3) { if (tt + 2 < 64) { ST(0, c,   0, tt + 2);
                                             ST(0, c, 128, tt + 2); } }
            __builtin_amdgcn_s_barrier();
            __builtin_amdgcn_s_setprio(1);
#pragma unroll
            for (int ks = 0; ks < 2; ++ks)
#pragma unroll
                for (int i = 0; i < 2; ++i)
#pragma unroll
                    for (int nf = 0; nf < 4; ++nf)
                        acc[2 * q + i][nf] = __builtin_amdgcn_mfma_f32_16x16x32_f16(
                            af[ks][i], bf[ks][nf], acc[2 * q + i][nf], 0, 0, 0);
            __builtin_amdgcn_s_setprio(0);
            if (q == 3) {
                if (tt < 62)       asm volatile("s_waitcnt vmcnt(6)" ::: "memory");
                else if (tt == 62) asm volatile("s_waitcnt vmcnt(0)" ::: "memory");
            }
            __builtin_amdgcn_s_barrier();
        }
    }
}

// GEMM1: hidden @ Wqkv^T -> q (RoPE+scale fused), k (RoPE fused), V^T (fused).
__global__ __launch_bounds__(512) void k_gemm_qkv(
    const f16* __restrict__ A, const f16* __restrict__ Bt,
    f16* __restrict__ q, f16* __restrict__ kk_, f16* __restrict__ vt,
    const float* __restrict__ cosb, const float* __restrict__ sinb) {
    __shared__ __align__(16) char L[131072];
    const int bid = blockIdx.x;                    // 384 = 16m x 24n
    const int swzb = (bid & 7) * 48 + (bid >> 3);  // XCD-bijective
    const int m0 = (swzb / 24) * 256, n0 = (swzb % 24) * 256;
    f32x4 acc[8][4] = {};
    gemm256_core(A, Bt, L, m0, n0, acc);

    const int lane = threadIdx.x & 63, wave = threadIdx.x >> 6;
    const int wm = wave >> 2, wn = wave & 3;
    const int fr = lane & 15, fg = lane >> 4;
#pragma unroll
    for (int mf = 0; mf < 8; ++mf) {
        int r0 = m0 + wm * 128 + mf * 16 + 4 * fg;
        int b = r0 >> 11, s = r0 & (Sn - 1);   // r0 multiple of 4: same b, s..s+3
        const float* cb_ = cosb + ((long)b * Sn + s) * 64;
        const float* sb_ = sinb + ((long)b * Sn + s) * 64;
#pragma unroll
        for (int nf = 0; nf < 4; ++nf) {
            int cc = n0 + wn * 64 + nf * 16 + fr;
            int d = cc & 127;
            if (cc < 5120) {
                float vals[4];
#pragma unroll
                for (int e = 0; e < 4; ++e) vals[e] = acc[mf][nf][e];
                if (d < 64) {
                    int ci = d >> 1;
                    bool odd = (d & 1);
#pragma unroll
                    for (int e = 0; e < 4; ++e) {
                        float p = __shfl_xor(vals[e], 1, 64);   // lane^1 = d^1
                        float c = cb_[e * 64 + ci], sv = sb_[e * 64 + ci];
                        vals[e] = odd ? (vals[e] * c + p * sv)
                                      : (vals[e] * c - p * sv);
                    }
                }
                if (cc < 4096) {
                    int h = cc >> 7;
#pragma unroll
                    for (int e = 0; e < 4; ++e)
                        q[(((long)b * NH + h) * Sn + s + e) * HD + d] =
                            (f16)(vals[e] * QSC);
                } else {
                    int h = (cc - 4096) >> 7;
#pragma unroll
                    for (int e = 0; e < 4; ++e)
                        kk_[(((long)b * NKV + h) * Sn + s + e) * HD + d] =
                            (f16)vals[e];
                }
            } else {
                int h = (cc - 5120) >> 7;
                uint2 w = {pk2(acc[mf][nf][0], acc[mf][nf][1]),
                           pk2(acc[mf][nf][2], acc[mf][nf][3])};
                *(uint2*)&vt[(((long)b * NKV + h) * HD + d) * Sn + s] = w;
            }
        }
    }
}

// GEMM2: attn_out @ wo^T -> d_out f32, 256 blocks (16x16)
__global__ __launch_bounds__(512) void k_gemm_out(
    const f16* __restrict__ A, const f16* __restrict__ Bt,
    float* __restrict__ out) {
    __shared__ __align__(16) char L[131072];
    const int bid = blockIdx.x;
    const int swzb = (bid & 7) * 32 + (bid >> 3);
    const int m0 = (swzb >> 4) * 256, n0 = (swzb & 15) * 256;
    f32x4 acc[8][4] = {};
    gemm256_core(A, Bt, L, m0, n0, acc);

    const int lane = threadIdx.x & 63, wave = threadIdx.x >> 6;
    const int wm = wave >> 2, wn = wave & 3;
    const int fr = lane & 15, fg = lane >> 4;
#pragma unroll
    for (int mf = 0; mf < 8; ++mf) {
        int r0 = m0 + wm * 128 + mf * 16 + 4 * fg;
#pragma unroll
        for (int nf = 0; nf < 4; ++nf) {
            int cc = n0 + wn * 64 + nf * 16 + fr;
#pragma unroll
            for (int e = 0; e < 4; ++e)
                out[(long)(r0 + e) * 4096 + cc] = acc[mf][nf][e];
        }
    }
}

// ---------------------------------------------------------------------------
// Flash attention v6 (r13-proven): QBLK=256 (8 waves x 32 q), 32x32x16 MFMA,
// in-register P via pk2 + shfl_xor(32); swapped QK^T (q lane-local softmax).
//   A: row=lane&31, k=8*(lane>>5)+e   B: k=8*(lane>>5)+e, col=lane&31
//   C: col=lane&31, row=(reg&3)+8*(reg>>2)+4*(lane>>5)

__device__ __forceinline__ f16x8 ld_sw256(const f16* base, int r, int c) {
    int byte = r * 256 + ((c * 2) ^ ((r & 7) << 4));
    return *(const f16x8*)((const char*)base + byte);
}
__device__ __forceinline__ f16x8 ld_sw128(const f16* base, int r, int c) {
    int byte = r * 128 + ((c * 2) ^ ((r & 7) << 4));
    return *(const f16x8*)((const char*)base + byte);
}

// K tile [64 kv][128 d] f16 = 16KB = 16 chunks; 8 waves x 2 chunks
__device__ __forceinline__ void stage_k(const f16* __restrict__ Kb, f16* ksm,
                                        int k0, int wave, int lane) {
#pragma unroll
    for (int i = 0; i < 2; ++i) {
        int dbase = (i * 8 + wave) * 1024;
        int d = dbase + lane * 16;
        int row = d >> 8;
        int cb = (d & 255) ^ ((row & 7) << 4);
        async_ld16(Kb + (long)(k0 + row) * HD + (cb >> 1), (char*)ksm + dbase);
    }
}
__device__ __forceinline__ void stage_v(const f16* __restrict__ Vb, f16* vsm,
                                        int k0, int wave, int lane) {
#pragma unroll
    for (int i = 0; i < 2; ++i) {
        int dbase = (i * 8 + wave) * 1024;
        int d = dbase + lane * 16;
        int row = d >> 7;
        int cb = (d & 127) ^ ((row & 7) << 4);
        async_ld16(Vb + (long)row * Sn + k0 + (cb >> 1), (char*)vsm + dbase);
    }
}

__global__ __launch_bounds__(512) void k_attn(
    const f16* __restrict__ Q, const f16* __restrict__ K,
    const f16* __restrict__ Vt, f16* __restrict__ O) {
    __shared__ __align__(16) f16 Ksm[2][64 * 128];   // 32KB
    __shared__ __align__(16) f16 Vsm[2][128 * 64];   // 32KB

    // grid 512: id = ((b*4 + hg)*8 + pos)*8 + kvh; pos pairs (heavy, light)
    const int id = blockIdx.x;
    const int kvh = id & 7;                 // XCD-local KV
    const int r_ = id >> 3;
    const int pos = r_ & 7;
    const int qt = (pos & 1) ? (pos >> 1) : (7 - (pos >> 1)); // 7,0,6,1,5,2,4,3
    const int hg = (r_ >> 3) & 3;
    const int b  = r_ >> 5;
    const int h  = kvh * 4 + hg;
    const int q0 = qt * 256;
    const int t = threadIdx.x, lane = t & 63, wave = t >> 6;
    const int q0w = q0 + wave * 32;
    const int lq = lane & 31, hi = lane >> 5;

    const f16* Qb = Q + ((long)(b * NH + h) * Sn) * HD;
    const f16* Kb = K + ((long)(b * NKV + kvh) * Sn) * HD;
    const f16* Vb = Vt + ((long)(b * NKV + kvh) * HD) * Sn;

    f16x8 qf[8];
#pragma unroll
    for (int s = 0; s < 8; ++s)
        qf[s] = *(const f16x8*)&Qb[(long)(q0w + lq) * HD + 16 * s + 8 * hi];

    f32x16 oacc[4] = {};
    float mrun = -1e30f, lrun = 0.f;

    const int nt = q0 / 64 + 4;   // cover q0+255
    stage_k(Kb, Ksm[0], 0, wave, lane);
    stage_v(Vb, Vsm[0], 0, wave, lane);

    for (int kt = 0; kt < nt; ++kt) {
        const int k0 = kt * 64;
        const int cur = kt & 1;
        if (kt + 1 < nt) {
            stage_k(Kb, Ksm[cur ^ 1], (kt + 1) * 64, wave, lane);
            stage_v(Vb, Vsm[cur ^ 1], (kt + 1) * 64, wave, lane);
            asm volatile("s_waitcnt vmcnt(4)" ::: "memory"); // cur tile landed
        } else {
            asm volatile("s_waitcnt vmcnt(0)" ::: "memory");
        }
        __builtin_amdgcn_s_barrier();

        if (k0 <= q0w + 31) {
            f32x16 st[2] = {};
#pragma unroll
            for (int s = 0; s < 8; ++s) {
                f16x8 kf0 = ld_sw256(Ksm[cur], lq,      16 * s + 8 * hi);
                f16x8 kf1 = ld_sw256(Ksm[cur], 32 + lq, 16 * s + 8 * hi);
                st[0] = __builtin_amdgcn_mfma_f32_32x32x16_f16(kf0, qf[s], st[0], 0, 0, 0);
                st[1] = __builtin_amdgcn_mfma_f32_32x32x16_f16(kf1, qf[s], st[1], 0, 0, 0);
            }
            const bool full = (k0 + 63 <= q0w);
            if (!full) {
#pragma unroll
                for (int mt = 0; mt < 2; ++mt)
#pragma unroll
                    for (int r = 0; r < 16; ++r) {
                        int kvv = k0 + 32 * mt + (r & 3) + 8 * (r >> 2) + 4 * hi;
                        if (kvv > q0w + lq) st[mt][r] = -1e30f;
                    }
            }
            float pm = st[0][0];
#pragma unroll
            for (int r = 1; r < 16; ++r) pm = fmaxf(pm, st[0][r]);
#pragma unroll
            for (int r = 0; r < 16; ++r) pm = fmaxf(pm, st[1][r]);
            pm = fmaxf(pm, __shfl_xor(pm, 32, 64));
            if (__any(pm > mrun + 8.f)) {
                float mn = fmaxf(mrun, pm);
                float sc = fexp2(mrun - mn);
                mrun = mn;
                lrun *= sc;
                float scr[16];
#pragma unroll
                for (int r = 0; r < 16; ++r)
                    scr[r] = __shfl(sc, (r & 3) + 8 * (r >> 2) + 4 * hi, 64);
#pragma unroll
                for (int db = 0; db < 4; ++db)
#pragma unroll
                    for (int r = 0; r < 16; ++r)
                        oacc[db][r] *= scr[r];
            }
            unsigned pw[2][8];
#pragma unroll
            for (int mt = 0; mt < 2; ++mt)
#pragma unroll
                for (int i = 0; i < 8; ++i) {
                    float p0 = fexp2(st[mt][2 * i]     - mrun);
                    float p1 = fexp2(st[mt][2 * i + 1] - mrun);
                    lrun += p0 + p1;
                    pw[mt][i] = pk2(p0, p1);
                }
#pragma unroll
            for (int s = 0; s < 4; ++s) {
                const int mt = s >> 1, sl = s & 1;
                unsigned a0 = pw[mt][4 * sl], a1 = pw[mt][4 * sl + 1];
                unsigned a2 = pw[mt][4 * sl + 2], a3 = pw[mt][4 * sl + 3];
                unsigned own0 = hi ? a2 : a0, own1 = hi ? a3 : a1;
                unsigned snd0 = hi ? a0 : a2, snd1 = hi ? a1 : a3;
                unsigned rx0 = (unsigned)__shfl_xor((int)snd0, 32, 64);
                unsigned rx1 = (unsigned)__shfl_xor((int)snd1, 32, 64);
                union { unsigned u[4]; f16x8 v; } pu;
                pu.u[0] = hi ? rx0 : own0;
                pu.u[1] = hi ? rx1 : own1;
                pu.u[2] = hi ? own0 : rx0;
                pu.u[3] = hi ? own1 : rx1;
#pragma unroll
                for (int db = 0; db < 4; ++db) {
                    f16x8 vf = ld_sw128(Vsm[cur], 32 * db + lq, 16 * s + 8 * hi);
                    oacc[db] = __builtin_amdgcn_mfma_f32_32x32x16_f16(pu.v, vf, oacc[db], 0, 0, 0);
                }
            }
        }
        __builtin_amdgcn_s_barrier();
    }

    lrun += __shfl_xor(lrun, 32, 64);
    float li = 1.f / lrun;
    float ir[16];
#pragma unroll
    for (int r = 0; r < 16; ++r)
        ir[r] = __shfl(li, (r & 3) + 8 * (r >> 2) + 4 * hi, 64);
#pragma unroll
    for (int db = 0; db < 4; ++db)
#pragma unroll
        for (int r = 0; r < 16; ++r) {
            int qloc = (r & 3) + 8 * (r >> 2) + 4 * hi;
            long tok = (long)b * Sn + q0w + qloc;
            O[tok * (NH * HD) + h * HD + 32 * db + lq] = (f16)(oacc[db][r] * ir[r]);
        }
}

// sentinel if workspace too small
__global__ void k_ws_fail(float* out) { out[0] = 1.0e9f; }

// ---------------------------------------------------------------------------
extern "C" void kernel_launch(void* const* d_in, const int* in_sizes, int n_in,
                              void* d_out, int out_size, void* d_ws, size_t ws_size,
                              hipStream_t stream) {
    const float* hs   = (const float*)d_in[0];
    const float* wq   = (const float*)d_in[1];
    const float* wk   = (const float*)d_in[2];
    const float* wv   = (const float*)d_in[3];
    const float* wo   = (const float*)d_in[4];
    const float* cosb = (const float*)d_in[5];
    const float* sinb = (const float*)d_in[6];
    float* out = (float*)d_out;

    const size_t OFF_WQKV = 0;
    const size_t OFF_WO   = 50331648;
    const size_t OFF_HID  = 83886080;
    const size_t OFF_Q    = 117440512;
    const size_t OFF_K    = 150994944;
    const size_t OFF_VT   = 167772160;
    const size_t WS_NEED  = 176160768;
    if (ws_size < WS_NEED) { k_ws_fail<<<1, 1, 0, stream>>>(out); return; }

    char* ws = (char*)d_ws;
    f16* wqkv_t = (f16*)(ws + OFF_WQKV);
    f16* wo_t   = (f16*)(ws + OFF_WO);
    f16* hid    = (f16*)(ws + OFF_HID);
    f16* qb     = (f16*)(ws + OFF_Q);
    f16* kb     = (f16*)(ws + OFF_K);
    f16* vtb    = (f16*)(ws + OFF_VT);

    // 1 prep dispatch: 8192 cvt blocks + (4096+1024+1024+4096) tcvt blocks
    k_prep<<<dim3(18432), 256, 0, stream>>>(hs, hid, wq, wk, wv, wo, wqkv_t, wo_t);
    k_gemm_qkv<<<dim3(384), 512, 0, stream>>>(hid, wqkv_t, qb, kb, vtb, cosb, sinb);
    k_attn<<<dim3(512), 512, 0, stream>>>(qb, kb, vtb, hid);
    k_gemm_out<<<dim3(256), 512, 0, stream>>>(hid, wo_t, out);
}

// Round 15
// 543.981 us; speedup vs baseline: 2.1603x; 1.0329x over previous
//
#include <hip/hip_runtime.h>

// ============================================================================
// GLM4-MoE attention layer on MI355X (gfx950), fp16 MFMA pipeline.
// Round 15: GEMM1 re-tiled 256x192 -> 512 blocks = exactly 2 FULL dispatch
// rounds (was 384 blocks = 2 rounds with the 2nd half-empty; ~25% of GEMM1's
// wall time was idle CUs). 8-phase core templated on NTILE: NF=3 B-frags,
// 7 loads/tile, counted vmcnt(5) (ledger re-derived, mirrors r11's proven
// vmcnt(6) for NF=4). GEMM2 stays NTILE=256 (256 blocks = 1 full round).
// Attention (r13, QBLK=256, in-reg P), prep merge (r14), fused RoPE/V^T (r12)
// unchanged.
// ============================================================================

typedef _Float16 f16;
typedef _Float16 f16x8 __attribute__((ext_vector_type(8)));
typedef float f32x4 __attribute__((ext_vector_type(4)));
typedef float f32x16 __attribute__((ext_vector_type(16)));

static constexpr int Bn = 2, Sn = 2048, Hn = 4096, NH = 32, NKV = 8, HD = 128;
static constexpr float QSC = 0.08838834764831845f * 1.44269504088896340736f; // 1/sqrt(128)*log2e

#define AS1 __attribute__((address_space(1)))
#define AS3 __attribute__((address_space(3)))

__device__ __forceinline__ void async_ld16(const void* g, void* l) {
    __builtin_amdgcn_global_load_lds((const AS1 void*)g, (AS3 void*)l, 16, 0, 0);
}

__device__ __forceinline__ unsigned pk2(float a, float b) {
    unsigned r;
    asm("v_cvt_pkrtz_f16_f32 %0, %1, %2" : "=v"(r) : "v"(a), "v"(b));
    return r;
}

// native exp2: v_exp_f32 computes 2^x
__device__ __forceinline__ float fexp2(float x) {
    float r;
    asm("v_exp_f32 %0, %1" : "=v"(r) : "v"(x));
    return r;
}

// ---------------------------------------------------------------------------
// Merged prep: blocks [0,8192) = hidden f32->f16 convert (8 elems/thread);
// blocks [8192,18432) = four 64x64 transpose-converts (wq/wk/wv/wo).
__global__ __launch_bounds__(256) void k_prep(
    const float* __restrict__ hs, f16* __restrict__ hid,
    const float* __restrict__ wq, const float* __restrict__ wk,
    const float* __restrict__ wv, const float* __restrict__ wo,
    f16* __restrict__ wqkv_t, f16* __restrict__ wo_t) {
    int bid = blockIdx.x;
    if (bid < 8192) {
        long i = ((long)bid * 256 + threadIdx.x) * 8;
        float4 a = *(const float4*)(hs + i);
        float4 b = *(const float4*)(hs + i + 4);
        f16x8 o = {(f16)a.x, (f16)a.y, (f16)a.z, (f16)a.w,
                   (f16)b.x, (f16)b.y, (f16)b.z, (f16)b.w};
        *(f16x8*)(hid + i) = o;
        return;
    }
    bid -= 8192;
    const float* src;
    f16* dst;
    int N, bx, by;
    if (bid < 4096)      { src = wq; dst = wqkv_t;                    N = 4096; bx = bid & 63; by = bid >> 6; }
    else if (bid < 5120) { bid -= 4096; src = wk; dst = wqkv_t + (long)4096 * 4096; N = 1024; bx = bid & 15; by = bid >> 4; }
    else if (bid < 6144) { bid -= 5120; src = wv; dst = wqkv_t + (long)5120 * 4096; N = 1024; bx = bid & 15; by = bid >> 4; }
    else                 { bid -= 6144; src = wo; dst = wo_t;         N = 4096; bx = bid & 63; by = bid >> 6; }
    __shared__ float tile[64][65];
    const int k0 = by * 64, n0 = bx * 64;
    const int tx = threadIdx.x & 63, ty = threadIdx.x >> 6;   // (64,4)
#pragma unroll
    for (int r = ty; r < 64; r += 4)
        tile[r][tx] = src[(long)(k0 + r) * N + (n0 + tx)];
    __syncthreads();
#pragma unroll
    for (int r = ty; r < 64; r += 4)
        dst[(long)(n0 + r) * 4096 + (k0 + tx)] = (f16)tile[tx][r];
}

// ---------------------------------------------------------------------------
// 256xNTILE GEMM core (r11-proven structure), BK=64, 8 waves (2M x 4N),
// K=4096. 8-phase interleave, counted vmcnt once per K-tile (never 0
// mid-loop). NTILE=256: NF=4, 8 loads/tile, vmcnt(6) [r11 verified].
// NTILE=192: NF=3, 7 loads/tile, vmcnt(5) [same ledger derivation].
// LDS: buf c at c*BUF; A [256r][128B] at +0; B [NTILEr][128B] at +32768.
template<int NTILE>
__device__ __forceinline__ void gemm_core(
    const f16* __restrict__ A, const f16* __restrict__ Bt,
    char* L, int m0, int n0, f32x4 acc[8][NTILE / 64]) {
    constexpr int NF  = NTILE / 64;          // B frags per wave per kstep
    constexpr int BUF = 32768 + NTILE * 128; // bytes per buffer
    const int t = threadIdx.x, lane = t & 63, wave = t >> 6;
    const int wm = wave >> 2, wn = wave & 3;
    const int fr = lane & 15, fg = lane >> 4;

    const int srowL = wave * 8 + (lane >> 3);
    const int scol  = 8 * ((lane & 7) ^ (lane >> 3));
    const f16* ga = A  + (long)(m0 + srowL) * 4096 + scol;
    const f16* gb = Bt + (long)(n0 + srowL) * 4096 + scol;
    const int woff = wave * 1024;

    auto ST = [&](int sel, int c, int row0, int kt) {
        const f16* g = sel ? gb : ga;
        async_ld16(g + (long)row0 * 4096 + kt * 64,
                   L + c * BUF + sel * 32768 + row0 * 128 + woff);
    };

    // prologue: tile0 complete; tile1 B-all + A rows {0,128}
    ST(0, 0, 0, 0); ST(0, 0, 64, 0); ST(0, 0, 128, 0); ST(0, 0, 192, 0);
#pragma unroll
    for (int r = 0; r < NTILE; r += 64) ST(1, 0, r, 0);
#pragma unroll
    for (int r = 0; r < NTILE; r += 64) ST(1, 1, r, 1);
    ST(0, 1, 0, 1); ST(0, 1, 128, 1);
    if constexpr (NF == 4) asm volatile("s_waitcnt vmcnt(6)" ::: "memory");
    else                   asm volatile("s_waitcnt vmcnt(5)" ::: "memory");
    __builtin_amdgcn_s_barrier();

    const int abase = wm * 128;
    const int bbase = wn * (NF * 16);

    for (int tt = 0; tt < 64; ++tt) {
        const int c = tt & 1;
        const char* bufA = L + c * BUF;
        const char* bufB = bufA + 32768;
        f16x8 bf[2][NF];

#pragma unroll
        for (int q = 0; q < 4; ++q) {
            if (q == 0) {
#pragma unroll
                for (int ks = 0; ks < 2; ++ks)
#pragma unroll
                    for (int nf = 0; nf < NF; ++nf) {
                        int r = bbase + nf * 16 + fr;
                        bf[ks][nf] = *(const f16x8*)(bufB + r * 128 +
                                        ((ks * 64 + 16 * fg) ^ ((r & 7) << 4)));
                    }
            }
            f16x8 af[2][2];
#pragma unroll
            for (int ks = 0; ks < 2; ++ks)
#pragma unroll
                for (int i = 0; i < 2; ++i) {
                    int r = abase + (2 * q + i) * 16 + fr;
                    af[ks][i] = *(const f16x8*)(bufA + r * 128 +
                                    ((ks * 64 + 16 * fg) ^ ((r & 7) << 4)));
                }
            if (q == 0) { if (tt + 1 < 64) { ST(0, c ^ 1,  64, tt + 1);
                                             ST(0, c ^ 1, 192, tt + 1); } }
            if (q == 1) { if (tt + 2 < 64) { ST(1, c,   0, tt + 2);
                                             ST(1, c,  64, tt + 2); } }
            if (q == 2) { if (tt + 2 < 64) { ST(1, c, 128, tt + 2);
                                             if constexpr (NF == 4)
                                                 ST(1, c, 192, tt + 2); } }
            if (q == 3) { if (tt + 2 < 64) { ST(0, c,   0, tt + 2);
                                             ST(0, c, 128, tt + 2); } }
            __builtin_amdgcn_s_barrier();
            __builtin_amdgcn_s_setprio(1);
#pragma unroll
            for (int ks = 0; ks < 2; ++ks)
#pragma unroll
                for (int i = 0; i < 2; ++i)
#pragma unroll
                    for (int nf = 0; nf < NF; ++nf)
                        acc[2 * q + i][nf] = __builtin_amdgcn_mfma_f32_16x16x32_f16(
                            af[ks][i], bf[ks][nf], acc[2 * q + i][nf], 0, 0, 0);
            __builtin_amdgcn_s_setprio(0);
            if (q == 3) {
                if (tt < 62) {
                    if constexpr (NF == 4) asm volatile("s_waitcnt vmcnt(6)" ::: "memory");
                    else                   asm volatile("s_waitcnt vmcnt(5)" ::: "memory");
                } else if (tt == 62) {
                    asm volatile("s_waitcnt vmcnt(0)" ::: "memory");
                }
            }
            __builtin_amdgcn_s_barrier();
        }
    }
}

// GEMM1: hidden @ Wqkv^T -> q (RoPE+scale fused), k (RoPE fused), V^T (fused).
// 256x192 tiles -> 512 blocks = 2 full dispatch rounds (no half-empty tail).
__global__ __launch_bounds__(512) void k_gemm_qkv(
    const f16* __restrict__ A, const f16* __restrict__ Bt,
    f16* __restrict__ q, f16* __restrict__ kk_, f16* __restrict__ vt,
    const float* __restrict__ cosb, const float* __restrict__ sinb) {
    __shared__ __align__(16) char L[2 * (32768 + 192 * 128)];   // 112KB
    const int bid = blockIdx.x;                    // 512 = 16m x 32n
    const int swzb = (bid & 7) * 64 + (bid >> 3);  // XCD-bijective
    const int m0 = (swzb >> 5) * 256, n0 = (swzb & 31) * 192;
    f32x4 acc[8][3] = {};
    gemm_core<192>(A, Bt, L, m0, n0, acc);

    const int lane = threadIdx.x & 63, wave = threadIdx.x >> 6;
    const int wm = wave >> 2, wn = wave & 3;
    const int fr = lane & 15, fg = lane >> 4;
#pragma unroll
    for (int mf = 0; mf < 8; ++mf) {
        int r0 = m0 + wm * 128 + mf * 16 + 4 * fg;
        int b = r0 >> 11, s = r0 & (Sn - 1);   // r0 multiple of 4: same b, s..s+3
        const float* cb_ = cosb + ((long)b * Sn + s) * 64;
        const float* sb_ = sinb + ((long)b * Sn + s) * 64;
#pragma unroll
        for (int nf = 0; nf < 3; ++nf) {
            int cc = n0 + wn * 48 + nf * 16 + fr;
            int d = cc & 127;
            if (cc < 5120) {
                float vals[4];
#pragma unroll
                for (int e = 0; e < 4; ++e) vals[e] = acc[mf][nf][e];
                if (d < 64) {
                    int ci = d >> 1;
                    bool odd = (d & 1);
#pragma unroll
                    for (int e = 0; e < 4; ++e) {
                        float p = __shfl_xor(vals[e], 1, 64);   // lane^1 = d^1
                        float c = cb_[e * 64 + ci], sv = sb_[e * 64 + ci];
                        vals[e] = odd ? (vals[e] * c + p * sv)
                                      : (vals[e] * c - p * sv);
                    }
                }
                if (cc < 4096) {
                    int h = cc >> 7;
#pragma unroll
                    for (int e = 0; e < 4; ++e)
                        q[(((long)b * NH + h) * Sn + s + e) * HD + d] =
                            (f16)(vals[e] * QSC);
                } else {
                    int h = (cc - 4096) >> 7;
#pragma unroll
                    for (int e = 0; e < 4; ++e)
                        kk_[(((long)b * NKV + h) * Sn + s + e) * HD + d] =
                            (f16)vals[e];
                }
            } else {
                int h = (cc - 5120) >> 7;
                uint2 w = {pk2(acc[mf][nf][0], acc[mf][nf][1]),
                           pk2(acc[mf][nf][2], acc[mf][nf][3])};
                *(uint2*)&vt[(((long)b * NKV + h) * HD + d) * Sn + s] = w;
            }
        }
    }
}

// GEMM2: attn_out @ wo^T -> d_out f32, 256 blocks (16x16) = 1 full round
__global__ __launch_bounds__(512) void k_gemm_out(
    const f16* __restrict__ A, const f16* __restrict__ Bt,
    float* __restrict__ out) {
    __shared__ __align__(16) char L[131072];
    const int bid = blockIdx.x;
    const int swzb = (bid & 7) * 32 + (bid >> 3);
    const int m0 = (swzb >> 4) * 256, n0 = (swzb & 15) * 256;
    f32x4 acc[8][4] = {};
    gemm_core<256>(A, Bt, L, m0, n0, acc);

    const int lane = threadIdx.x & 63, wave = threadIdx.x >> 6;
    const int wm = wave >> 2, wn = wave & 3;
    const int fr = lane & 15, fg = lane >> 4;
#pragma unroll
    for (int mf = 0; mf < 8; ++mf) {
        int r0 = m0 + wm * 128 + mf * 16 + 4 * fg;
#pragma unroll
        for (int nf = 0; nf < 4; ++nf) {
            int cc = n0 + wn * 64 + nf * 16 + fr;
#pragma unroll
            for (int e = 0; e < 4; ++e)
                out[(long)(r0 + e) * 4096 + cc] = acc[mf][nf][e];
        }
    }
}

// ---------------------------------------------------------------------------
// Flash attention v6 (r13-proven): QBLK=256 (8 waves x 32 q), 32x32x16 MFMA,
// in-register P via pk2 + shfl_xor(32); swapped QK^T (q lane-local softmax).
//   A: row=lane&31, k=8*(lane>>5)+e   B: k=8*(lane>>5)+e, col=lane&31
//   C: col=lane&31, row=(reg&3)+8*(reg>>2)+4*(lane>>5)

__device__ __forceinline__ f16x8 ld_sw256(const f16* base, int r, int c) {
    int byte = r * 256 + ((c * 2) ^ ((r & 7) << 4));
    return *(const f16x8*)((const char*)base + byte);
}
__device__ __forceinline__ f16x8 ld_sw128(const f16* base, int r, int c) {
    int byte = r * 128 + ((c * 2) ^ ((r & 7) << 4));
    return *(const f16x8*)((const char*)base + byte);
}

// K tile [64 kv][128 d] f16 = 16KB = 16 chunks; 8 waves x 2 chunks
__device__ __forceinline__ void stage_k(const f16* __restrict__ Kb, f16* ksm,
                                        int k0, int wave, int lane) {
#pragma unroll
    for (int i = 0; i < 2; ++i) {
        int dbase = (i * 8 + wave) * 1024;
        int d = dbase + lane * 16;
        int row = d >> 8;
        int cb = (d & 255) ^ ((row & 7) << 4);
        async_ld16(Kb + (long)(k0 + row) * HD + (cb >> 1), (char*)ksm + dbase);
    }
}
__device__ __forceinline__ void stage_v(const f16* __restrict__ Vb, f16* vsm,
                                        int k0, int wave, int lane) {
#pragma unroll
    for (int i = 0; i < 2; ++i) {
        int dbase = (i * 8 + wave) * 1024;
        int d = dbase + lane * 16;
        int row = d >> 7;
        int cb = (d & 127) ^ ((row & 7) << 4);
        async_ld16(Vb + (long)row * Sn + k0 + (cb >> 1), (char*)vsm + dbase);
    }
}

__global__ __launch_bounds__(512) void k_attn(
    const f16* __restrict__ Q, const f16* __restrict__ K,
    const f16* __restrict__ Vt, f16* __restrict__ O) {
    __shared__ __align__(16) f16 Ksm[2][64 * 128];   // 32KB
    __shared__ __align__(16) f16 Vsm[2][128 * 64];   // 32KB

    // grid 512: id = ((b*4 + hg)*8 + pos)*8 + kvh; pos pairs (heavy, light)
    const int id = blockIdx.x;
    const int kvh = id & 7;                 // XCD-local KV
    const int r_ = id >> 3;
    const int pos = r_ & 7;
    const int qt = (pos & 1) ? (pos >> 1) : (7 - (pos >> 1)); // 7,0,6,1,5,2,4,3
    const int hg = (r_ >> 3) & 3;
    const int b  = r_ >> 5;
    const int h  = kvh * 4 + hg;
    const int q0 = qt * 256;
    const int t = threadIdx.x, lane = t & 63, wave = t >> 6;
    const int q0w = q0 + wave * 32;
    const int lq = lane & 31, hi = lane >> 5;

    const f16* Qb = Q + ((long)(b * NH + h) * Sn) * HD;
    const f16* Kb = K + ((long)(b * NKV + kvh) * Sn) * HD;
    const f16* Vb = Vt + ((long)(b * NKV + kvh) * HD) * Sn;

    f16x8 qf[8];
#pragma unroll
    for (int s = 0; s < 8; ++s)
        qf[s] = *(const f16x8*)&Qb[(long)(q0w + lq) * HD + 16 * s + 8 * hi];

    f32x16 oacc[4] = {};
    float mrun = -1e30f, lrun = 0.f;

    const int nt = q0 / 64 + 4;   // cover q0+255
    stage_k(Kb, Ksm[0], 0, wave, lane);
    stage_v(Vb, Vsm[0], 0, wave, lane);

    for (int kt = 0; kt < nt; ++kt) {
        const int k0 = kt * 64;
        const int cur = kt & 1;
        if (kt + 1 < nt) {
            stage_k(Kb, Ksm[cur ^ 1], (kt + 1) * 64, wave, lane);
            stage_v(Vb, Vsm[cur ^ 1], (kt + 1) * 64, wave, lane);
            asm volatile("s_waitcnt vmcnt(4)" ::: "memory"); // cur tile landed
        } else {
            asm volatile("s_waitcnt vmcnt(0)" ::: "memory");
        }
        __builtin_amdgcn_s_barrier();

        if (k0 <= q0w + 31) {
            f32x16 st[2] = {};
#pragma unroll
            for (int s = 0; s < 8; ++s) {
                f16x8 kf0 = ld_sw256(Ksm[cur], lq,      16 * s + 8 * hi);
                f16x8 kf1 = ld_sw256(Ksm[cur], 32 + lq, 16 * s + 8 * hi);
                st[0] = __builtin_amdgcn_mfma_f32_32x32x16_f16(kf0, qf[s], st[0], 0, 0, 0);
                st[1] = __builtin_amdgcn_mfma_f32_32x32x16_f16(kf1, qf[s], st[1], 0, 0, 0);
            }
            const bool full = (k0 + 63 <= q0w);
            if (!full) {
#pragma unroll
                for (int mt = 0; mt < 2; ++mt)
#pragma unroll
                    for (int r = 0; r < 16; ++r) {
                        int kvv = k0 + 32 * mt + (r & 3) + 8 * (r >> 2) + 4 * hi;
                        if (kvv > q0w + lq) st[mt][r] = -1e30f;
                    }
            }
            float pm = st[0][0];
#pragma unroll
            for (int r = 1; r < 16; ++r) pm = fmaxf(pm, st[0][r]);
#pragma unroll
            for (int r = 0; r < 16; ++r) pm = fmaxf(pm, st[1][r]);
            pm = fmaxf(pm, __shfl_xor(pm, 32, 64));
            if (__any(pm > mrun + 8.f)) {
                float mn = fmaxf(mrun, pm);
                float sc = fexp2(mrun - mn);
                mrun = mn;
                lrun *= sc;
                float scr[16];
#pragma unroll
                for (int r = 0; r < 16; ++r)
                    scr[r] = __shfl(sc, (r & 3) + 8 * (r >> 2) + 4 * hi, 64);
#pragma unroll
                for (int db = 0; db < 4; ++db)
#pragma unroll
                    for (int r = 0; r < 16; ++r)
                        oacc[db][r] *= scr[r];
            }
            unsigned pw[2][8];
#pragma unroll
            for (int mt = 0; mt < 2; ++mt)
#pragma unroll
                for (int i = 0; i < 8; ++i) {
                    float p0 = fexp2(st[mt][2 * i]     - mrun);
                    float p1 = fexp2(st[mt][2 * i + 1] - mrun);
                    lrun += p0 + p1;
                    pw[mt][i] = pk2(p0, p1);
                }
#pragma unroll
            for (int s = 0; s < 4; ++s) {
                const int mt = s >> 1, sl = s & 1;
                unsigned a0 = pw[mt][4 * sl], a1 = pw[mt][4 * sl + 1];
                unsigned a2 = pw[mt][4 * sl + 2], a3 = pw[mt][4 * sl + 3];
                unsigned own0 = hi ? a2 : a0, own1 = hi ? a3 : a1;
                unsigned snd0 = hi ? a0 : a2, snd1 = hi ? a1 : a3;
                unsigned rx0 = (unsigned)__shfl_xor((int)snd0, 32, 64);
                unsigned rx1 = (unsigned)__shfl_xor((int)snd1, 32, 64);
                union { unsigned u[4]; f16x8 v; } pu;
                pu.u[0] = hi ? rx0 : own0;
                pu.u[1] = hi ? rx1 : own1;
                pu.u[2] = hi ? own0 : rx0;
                pu.u[3] = hi ? own1 : rx1;
#pragma unroll
                for (int db = 0; db < 4; ++db) {
                    f16x8 vf = ld_sw128(Vsm[cur], 32 * db + lq, 16 * s + 8 * hi);
                    oacc[db] = __builtin_amdgcn_mfma_f32_32x32x16_f16(pu.v, vf, oacc[db], 0, 0, 0);
                }
            }
        }
        __builtin_amdgcn_s_barrier();
    }

    lrun += __shfl_xor(lrun, 32, 64);
    float li = 1.f / lrun;
    float ir[16];
#pragma unroll
    for (int r = 0; r < 16; ++r)
        ir[r] = __shfl(li, (r & 3) + 8 * (r >> 2) + 4 * hi, 64);
#pragma unroll
    for (int db = 0; db < 4; ++db)
#pragma unroll
        for (int r = 0; r < 16; ++r) {
            int qloc = (r & 3) + 8 * (r >> 2) + 4 * hi;
            long tok = (long)b * Sn + q0w + qloc;
            O[tok * (NH * HD) + h * HD + 32 * db + lq] = (f16)(oacc[db][r] * ir[r]);
        }
}

// sentinel if workspace too small
__global__ void k_ws_fail(float* out) { out[0] = 1.0e9f; }

// ---------------------------------------------------------------------------
extern "C" void kernel_launch(void* const* d_in, const int* in_sizes, int n_in,
                              void* d_out, int out_size, void* d_ws, size_t ws_size,
                              hipStream_t stream) {
    const float* hs   = (const float*)d_in[0];
    const float* wq   = (const float*)d_in[1];
    const float* wk   = (const float*)d_in[2];
    const float* wv   = (const float*)d_in[3];
    const float* wo   = (const float*)d_in[4];
    const float* cosb = (const float*)d_in[5];
    const float* sinb = (const float*)d_in[6];
    float* out = (float*)d_out;

    const size_t OFF_WQKV = 0;
    const size_t OFF_WO   = 50331648;
    const size_t OFF_HID  = 83886080;
    const size_t OFF_Q    = 117440512;
    const size_t OFF_K    = 150994944;
    const size_t OFF_VT   = 167772160;
    const size_t WS_NEED  = 176160768;
    if (ws_size < WS_NEED) { k_ws_fail<<<1, 1, 0, stream>>>(out); return; }

    char* ws = (char*)d_ws;
    f16* wqkv_t = (f16*)(ws + OFF_WQKV);
    f16* wo_t   = (f16*)(ws + OFF_WO);
    f16* hid    = (f16*)(ws + OFF_HID);
    f16* qb     = (f16*)(ws + OFF_Q);
    f16* kb     = (f16*)(ws + OFF_K);
    f16* vtb    = (f16*)(ws + OFF_VT);

    // 1 prep dispatch: 8192 cvt blocks + (4096+1024+1024+4096) tcvt blocks
    k_prep<<<dim3(18432), 256, 0, stream>>>(hs, hid, wq, wk, wv, wo, wqkv_t, wo_t);
    k_gemm_qkv<<<dim3(512), 512, 0, stream>>>(hid, wqkv_t, qb, kb, vtb, cosb, sinb);
    k_attn<<<dim3(512), 512, 0, stream>>>(qb, kb, vtb, hid);
    k_gemm_out<<<dim3(256), 512, 0, stream>>>(hid, wo_t, out);
}

// Round 16
// 522.074 us; speedup vs baseline: 2.2510x; 1.0420x over previous
//
#include <hip/hip_runtime.h>

// ============================================================================
// GLM4-MoE attention layer on MI355X (gfx950), fp16 MFMA pipeline.
// Round 16: GEMM1 wave-tile fattened. r15 analysis: LDS read pipe was the
// critical path (176KB/K-tile = 2070cy vs 1546cy MFMA -> 42% util ceiling).
// New GEMM1: block 256x384, 8 waves of 128x96 (LDS/MFMA = 2635/3093cy ->
// MFMA-bound), LDS 160KB (full pool, AITER-precedented), grid 256 = 1 full
// round. ks-major phases (ks,mh), B-frags of one ks live at a time (VGPR
// ~250). Staging ledger: ph0 stages A-hi(t+1)->buf^1; ph3 stages B(t+2)+
// A-lo(t+2)->buf (regions dead by ph2-end barrier); vmcnt(8) steady,
// vmcnt(0) at t=62. GEMM2 keeps r15 NTILE=256 template. Attn/prep unchanged.
// ============================================================================

typedef _Float16 f16;
typedef _Float16 f16x8 __attribute__((ext_vector_type(8)));
typedef float f32x4 __attribute__((ext_vector_type(4)));
typedef float f32x16 __attribute__((ext_vector_type(16)));

static constexpr int Bn = 2, Sn = 2048, Hn = 4096, NH = 32, NKV = 8, HD = 128;
static constexpr float QSC = 0.08838834764831845f * 1.44269504088896340736f; // 1/sqrt(128)*log2e

#define AS1 __attribute__((address_space(1)))
#define AS3 __attribute__((address_space(3)))

__device__ __forceinline__ void async_ld16(const void* g, void* l) {
    __builtin_amdgcn_global_load_lds((const AS1 void*)g, (AS3 void*)l, 16, 0, 0);
}

__device__ __forceinline__ unsigned pk2(float a, float b) {
    unsigned r;
    asm("v_cvt_pkrtz_f16_f32 %0, %1, %2" : "=v"(r) : "v"(a), "v"(b));
    return r;
}

// native exp2: v_exp_f32 computes 2^x
__device__ __forceinline__ float fexp2(float x) {
    float r;
    asm("v_exp_f32 %0, %1" : "=v"(r) : "v"(x));
    return r;
}

// ---------------------------------------------------------------------------
// Merged prep: blocks [0,8192) = hidden f32->f16 convert (8 elems/thread);
// blocks [8192,18432) = four 64x64 transpose-converts (wq/wk/wv/wo).
__global__ __launch_bounds__(256) void k_prep(
    const float* __restrict__ hs, f16* __restrict__ hid,
    const float* __restrict__ wq, const float* __restrict__ wk,
    const float* __restrict__ wv, const float* __restrict__ wo,
    f16* __restrict__ wqkv_t, f16* __restrict__ wo_t) {
    int bid = blockIdx.x;
    if (bid < 8192) {
        long i = ((long)bid * 256 + threadIdx.x) * 8;
        float4 a = *(const float4*)(hs + i);
        float4 b = *(const float4*)(hs + i + 4);
        f16x8 o = {(f16)a.x, (f16)a.y, (f16)a.z, (f16)a.w,
                   (f16)b.x, (f16)b.y, (f16)b.z, (f16)b.w};
        *(f16x8*)(hid + i) = o;
        return;
    }
    bid -= 8192;
    const float* src;
    f16* dst;
    int N, bx, by;
    if (bid < 4096)      { src = wq; dst = wqkv_t;                    N = 4096; bx = bid & 63; by = bid >> 6; }
    else if (bid < 5120) { bid -= 4096; src = wk; dst = wqkv_t + (long)4096 * 4096; N = 1024; bx = bid & 15; by = bid >> 4; }
    else if (bid < 6144) { bid -= 5120; src = wv; dst = wqkv_t + (long)5120 * 4096; N = 1024; bx = bid & 15; by = bid >> 4; }
    else                 { bid -= 6144; src = wo; dst = wo_t;         N = 4096; bx = bid & 63; by = bid >> 6; }
    __shared__ float tile[64][65];
    const int k0 = by * 64, n0 = bx * 64;
    const int tx = threadIdx.x & 63, ty = threadIdx.x >> 6;   // (64,4)
#pragma unroll
    for (int r = ty; r < 64; r += 4)
        tile[r][tx] = src[(long)(k0 + r) * N + (n0 + tx)];
    __syncthreads();
#pragma unroll
    for (int r = ty; r < 64; r += 4)
        dst[(long)(n0 + r) * 4096 + (k0 + tx)] = (f16)tile[tx][r];
}

// ---------------------------------------------------------------------------
// 256x384 GEMM core: 8 waves (2M x 4N), wave 128x96, BK=64, K=4096.
// LDS 160KB: buf c at c*81920; A [256r][128B] at +0; B [384r][128B] at +32768.
// Rows swizzled: byte cb ^ ((row&7)<<4). 4 ks-major phases per K-tile.
__device__ __forceinline__ void gemm384_core(
    const f16* __restrict__ A, const f16* __restrict__ Bt,
    char* L, int m0, int n0, f32x4 acc[8][6]) {
    const int t = threadIdx.x, lane = t & 63, wave = t >> 6;
    const int wm = wave >> 2, wn = wave & 3;
    const int fr = lane & 15, fg = lane >> 4;

    const int srowL = wave * 8 + (lane >> 3);
    const int scol  = 8 * ((lane & 7) ^ (lane >> 3));
    const f16* ga = A  + (long)(m0 + srowL) * 4096 + scol;
    const f16* gb = Bt + (long)(n0 + srowL) * 4096 + scol;
    const int woff = wave * 1024;

    auto ST = [&](int sel, int c, int row0, int kt) {
        const f16* g = sel ? gb : ga;
        async_ld16(g + (long)row0 * 4096 + kt * 64,
                   L + c * 81920 + sel * 32768 + row0 * 128 + woff);
    };

    // prologue: t0 full (A4 + B6); then B(t1)x6 + A-lo(t1)x2.
    ST(0, 0, 0, 0); ST(0, 0, 64, 0); ST(0, 0, 128, 0); ST(0, 0, 192, 0);
#pragma unroll
    for (int r = 0; r < 384; r += 64) ST(1, 0, r, 0);
#pragma unroll
    for (int r = 0; r < 384; r += 64) ST(1, 1, r, 1);
    ST(0, 1, 0, 1); ST(0, 1, 128, 1);
    asm volatile("s_waitcnt vmcnt(8)" ::: "memory");  // t0 landed; t1's 8 in flight
    __builtin_amdgcn_s_barrier();

    const int abase = wm * 128;
    const int bbase = wn * 96;

    for (int tt = 0; tt < 64; ++tt) {
        const int c = tt & 1;
        const char* bufA = L + c * 81920;
        const char* bufB = bufA + 32768;
        f16x8 bf[6];

#pragma unroll
        for (int ph = 0; ph < 4; ++ph) {
            const int ks = ph >> 1, mh = ph & 1;
            // ---- ds_read: B-frags for this ks (phases 0,2); A-frags always
            if (mh == 0) {
#pragma unroll
                for (int nf = 0; nf < 6; ++nf) {
                    int r = bbase + nf * 16 + fr;
                    bf[nf] = *(const f16x8*)(bufB + r * 128 +
                                 ((ks * 64 + 16 * fg) ^ ((r & 7) << 4)));
                }
            }
            f16x8 af[4];
#pragma unroll
            for (int i = 0; i < 4; ++i) {
                int r = abase + mh * 64 + i * 16 + fr;
                af[i] = *(const f16x8*)(bufA + r * 128 +
                             ((ks * 64 + 16 * fg) ^ ((r & 7) << 4)));
            }
            // ---- staging (ledger in header)
            if (ph == 0) { if (tt + 1 < 64) { ST(0, c ^ 1,  64, tt + 1);
                                              ST(0, c ^ 1, 192, tt + 1); } }
            if (ph == 3) { if (tt + 2 < 64) {
#pragma unroll
                for (int r = 0; r < 384; r += 64) ST(1, c, r, tt + 2);
                ST(0, c, 0, tt + 2); ST(0, c, 128, tt + 2); } }
            __builtin_amdgcn_s_barrier();
            __builtin_amdgcn_s_setprio(1);
#pragma unroll
            for (int i = 0; i < 4; ++i)
#pragma unroll
                for (int nf = 0; nf < 6; ++nf)
                    acc[mh * 4 + i][nf] = __builtin_amdgcn_mfma_f32_16x16x32_f16(
                        af[i], bf[nf], acc[mh * 4 + i][nf], 0, 0, 0);
            __builtin_amdgcn_s_setprio(0);
            if (ph == 3) {
                if (tt < 62)       asm volatile("s_waitcnt vmcnt(8)" ::: "memory");
                else if (tt == 62) asm volatile("s_waitcnt vmcnt(0)" ::: "memory");
            }
            __builtin_amdgcn_s_barrier();
        }
    }
}

// ---------------------------------------------------------------------------
// 256x256 GEMM core (r11/r15-proven) for GEMM2.
__device__ __forceinline__ void gemm256_core(
    const f16* __restrict__ A, const f16* __restrict__ Bt,
    char* L, int m0, int n0, f32x4 acc[8][4]) {
    const int t = threadIdx.x, lane = t & 63, wave = t >> 6;
    const int wm = wave >> 2, wn = wave & 3;
    const int fr = lane & 15, fg = lane >> 4;

    const int srowL = wave * 8 + (lane >> 3);
    const int scol  = 8 * ((lane & 7) ^ (lane >> 3));
    const f16* ga = A  + (long)(m0 + srowL) * 4096 + scol;
    const f16* gb = Bt + (long)(n0 + srowL) * 4096 + scol;
    const int woff = wave * 1024;

    auto ST = [&](int sel, int c, int row0, int kt) {
        const f16* g = sel ? gb : ga;
        async_ld16(g + (long)row0 * 4096 + kt * 64,
                   L + c * 65536 + sel * 32768 + row0 * 128 + woff);
    };

    ST(0, 0, 0, 0);   ST(0, 0, 64, 0);  ST(0, 0, 128, 0); ST(0, 0, 192, 0);
    ST(1, 0, 0, 0);   ST(1, 0, 64, 0);  ST(1, 0, 128, 0); ST(1, 0, 192, 0);
    ST(1, 1, 0, 1);   ST(1, 1, 64, 1);  ST(1, 1, 128, 1); ST(1, 1, 192, 1);
    ST(0, 1, 0, 1);   ST(0, 1, 128, 1);
    asm volatile("s_waitcnt vmcnt(6)" ::: "memory");
    __builtin_amdgcn_s_barrier();

    const int abase = wm * 128;
    const int bbase = wn * 64;

    for (int tt = 0; tt < 64; ++tt) {
        const int c = tt & 1;
        const char* bufA = L + c * 65536;
        const char* bufB = bufA + 32768;
        f16x8 bf[2][4];

#pragma unroll
        for (int q = 0; q < 4; ++q) {
            if (q == 0) {
#pragma unroll
                for (int ks = 0; ks < 2; ++ks)
#pragma unroll
                    for (int nf = 0; nf < 4; ++nf) {
                        int r = bbase + nf * 16 + fr;
                        bf[ks][nf] = *(const f16x8*)(bufB + r * 128 +
                                        ((ks * 64 + 16 * fg) ^ ((r & 7) << 4)));
                    }
            }
            f16x8 af[2][2];
#pragma unroll
            for (int ks = 0; ks < 2; ++ks)
#pragma unroll
                for (int i = 0; i < 2; ++i) {
                    int r = abase + (2 * q + i) * 16 + fr;
                    af[ks][i] = *(const f16x8*)(bufA + r * 128 +
                                    ((ks * 64 + 16 * fg) ^ ((r & 7) << 4)));
                }
            if (q == 0) { if (tt + 1 < 64) { ST(0, c ^ 1,  64, tt + 1);
                                             ST(0, c ^ 1, 192, tt + 1); } }
            if (q == 1) { if (tt + 2 < 64) { ST(1, c,   0, tt + 2);
                                             ST(1, c,  64, tt + 2); } }
            if (q == 2) { if (tt + 2 < 64) { ST(1, c, 128, tt + 2);
                                             ST(1, c, 192, tt + 2); } }
            if (q == 3) { if (tt + 2 < 64) { ST(0, c,   0, tt + 2);
                                             ST(0, c, 128, tt + 2); } }
            __builtin_amdgcn_s_barrier();
            __builtin_amdgcn_s_setprio(1);
#pragma unroll
            for (int ks = 0; ks < 2; ++ks)
#pragma unroll
                for (int i = 0; i < 2; ++i)
#pragma unroll
                    for (int nf = 0; nf < 4; ++nf)
                        acc[2 * q + i][nf] = __builtin_amdgcn_mfma_f32_16x16x32_f16(
                            af[ks][i], bf[ks][nf], acc[2 * q + i][nf], 0, 0, 0);
            __builtin_amdgcn_s_setprio(0);
            if (q == 3) {
                if (tt < 62)       asm volatile("s_waitcnt vmcnt(6)" ::: "memory");
                else if (tt == 62) asm volatile("s_waitcnt vmcnt(0)" ::: "memory");
            }
            __builtin_amdgcn_s_barrier();
        }
    }
}

// GEMM1: hidden @ Wqkv^T -> q (RoPE+scale fused), k (RoPE fused), V^T (fused).
// 256x384 tiles -> 256 blocks = 1 full dispatch round.
__global__ __launch_bounds__(512) void k_gemm_qkv(
    const f16* __restrict__ A, const f16* __restrict__ Bt,
    f16* __restrict__ q, f16* __restrict__ kk_, f16* __restrict__ vt,
    const float* __restrict__ cosb, const float* __restrict__ sinb) {
    __shared__ __align__(16) char L[163840];       // full 160KB pool
    const int bid = blockIdx.x;                    // 256 = 16m x 16n
    const int swzb = (bid & 7) * 32 + (bid >> 3);  // XCD-bijective
    const int m0 = (swzb >> 4) * 256, n0 = (swzb & 15) * 384;
    f32x4 acc[8][6] = {};
    gemm384_core(A, Bt, L, m0, n0, acc);

    const int lane = threadIdx.x & 63, wave = threadIdx.x >> 6;
    const int wm = wave >> 2, wn = wave & 3;
    const int fr = lane & 15, fg = lane >> 4;
#pragma unroll
    for (int mf = 0; mf < 8; ++mf) {
        int r0 = m0 + wm * 128 + mf * 16 + 4 * fg;
        int b = r0 >> 11, s = r0 & (Sn - 1);   // r0 multiple of 4: same b, s..s+3
        const float* cb_ = cosb + ((long)b * Sn + s) * 64;
        const float* sb_ = sinb + ((long)b * Sn + s) * 64;
#pragma unroll
        for (int nf = 0; nf < 6; ++nf) {
            int cc = n0 + wn * 96 + nf * 16 + fr;
            int d = cc & 127;
            if (cc < 5120) {
                float vals[4];
#pragma unroll
                for (int e = 0; e < 4; ++e) vals[e] = acc[mf][nf][e];
                if (d < 64) {
                    int ci = d >> 1;
                    bool odd = (d & 1);
#pragma unroll
                    for (int e = 0; e < 4; ++e) {
                        float p = __shfl_xor(vals[e], 1, 64);   // lane^1 = d^1
                        float c = cb_[e * 64 + ci], sv = sb_[e * 64 + ci];
                        vals[e] = odd ? (vals[e] * c + p * sv)
                                      : (vals[e] * c - p * sv);
                    }
                }
                if (cc < 4096) {
                    int h = cc >> 7;
#pragma unroll
                    for (int e = 0; e < 4; ++e)
                        q[(((long)b * NH + h) * Sn + s + e) * HD + d] =
                            (f16)(vals[e] * QSC);
                } else {
                    int h = (cc - 4096) >> 7;
#pragma unroll
                    for (int e = 0; e < 4; ++e)
                        kk_[(((long)b * NKV + h) * Sn + s + e) * HD + d] =
                            (f16)vals[e];
                }
            } else {
                int h = (cc - 5120) >> 7;
                uint2 w = {pk2(acc[mf][nf][0], acc[mf][nf][1]),
                           pk2(acc[mf][nf][2], acc[mf][nf][3])};
                *(uint2*)&vt[(((long)b * NKV + h) * HD + d) * Sn + s] = w;
            }
        }
    }
}

// GEMM2: attn_out @ wo^T -> d_out f32, 256 blocks (16x16) = 1 full round
__global__ __launch_bounds__(512) void k_gemm_out(
    const f16* __restrict__ A, const f16* __restrict__ Bt,
    float* __restrict__ out) {
    __shared__ __align__(16) char L[131072];
    const int bid = blockIdx.x;
    const int swzb = (bid & 7) * 32 + (bid >> 3);
    const int m0 = (swzb >> 4) * 256, n0 = (swzb & 15) * 256;
    f32x4 acc[8][4] = {};
    gemm256_core(A, Bt, L, m0, n0, acc);

    const int lane = threadIdx.x & 63, wave = threadIdx.x >> 6;
    const int wm = wave >> 2, wn = wave & 3;
    const int fr = lane & 15, fg = lane >> 4;
#pragma unroll
    for (int mf = 0; mf < 8; ++mf) {
        int r0 = m0 + wm * 128 + mf * 16 + 4 * fg;
#pragma unroll
        for (int nf = 0; nf < 4; ++nf) {
            int cc = n0 + wn * 64 + nf * 16 + fr;
#pragma unroll
            for (int e = 0; e < 4; ++e)
                out[(long)(r0 + e) * 4096 + cc] = acc[mf][nf][e];
        }
    }
}

// ---------------------------------------------------------------------------
// Flash attention v6 (r13-proven): QBLK=256 (8 waves x 32 q), 32x32x16 MFMA,
// in-register P via pk2 + shfl_xor(32); swapped QK^T (q lane-local softmax).
//   A: row=lane&31, k=8*(lane>>5)+e   B: k=8*(lane>>5)+e, col=lane&31
//   C: col=lane&31, row=(reg&3)+8*(reg>>2)+4*(lane>>5)

__device__ __forceinline__ f16x8 ld_sw256(const f16* base, int r, int c) {
    int byte = r * 256 + ((c * 2) ^ ((r & 7) << 4));
    return *(const f16x8*)((const char*)base + byte);
}
__device__ __forceinline__ f16x8 ld_sw128(const f16* base, int r, int c) {
    int byte = r * 128 + ((c * 2) ^ ((r & 7) << 4));
    return *(const f16x8*)((const char*)base + byte);
}

// K tile [64 kv][128 d] f16 = 16KB = 16 chunks; 8 waves x 2 chunks
__device__ __forceinline__ void stage_k(const f16* __restrict__ Kb, f16* ksm,
                                        int k0, int wave, int lane) {
#pragma unroll
    for (int i = 0; i < 2; ++i) {
        int dbase = (i * 8 + wave) * 1024;
        int d = dbase + lane * 16;
        int row = d >> 8;
        int cb = (d & 255) ^ ((row & 7) << 4);
        async_ld16(Kb + (long)(k0 + row) * HD + (cb >> 1), (char*)ksm + dbase);
    }
}
__device__ __forceinline__ void stage_v(const f16* __restrict__ Vb, f16* vsm,
                                        int k0, int wave, int lane) {
#pragma unroll
    for (int i = 0; i < 2; ++i) {
        int dbase = (i * 8 + wave) * 1024;
        int d = dbase + lane * 16;
        int row = d >> 7;
        int cb = (d & 127) ^ ((row & 7) << 4);
        async_ld16(Vb + (long)row * Sn + k0 + (cb >> 1), (char*)vsm + dbase);
    }
}

__global__ __launch_bounds__(512) void k_attn(
    const f16* __restrict__ Q, const f16* __restrict__ K,
    const f16* __restrict__ Vt, f16* __restrict__ O) {
    __shared__ __align__(16) f16 Ksm[2][64 * 128];   // 32KB
    __shared__ __align__(16) f16 Vsm[2][128 * 64];   // 32KB

    // grid 512: id = ((b*4 + hg)*8 + pos)*8 + kvh; pos pairs (heavy, light)
    const int id = blockIdx.x;
    const int kvh = id & 7;                 // XCD-local KV
    const int r_ = id >> 3;
    const int pos = r_ & 7;
    const int qt = (pos & 1) ? (pos >> 1) : (7 - (pos >> 1)); // 7,0,6,1,5,2,4,3
    const int hg = (r_ >> 3) & 3;
    const int b  = r_ >> 5;
    const int h  = kvh * 4 + hg;
    const int q0 = qt * 256;
    const int t = threadIdx.x, lane = t & 63, wave = t >> 6;
    const int q0w = q0 + wave * 32;
    const int lq = lane & 31, hi = lane >> 5;

    const f16* Qb = Q + ((long)(b * NH + h) * Sn) * HD;
    const f16* Kb = K + ((long)(b * NKV + kvh) * Sn) * HD;
    const f16* Vb = Vt + ((long)(b * NKV + kvh) * HD) * Sn;

    f16x8 qf[8];
#pragma unroll
    for (int s = 0; s < 8; ++s)
        qf[s] = *(const f16x8*)&Qb[(long)(q0w + lq) * HD + 16 * s + 8 * hi];

    f32x16 oacc[4] = {};
    float mrun = -1e30f, lrun = 0.f;

    const int nt = q0 / 64 + 4;   // cover q0+255
    stage_k(Kb, Ksm[0], 0, wave, lane);
    stage_v(Vb, Vsm[0], 0, wave, lane);

    for (int kt = 0; kt < nt; ++kt) {
        const int k0 = kt * 64;
        const int cur = kt & 1;
        if (kt + 1 < nt) {
            stage_k(Kb, Ksm[cur ^ 1], (kt + 1) * 64, wave, lane);
            stage_v(Vb, Vsm[cur ^ 1], (kt + 1) * 64, wave, lane);
            asm volatile("s_waitcnt vmcnt(4)" ::: "memory"); // cur tile landed
        } else {
            asm volatile("s_waitcnt vmcnt(0)" ::: "memory");
        }
        __builtin_amdgcn_s_barrier();

        if (k0 <= q0w + 31) {
            f32x16 st[2] = {};
#pragma unroll
            for (int s = 0; s < 8; ++s) {
                f16x8 kf0 = ld_sw256(Ksm[cur], lq,      16 * s + 8 * hi);
                f16x8 kf1 = ld_sw256(Ksm[cur], 32 + lq, 16 * s + 8 * hi);
                st[0] = __builtin_amdgcn_mfma_f32_32x32x16_f16(kf0, qf[s], st[0], 0, 0, 0);
                st[1] = __builtin_amdgcn_mfma_f32_32x32x16_f16(kf1, qf[s], st[1], 0, 0, 0);
            }
            const bool full = (k0 + 63 <= q0w);
            if (!full) {
#pragma unroll
                for (int mt = 0; mt < 2; ++mt)
#pragma unroll
                    for (int r = 0; r < 16; ++r) {
                        int kvv = k0 + 32 * mt + (r & 3) + 8 * (r >> 2) + 4 * hi;
                        if (kvv > q0w + lq) st[mt][r] = -1e30f;
                    }
            }
            float pm = st[0][0];
#pragma unroll
            for (int r = 1; r < 16; ++r) pm = fmaxf(pm, st[0][r]);
#pragma unroll
            for (int r = 0; r < 16; ++r) pm = fmaxf(pm, st[1][r]);
            pm = fmaxf(pm, __shfl_xor(pm, 32, 64));
            if (__any(pm > mrun + 8.f)) {
                float mn = fmaxf(mrun, pm);
                float sc = fexp2(mrun - mn);
                mrun = mn;
                lrun *= sc;
                float scr[16];
#pragma unroll
                for (int r = 0; r < 16; ++r)
                    scr[r] = __shfl(sc, (r & 3) + 8 * (r >> 2) + 4 * hi, 64);
#pragma unroll
                for (int db = 0; db < 4; ++db)
#pragma unroll
                    for (int r = 0; r < 16; ++r)
                        oacc[db][r] *= scr[r];
            }
            unsigned pw[2][8];
#pragma unroll
            for (int mt = 0; mt < 2; ++mt)
#pragma unroll
                for (int i = 0; i < 8; ++i) {
                    float p0 = fexp2(st[mt][2 * i]     - mrun);
                    float p1 = fexp2(st[mt][2 * i + 1] - mrun);
                    lrun += p0 + p1;
                    pw[mt][i] = pk2(p0, p1);
                }
#pragma unroll
            for (int s = 0; s < 4; ++s) {
                const int mt = s >> 1, sl = s & 1;
                unsigned a0 = pw[mt][4 * sl], a1 = pw[mt][4 * sl + 1];
                unsigned a2 = pw[mt][4 * sl + 2], a3 = pw[mt][4 * sl + 3];
                unsigned own0 = hi ? a2 : a0, own1 = hi ? a3 : a1;
                unsigned snd0 = hi ? a0 : a2, snd1 = hi ? a1 : a3;
                unsigned rx0 = (unsigned)__shfl_xor((int)snd0, 32, 64);
                unsigned rx1 = (unsigned)__shfl_xor((int)snd1, 32, 64);
                union { unsigned u[4]; f16x8 v; } pu;
                pu.u[0] = hi ? rx0 : own0;
                pu.u[1] = hi ? rx1 : own1;
                pu.u[2] = hi ? own0 : rx0;
                pu.u[3] = hi ? own1 : rx1;
#pragma unroll
                for (int db = 0; db < 4; ++db) {
                    f16x8 vf = ld_sw128(Vsm[cur], 32 * db + lq, 16 * s + 8 * hi);
                    oacc[db] = __builtin_amdgcn_mfma_f32_32x32x16_f16(pu.v, vf, oacc[db], 0, 0, 0);
                }
            }
        }
        __builtin_amdgcn_s_barrier();
    }

    lrun += __shfl_xor(lrun, 32, 64);
    float li = 1.f / lrun;
    float ir[16];
#pragma unroll
    for (int r = 0; r < 16; ++r)
        ir[r] = __shfl(li, (r & 3) + 8 * (r >> 2) + 4 * hi, 64);
#pragma unroll
    for (int db = 0; db < 4; ++db)
#pragma unroll
        for (int r = 0; r < 16; ++r) {
            int qloc = (r & 3) + 8 * (r >> 2) + 4 * hi;
            long tok = (long)b * Sn + q0w + qloc;
            O[tok * (NH * HD) + h * HD + 32 * db + lq] = (f16)(oacc[db][r] * ir[r]);
        }
}

// sentinel if workspace too small
__global__ void k_ws_fail(float* out) { out[0] = 1.0e9f; }

// ---------------------------------------------------------------------------
extern "C" void kernel_launch(void* const* d_in, const int* in_sizes, int n_in,
                              void* d_out, int out_size, void* d_ws, size_t ws_size,
                              hipStream_t stream) {
    const float* hs   = (const float*)d_in[0];
    const float* wq   = (const float*)d_in[1];
    const float* wk   = (const float*)d_in[2];
    const float* wv   = (const float*)d_in[3];
    const float* wo   = (const float*)d_in[4];
    const float* cosb = (const float*)d_in[5];
    const float* sinb = (const float*)d_in[6];
    float* out = (float*)d_out;

    const size_t OFF_WQKV = 0;
    const size_t OFF_WO   = 50331648;
    const size_t OFF_HID  = 83886080;
    const size_t OFF_Q    = 117440512;
    const size_t OFF_K    = 150994944;
    const size_t OFF_VT   = 167772160;
    const size_t WS_NEED  = 176160768;
    if (ws_size < WS_NEED) { k_ws_fail<<<1, 1, 0, stream>>>(out); return; }

    char* ws = (char*)d_ws;
    f16* wqkv_t = (f16*)(ws + OFF_WQKV);
    f16* wo_t   = (f16*)(ws + OFF_WO);
    f16* hid    = (f16*)(ws + OFF_HID);
    f16* qb     = (f16*)(ws + OFF_Q);
    f16* kb     = (f16*)(ws + OFF_K);
    f16* vtb    = (f16*)(ws + OFF_VT);

    // 1 prep dispatch: 8192 cvt blocks + (4096+1024+1024+4096) tcvt blocks
    k_prep<<<dim3(18432), 256, 0, stream>>>(hs, hid, wq, wk, wv, wo, wqkv_t, wo_t);
    k_gemm_qkv<<<dim3(256), 512, 0, stream>>>(hid, wqkv_t, qb, kb, vtb, cosb, sinb);
    k_attn<<<dim3(512), 512, 0, stream>>>(qb, kb, vtb, hid);
    k_gemm_out<<<dim3(256), 512, 0, stream>>>(hid, wo_t, out);
}